// Round 2
// baseline (14557.361 us; speedup 1.0000x reference)
//
#include <hip/hip_runtime.h>
#include <math.h>

#define B_ 2
#define L_ 4096
#define D_ 1024
#define H_ 4
#define DH 256
#define CHUNKSZ 32
#define NCH (L_/CHUNKSZ)      // 128
#define BL (B_*L_)            // 8192
#define BLD (B_*L_*D_)        // 8388608

__device__ __forceinline__ float sigmf(float x) { return 1.f / (1.f + expf(-x)); }
__device__ __forceinline__ float geluf(float x) { return 0.5f * x * (1.f + erff(x * 0.70710678118654752f)); }

// ---------------- GEMM: C[M,N] = A[M,K] @ B[K,N], f32, 128x128 tile ----------------
__global__ __launch_bounds__(256)
void gemm_f32(const float* __restrict__ A, const float* __restrict__ Bm,
              float* __restrict__ C, int M, int N, int K) {
  __shared__ float As[8][132];   // As[k][r]
  __shared__ float Bs[8][132];   // Bs[k][c]
  int bm = blockIdx.y * 128, bn = blockIdx.x * 128;
  int tx = threadIdx.x & 15, ty = threadIdx.x >> 4;
  float acc[8][8] = {};
  for (int k0 = 0; k0 < K; k0 += 8) {
    for (int i = threadIdx.x; i < 1024; i += 256) {
      int r = i >> 3, c = i & 7;
      As[c][r] = A[(long)(bm + r) * K + k0 + c];
    }
    for (int i = threadIdx.x; i < 1024; i += 256) {
      int r = i >> 7, c = i & 127;
      Bs[r][c] = Bm[(long)(k0 + r) * N + bn + c];
    }
    __syncthreads();
#pragma unroll
    for (int kk = 0; kk < 8; ++kk) {
      float a[8], b[8];
#pragma unroll
      for (int i = 0; i < 8; ++i) a[i] = As[kk][ty * 8 + i];
#pragma unroll
      for (int j = 0; j < 8; ++j) b[j] = Bs[kk][tx * 8 + j];
#pragma unroll
      for (int i = 0; i < 8; ++i)
#pragma unroll
        for (int j = 0; j < 8; ++j) acc[i][j] += a[i] * b[j];
    }
    __syncthreads();
  }
  for (int i = 0; i < 8; ++i)
    for (int j = 0; j < 8; ++j)
      C[(long)(bm + ty * 8 + i) * N + bn + tx * 8 + j] = acc[i][j];
}

// ---------------- depthwise causal conv (+ optional silu) ----------------
__global__ __launch_bounds__(256)
void dwconv_k(const float* __restrict__ x, const float* __restrict__ w,
              float* __restrict__ y, int K, int do_silu) {
  int idx = blockIdx.x * 256 + threadIdx.x;
  if (idx >= BLD) return;
  int c = idx % D_;
  int l = (idx / D_) % L_;
  const float* wc = w + c * K;
  float acc = 0.f;
  for (int j = 0; j < K; ++j) {
    int ll = l - (K - 1) + j;
    if (ll >= 0) acc += wc[j] * x[idx + (ll - l) * D_];
  }
  if (do_silu) acc = acc * sigmf(acc);
  y[idx] = acc;
}

// ---------------- small-N GEMV: out[m,n] = act(sum_k X[m,k] W[k,n] + bias) ----------------
__global__ __launch_bounds__(256)
void gemv_smallN(const float* __restrict__ X, const float* __restrict__ W,
                 const float* __restrict__ bias, float* __restrict__ out,
                 int K, int N, int act) {
  __shared__ float red[256];
  long m = blockIdx.x;
  const float* x = X + m * K;
  for (int n = 0; n < N; ++n) {
    float s = 0.f;
    for (int k = threadIdx.x; k < K; k += 256) s += x[k] * W[(long)k * N + n];
    red[threadIdx.x] = s;
    __syncthreads();
    for (int st = 128; st > 0; st >>= 1) {
      if (threadIdx.x < st) red[threadIdx.x] += red[threadIdx.x + st];
      __syncthreads();
    }
    if (threadIdx.x == 0) {
      float v = red[0] + (bias ? bias[n] : 0.f);
      if (act == 1) v = sigmf(v);
      out[m * N + n] = v;
    }
    __syncthreads();
  }
}

// ---------------- l2norm in place over rows of 256 ----------------
__global__ __launch_bounds__(256)
void l2norm_inplace(float* __restrict__ x) {
  __shared__ float red[256];
  long row = blockIdx.x;
  float v = x[row * 256 + threadIdx.x];
  red[threadIdx.x] = v * v;
  __syncthreads();
  for (int st = 128; st > 0; st >>= 1) {
    if (threadIdx.x < st) red[threadIdx.x] += red[threadIdx.x + st];
    __syncthreads();
  }
  float inv = rsqrtf(red[0] + 1e-6f);
  x[row * 256 + threadIdx.x] = v * inv;
}

// ---------------- per-chunk: inv, u = inv@(v*beta), w = inv@(kn*beta), attn ----------------
// beta fused: kb row i = beta_i * kn row i; vb row t = beta_t * v row t.
__global__ __launch_bounds__(256)
void chunk_uw(const float* __restrict__ qn, const float* __restrict__ kn,
              const float* __restrict__ v, const float* __restrict__ beta,
              float* __restrict__ u, float* __restrict__ w, float* __restrict__ attn) {
  __shared__ float skT[256][33];   // kn chunk transposed: skT[d][row]
  __shared__ float sinv[32][33];
  __shared__ float sbeta[32];
  int blk = blockIdx.x;
  int ci = blk % NCH;
  int bh = blk / NCH;
  int h = bh % H_;
  int b = bh / H_;
  long base = ((long)b * L_ + (long)ci * CHUNKSZ) * D_ + h * DH;
  long brow = (long)b * L_ + (long)ci * CHUNKSZ;
  int tid = threadIdx.x;
  for (int i = tid; i < 32 * 256; i += 256) {
    int r = i >> 8, c = i & 255;
    skT[c][r] = kn[base + (long)r * D_ + c];
  }
  if (tid < 32) sbeta[tid] = beta[(brow + tid) * H_ + h];
  __syncthreads();
  int j = tid & 31, i0 = tid >> 5;
  // A = -(kb @ kn^T) * strict_lower ; kb_i . kn_j = beta_i * (kn_i . kn_j)
  for (int r = 0; r < 4; ++r) {
    int i = i0 + (r << 3);
    float acc = 0.f;
    for (int d = 0; d < 256; ++d) acc += skT[d][i] * skT[d][j];
    sinv[i][j] = (i > j) ? -acc * sbeta[i] : 0.f;
  }
  __syncthreads();
  // forward substitution (matches reference in-place row updates)
  for (int i = 1; i < 32; ++i) {
    float val = 0.f;
    if (tid < 32) {
      for (int t = 0; t < i; ++t) val += sinv[i][t] * sinv[t][tid];
    }
    __syncthreads();
    if (tid < 32) sinv[i][tid] += val;
    __syncthreads();
  }
  if (tid < 32) sinv[tid][tid] += 1.f;
  // attn = (qn @ kn^T) * lower_incl
  long attn_base = (long)blk * 1024;
  for (int r = 0; r < 4; ++r) {
    int i = i0 + (r << 3);
    const float* qrow = qn + base + (long)i * D_;
    float acc = 0.f;
    for (int d = 0; d < 256; ++d) acc += qrow[d] * skT[d][j];
    attn[attn_base + i * 32 + j] = (i >= j) ? acc : 0.f;
  }
  __syncthreads();
  // u = inv @ vb ; w = inv @ kb   (thread owns column c; kb from skT, vb from v*beta)
  int c = tid;
  float vt[32], kt[32];
#pragma unroll
  for (int t = 0; t < 32; ++t) {
    vt[t] = v[base + t * D_ + c] * sbeta[t];
    kt[t] = skT[c][t] * sbeta[t];
  }
#pragma unroll
  for (int i2 = 0; i2 < 32; ++i2) {
    float au = 0.f, aw = 0.f;
#pragma unroll
    for (int t = 0; t <= i2; ++t) {
      float f = sinv[i2][t];
      au += f * vt[t];
      aw += f * kt[t];
    }
    u[base + i2 * D_ + c] = au;
    w[base + i2 * D_ + c] = aw;
  }
}

// ---------------- sequential scan over chunks; block = (b,h,colgroup of 32) ----------------
// NOTE: `out` may alias `u` (u chunk is staged to LDS before the aliasing store;
// each block owns a disjoint 32-column group). No __restrict__ on u/out.
__global__ __launch_bounds__(256)
void delta_scan(const float* __restrict__ qn, const float* __restrict__ kn,
                const float* u, const float* __restrict__ w,
                const float* __restrict__ attn, float* out) {
  __shared__ float S[256][33];
  __shared__ float su[32][33];
  __shared__ float sattn[32][33];
  __shared__ float su2[32][33];
  int blk = blockIdx.x;          // bh*8 + cg
  int cg = blk & 7;
  int bh = blk >> 3;
  int h = bh % H_;
  int b = bh / H_;
  int tid = threadIdx.x;
  int cc = tid & 31, i0 = tid >> 5;
  int col0 = cg * 32;
  for (int i = tid; i < 256 * 32; i += 256) {
    int dd = i >> 5, c2 = i & 31;
    S[dd][c2] = 0.f;
  }
  __syncthreads();
  for (int ci = 0; ci < NCH; ++ci) {
    long base = ((long)b * L_ + (long)ci * CHUNKSZ) * D_ + h * DH;
    for (int i = tid; i < 32 * 32; i += 256) {
      int r = i >> 5, c = i & 31;
      su[r][c] = u[base + (long)r * D_ + col0 + c];
      sattn[r][c] = attn[((long)bh * NCH + ci) * 1024 + r * 32 + c];
    }
    __syncthreads();
    // u2 = su - w @ S_slice
    float u2r[4];
#pragma unroll
    for (int r = 0; r < 4; ++r) {
      int i = i0 + (r << 3);
      const float* wrow = w + base + (long)i * D_;
      float acc = 0.f;
      for (int d = 0; d < 256; ++d) acc += wrow[d] * S[d][cc];
      u2r[r] = su[i][cc] - acc;
    }
#pragma unroll
    for (int r = 0; r < 4; ++r) su2[i0 + (r << 3)][cc] = u2r[r];
    __syncthreads();
    // o = q @ S_slice + attn @ u2
#pragma unroll
    for (int r = 0; r < 4; ++r) {
      int i = i0 + (r << 3);
      const float* qrow = qn + base + (long)i * D_;
      float acc = 0.f;
      for (int d = 0; d < 256; ++d) acc += qrow[d] * S[d][cc];
      for (int t = 0; t < 32; ++t) acc += sattn[i][t] * su2[t][cc];  // masked entries are 0
      out[base + (long)i * D_ + col0 + cc] = acc;
    }
    __syncthreads();
    // S += k^T @ u2  (thread owns (d = i0+8r, cc))
    for (int r = 0; r < 32; ++r) {
      int d = i0 + (r << 3);
      float acc = 0.f;
      for (int t = 0; t < 32; ++t) acc += kn[base + (long)t * D_ + d] * su2[t][cc];
      S[d][cc] += acc;
    }
    __syncthreads();
  }
}

// ---------------- head stats: per (b,l): mean over H of [mean,var,absmean,l2] ----------------
__global__ __launch_bounds__(256)
void head_stats_k(const float* __restrict__ x, float* __restrict__ out,
                  int ostride, int ooff) {
  __shared__ float rs[256], rq[256], ra[256];
  long bl = blockIdx.x;
  int tid = threadIdx.x;
  float m_acc = 0, v_acc = 0, a_acc = 0, l_acc = 0;
  for (int h = 0; h < H_; ++h) {
    float v = x[bl * D_ + h * DH + tid];
    rs[tid] = v; rq[tid] = v * v; ra[tid] = fabsf(v);
    __syncthreads();
    for (int st = 128; st > 0; st >>= 1) {
      if (tid < st) { rs[tid] += rs[tid + st]; rq[tid] += rq[tid + st]; ra[tid] += ra[tid + st]; }
      __syncthreads();
    }
    if (tid == 0) {
      float mean = rs[0] / 256.f;
      m_acc += mean;
      v_acc += rq[0] / 256.f - mean * mean;
      a_acc += ra[0] / 256.f;
      l_acc += sqrtf(rq[0]);
    }
    __syncthreads();
  }
  if (tid == 0) {
    float* o = out + bl * ostride + ooff;
    o[0] = m_acc / H_; o[1] = v_acc / H_; o[2] = a_acc / H_; o[3] = l_acc / H_;
  }
}

// ---------------- g = gelu(g + bias + stats @ Wtail) ----------------
__global__ __launch_bounds__(256)
void tail_bias_gelu(float* __restrict__ g, const float* __restrict__ stats,
                    const float* __restrict__ Wt, const float* __restrict__ bias,
                    int N, int K2) {
  long idx = (long)blockIdx.x * 256 + threadIdx.x;
  if (idx >= (long)BL * N) return;
  int n = idx % N;
  long m = idx / N;
  float s = g[idx] + bias[n];
  for (int k = 0; k < K2; ++k) s += stats[m * K2 + k] * Wt[(long)k * N + n];
  g[idx] = geluf(s);
}

// ---------------- softmax with temp, clip, renorm ----------------
__global__ __launch_bounds__(256)
void softmax_p(const float* __restrict__ logits, const float* __restrict__ temp_in,
               float* __restrict__ p) {
  int bl = blockIdx.x * 256 + threadIdx.x;
  if (bl >= BL) return;
  float temp = log1pf(expf(temp_in[0]));
  float l0 = logits[bl * 4 + 0] / temp, l1 = logits[bl * 4 + 1] / temp;
  float l2 = logits[bl * 4 + 2] / temp, l3 = logits[bl * 4 + 3] / temp;
  float mx = fmaxf(fmaxf(l0, l1), fmaxf(l2, l3));
  float e0 = expf(l0 - mx), e1 = expf(l1 - mx), e2 = expf(l2 - mx), e3 = expf(l3 - mx);
  float s = e0 + e1 + e2 + e3;
  e0 /= s; e1 /= s; e2 /= s; e3 /= s;
  e0 = fmaxf(e0, 0.02f); e1 = fmaxf(e1, 0.02f); e2 = fmaxf(e2, 0.02f); e3 = fmaxf(e3, 0.02f);
  s = e0 + e1 + e2 + e3;
  p[bl * 4 + 0] = e0 / s; p[bl * 4 + 1] = e1 / s; p[bl * 4 + 2] = e2 / s; p[bl * 4 + 3] = e3 / s;
}

// ---------------- mixture combine + conv residual ----------------
__global__ __launch_bounds__(256)
void combine(const float* __restrict__ ls, const float* __restrict__ ll,
             const float* __restrict__ dd, const float* __restrict__ vd,
             const float* __restrict__ p, const float* __restrict__ resg,
             const float* __restrict__ crl, float* __restrict__ o) {
  int idx = blockIdx.x * 256 + threadIdx.x;
  if (idx >= BLD) return;
  int c = idx % D_;
  long bl = idx / D_;
  int h = c >> 8;
  const float* pp = p + bl * 4;
  float sgate = sigmf(crl[h]) * resg[bl * H_ + h];
  o[idx] = pp[0] * ls[idx] + pp[1] * ll[idx] + pp[2] * dd[idx] + pp[3] * vd[idx] + sgate * ls[idx];
}

// ---------------- o = rmsnorm(o * og) * norm_w  per (b,l,h) ----------------
__global__ __launch_bounds__(256)
void scale_rmsnorm(float* __restrict__ o, const float* __restrict__ og,
                   const float* __restrict__ nw) {
  __shared__ float red[256];
  long row = blockIdx.x;       // b*L*H + ...
  long bl = row >> 2;          // /H
  int tid = threadIdx.x;
  float v = o[row * 256 + tid] * og[bl];
  red[tid] = v * v;
  __syncthreads();
  for (int st = 128; st > 0; st >>= 1) {
    if (tid < st) red[tid] += red[tid + st];
    __syncthreads();
  }
  float scale = rsqrtf(red[0] / 256.f + 1e-5f);
  o[row * 256 + tid] = v * scale * nw[tid];
}

extern "C" void kernel_launch(void* const* d_in, const int* in_sizes, int n_in,
                              void* d_out, int out_size, void* d_ws, size_t ws_size,
                              hipStream_t stream) {
  const float* hs       = (const float*)d_in[0];
  const float* Wq       = (const float*)d_in[1];
  const float* Wk       = (const float*)d_in[2];
  const float* Wv       = (const float*)d_in[3];
  const float* Wb       = (const float*)d_in[4];
  const float* wq_conv  = (const float*)d_in[5];
  const float* wk_conv  = (const float*)d_in[6];
  const float* wv_conv  = (const float*)d_in[7];
  const float* fir_long = (const float*)d_in[8];
  const float* fir_short= (const float*)d_in[9];
  const float* Wg1      = (const float*)d_in[10];
  const float* bg1      = (const float*)d_in[11];
  const float* Wg2      = (const float*)d_in[12];
  const float* bg2      = (const float*)d_in[13];
  const float* logit_temp     = (const float*)d_in[14];
  const float* conv_res_logit = (const float*)d_in[15];
  const float* Wres     = (const float*)d_in[16];
  const float* bres     = (const float*)d_in[17];
  const float* Wog1     = (const float*)d_in[18];
  const float* bog1     = (const float*)d_in[19];
  const float* Wog2     = (const float*)d_in[20];
  const float* bog2     = (const float*)d_in[21];
  const float* norm_w   = (const float*)d_in[22];
  const float* Wo       = (const float*)d_in[23];
  float* out = (float*)d_out;
  float* ws = (float*)d_ws;

  // 5 big buffers (BLD floats each) + small region. Total ~166 MB.
  float* b0 = ws;             // qlin -> kn -> gate_hidden -> o_mix
  float* b1 = ws + 1L * BLD;  // klin -> v_in (v_direct)
  float* b2 = ws + 2L * BLD;  // vlin -> u -> delta_out -> og_hidden
  float* b3 = ws + 3L * BLD;  // qn -> local_long
  float* b4 = ws + 4L * BLD;  // w -> local_short
  float* sm = ws + 5L * BLD;
  float* beta    = sm;                    // BL*H
  float* resg    = beta + BL * H_;        // BL*H
  float* stats16 = resg + BL * H_;        // BL*16
  float* og8     = stats16 + BL * 16;     // BL*8
  float* logits  = og8 + BL * 8;          // BL*4
  float* pbuf    = logits + BL * 4;       // BL*4
  float* ogv     = pbuf + BL * 4;         // BL
  float* attn    = ogv + BL;              // B*H*NCH*1024 = 1M floats

  size_t needed = (5L * BLD + BL * (H_ + H_ + 16 + 8 + 4 + 4 + 1) + (long)B_ * H_ * NCH * 1024) * 4;
  if (ws_size < needed) return;  // fail gracefully rather than fault

  dim3 blk(256);
  // 1. projections: qlin->b0, klin->b1, vlin->b2
  gemm_f32<<<dim3(8, 64), blk, 0, stream>>>(hs, Wq, b0, BL, D_, D_);
  gemm_f32<<<dim3(8, 64), blk, 0, stream>>>(hs, Wk, b1, BL, D_, D_);
  gemm_f32<<<dim3(8, 64), blk, 0, stream>>>(hs, Wv, b2, BL, D_, D_);
  // 2. conv + silu: qn<-b0->b3 ; kn<-b1->b0 ; v<-b2->b1
  dwconv_k<<<BLD / 256, blk, 0, stream>>>(b0, wq_conv, b3, 4, 1);
  dwconv_k<<<BLD / 256, blk, 0, stream>>>(b1, wk_conv, b0, 4, 1);
  dwconv_k<<<BLD / 256, blk, 0, stream>>>(b2, wv_conv, b1, 4, 1);
  // 3. beta, res gate
  gemv_smallN<<<BL, blk, 0, stream>>>(hs, Wb, nullptr, beta, D_, H_, 1);
  gemv_smallN<<<BL, blk, 0, stream>>>(hs, Wres, bres, resg, D_, H_, 1);
  // 4. l2norm q (b3), k (b0) per (b,l,h)
  l2norm_inplace<<<BL * H_, blk, 0, stream>>>(b3);
  l2norm_inplace<<<BL * H_, blk, 0, stream>>>(b0);
  // 5. per-chunk inverse, u->b2, w->b4, attn (beta fused)
  chunk_uw<<<B_ * H_ * NCH, blk, 0, stream>>>(b3, b0, b1, beta, b2, b4, attn);
  // 6. sequential scan -> delta_out (in place over u, b2)
  delta_scan<<<B_ * H_ * 8, blk, 0, stream>>>(b3, b0, b2, b4, attn, b2);
  // 7. local convs from v (b1): long->b3 (qn dead), short->b4 (w dead)
  dwconv_k<<<BLD / 256, blk, 0, stream>>>(b1, fir_long, b3, 64, 0);
  dwconv_k<<<BLD / 256, blk, 0, stream>>>(b1, fir_short, b4, 5, 0);
  // 8. stats16: (local_short, local_long, delta_out, v_direct)
  head_stats_k<<<BL, blk, 0, stream>>>(b4, stats16, 16, 0);
  head_stats_k<<<BL, blk, 0, stream>>>(b3, stats16, 16, 4);
  head_stats_k<<<BL, blk, 0, stream>>>(b2, stats16, 16, 8);
  head_stats_k<<<BL, blk, 0, stream>>>(b1, stats16, 16, 12);
  // 9. gate hidden = gelu(hs@Wg1[:1024] + stats@Wg1[1024:] + bg1) -> b0 (kn dead)
  gemm_f32<<<dim3(8, 64), blk, 0, stream>>>(hs, Wg1, b0, BL, D_, D_);
  tail_bias_gelu<<<(BL * D_) / 256, blk, 0, stream>>>(b0, stats16, Wg1 + 1024L * 1024, bg1, D_, 16);
  // 10. logits, p
  gemv_smallN<<<BL, blk, 0, stream>>>(b0, Wg2, bg2, logits, D_, 4, 0);
  softmax_p<<<BL / 256, blk, 0, stream>>>(logits, logit_temp, pbuf);
  // 11. combine -> b0 (gate hidden dead)
  combine<<<BLD / 256, blk, 0, stream>>>(b4, b3, b2, b1, pbuf, resg, conv_res_logit, b0);
  // 12. og stats (o=b0, v=b1)
  head_stats_k<<<BL, blk, 0, stream>>>(b0, og8, 8, 0);
  head_stats_k<<<BL, blk, 0, stream>>>(b1, og8, 8, 4);
  // 13. output gate hidden -> b2 (delta_out dead)
  gemm_f32<<<dim3(4, 64), blk, 0, stream>>>(hs, Wog1, b2, BL, 512, D_);
  tail_bias_gelu<<<(BL * 512) / 256, blk, 0, stream>>>(b2, og8, Wog1 + 1024L * 512, bog1, 512, 8);
  gemv_smallN<<<BL, blk, 0, stream>>>(b2, Wog2, bog2, ogv, 512, 1, 1);
  // 14. scale by og + rmsnorm (in place on b0)
  scale_rmsnorm<<<BL * H_, blk, 0, stream>>>(b0, ogv, norm_w);
  // 15. final projection
  gemm_f32<<<dim3(8, 64), blk, 0, stream>>>(b0, Wo, out, BL, D_, D_);
}

// Round 3
// 6898.544 us; speedup vs baseline: 2.1102x; 2.1102x over previous
//
#include <hip/hip_runtime.h>
#include <math.h>

#define B_ 2
#define L_ 4096
#define D_ 1024
#define H_ 4
#define DH 256
#define CHUNKSZ 32
#define NCH (L_/CHUNKSZ)      // 128
#define BL (B_*L_)            // 8192
#define BLD (B_*L_*D_)        // 8388608

__device__ __forceinline__ float sigmf(float x) { return 1.f / (1.f + expf(-x)); }
__device__ __forceinline__ float geluf(float x) { return 0.5f * x * (1.f + erff(x * 0.70710678118654752f)); }

// ---------------- GEMM: C[M,N] = A[M,K] @ B[K,N], f32, 128x128 tile ----------------
__global__ __launch_bounds__(256)
void gemm_f32(const float* __restrict__ A, const float* __restrict__ Bm,
              float* __restrict__ C, int M, int N, int K) {
  __shared__ float As[8][132];   // As[k][r]
  __shared__ float Bs[8][132];   // Bs[k][c]
  int bm = blockIdx.y * 128, bn = blockIdx.x * 128;
  int tx = threadIdx.x & 15, ty = threadIdx.x >> 4;
  float acc[8][8] = {};
  for (int k0 = 0; k0 < K; k0 += 8) {
    for (int i = threadIdx.x; i < 1024; i += 256) {
      int r = i >> 3, c = i & 7;
      As[c][r] = A[(long)(bm + r) * K + k0 + c];
    }
    for (int i = threadIdx.x; i < 1024; i += 256) {
      int r = i >> 7, c = i & 127;
      Bs[r][c] = Bm[(long)(k0 + r) * N + bn + c];
    }
    __syncthreads();
#pragma unroll
    for (int kk = 0; kk < 8; ++kk) {
      float a[8], b[8];
#pragma unroll
      for (int i = 0; i < 8; ++i) a[i] = As[kk][ty * 8 + i];
#pragma unroll
      for (int j = 0; j < 8; ++j) b[j] = Bs[kk][tx * 8 + j];
#pragma unroll
      for (int i = 0; i < 8; ++i)
#pragma unroll
        for (int j = 0; j < 8; ++j) acc[i][j] += a[i] * b[j];
    }
    __syncthreads();
  }
  for (int i = 0; i < 8; ++i)
    for (int j = 0; j < 8; ++j)
      C[(long)(bm + ty * 8 + i) * N + bn + tx * 8 + j] = acc[i][j];
}

// ---------------- depthwise causal conv (+ optional silu) ----------------
__global__ __launch_bounds__(256)
void dwconv_k(const float* __restrict__ x, const float* __restrict__ w,
              float* __restrict__ y, int K, int do_silu) {
  int idx = blockIdx.x * 256 + threadIdx.x;
  if (idx >= BLD) return;
  int c = idx % D_;
  int l = (idx / D_) % L_;
  const float* wc = w + c * K;
  float acc = 0.f;
  for (int j = 0; j < K; ++j) {
    int ll = l - (K - 1) + j;
    if (ll >= 0) acc += wc[j] * x[idx + (ll - l) * D_];
  }
  if (do_silu) acc = acc * sigmf(acc);
  y[idx] = acc;
}

// ---------------- small-N GEMV ----------------
__global__ __launch_bounds__(256)
void gemv_smallN(const float* __restrict__ X, const float* __restrict__ W,
                 const float* __restrict__ bias, float* __restrict__ out,
                 int K, int N, int act) {
  __shared__ float red[256];
  long m = blockIdx.x;
  const float* x = X + m * K;
  for (int n = 0; n < N; ++n) {
    float s = 0.f;
    for (int k = threadIdx.x; k < K; k += 256) s += x[k] * W[(long)k * N + n];
    red[threadIdx.x] = s;
    __syncthreads();
    for (int st = 128; st > 0; st >>= 1) {
      if (threadIdx.x < st) red[threadIdx.x] += red[threadIdx.x + st];
      __syncthreads();
    }
    if (threadIdx.x == 0) {
      float v = red[0] + (bias ? bias[n] : 0.f);
      if (act == 1) v = sigmf(v);
      out[m * N + n] = v;
    }
    __syncthreads();
  }
}

// ---------------- l2norm in place over rows of 256 ----------------
__global__ __launch_bounds__(256)
void l2norm_inplace(float* __restrict__ x) {
  __shared__ float red[256];
  long row = blockIdx.x;
  float v = x[row * 256 + threadIdx.x];
  red[threadIdx.x] = v * v;
  __syncthreads();
  for (int st = 128; st > 0; st >>= 1) {
    if (threadIdx.x < st) red[threadIdx.x] += red[threadIdx.x + st];
    __syncthreads();
  }
  float inv = rsqrtf(red[0] + 1e-6f);
  x[row * 256 + threadIdx.x] = v * inv;
}

// ---------------- per-chunk: inv, u = inv@(v*beta), w = inv@(kn*beta), attn ----------------
__global__ __launch_bounds__(256)
void chunk_uw(const float* __restrict__ qn, const float* __restrict__ kn,
              const float* __restrict__ v, const float* __restrict__ beta,
              float* __restrict__ u, float* __restrict__ w, float* __restrict__ attn) {
  __shared__ float skT[256][33];   // kn chunk transposed: skT[d][row]
  __shared__ float sinv[32][33];
  __shared__ float sbeta[32];
  int blk = blockIdx.x;
  int ci = blk % NCH;
  int bh = blk / NCH;
  int h = bh % H_;
  int b = bh / H_;
  long base = ((long)b * L_ + (long)ci * CHUNKSZ) * D_ + h * DH;
  long brow = (long)b * L_ + (long)ci * CHUNKSZ;
  int tid = threadIdx.x;
  for (int i = tid; i < 32 * 256; i += 256) {
    int r = i >> 8, c = i & 255;
    skT[c][r] = kn[base + (long)r * D_ + c];
  }
  if (tid < 32) sbeta[tid] = beta[(brow + tid) * H_ + h];
  __syncthreads();
  int j = tid & 31, i0 = tid >> 5;
  for (int r = 0; r < 4; ++r) {
    int i = i0 + (r << 3);
    float acc = 0.f;
    for (int d = 0; d < 256; ++d) acc += skT[d][i] * skT[d][j];
    sinv[i][j] = (i > j) ? -acc * sbeta[i] : 0.f;
  }
  __syncthreads();
  for (int i = 1; i < 32; ++i) {
    float val = 0.f;
    if (tid < 32) {
      for (int t = 0; t < i; ++t) val += sinv[i][t] * sinv[t][tid];
    }
    __syncthreads();
    if (tid < 32) sinv[i][tid] += val;
    __syncthreads();
  }
  if (tid < 32) sinv[tid][tid] += 1.f;
  long attn_base = (long)blk * 1024;
  for (int r = 0; r < 4; ++r) {
    int i = i0 + (r << 3);
    const float* qrow = qn + base + (long)i * D_;
    float acc = 0.f;
    for (int d = 0; d < 256; ++d) acc += qrow[d] * skT[d][j];
    attn[attn_base + i * 32 + j] = (i >= j) ? acc : 0.f;
  }
  __syncthreads();
  int c = tid;
  float vt[32], kt[32];
#pragma unroll
  for (int t = 0; t < 32; ++t) {
    vt[t] = v[base + t * D_ + c] * sbeta[t];
    kt[t] = skT[c][t] * sbeta[t];
  }
#pragma unroll
  for (int i2 = 0; i2 < 32; ++i2) {
    float au = 0.f, aw = 0.f;
#pragma unroll
    for (int t = 0; t <= i2; ++t) {
      float f = sinv[i2][t];
      au += f * vt[t];
      aw += f * kt[t];
    }
    u[base + i2 * D_ + c] = au;
    w[base + i2 * D_ + c] = aw;
  }
}

// ---------------- sequential scan over chunks; block = (b,h,colgroup of 32) ----------------
// S column-major float4 in LDS with XOR swizzle; q/w/k tiles staged as float4.
// `out` may alias `u` (u chunk staged to LDS before the aliasing store; blocks own
// disjoint column groups). No __restrict__ on u/out.
__global__ __launch_bounds__(256)
void delta_scan(const float* __restrict__ qn, const float* __restrict__ kn,
                const float* u, const float* __restrict__ w,
                const float* __restrict__ attn, float* out) {
  __shared__ float4 sS[2048];   // S[d][col0+c] at sS[c*64 + (d4 ^ (c&7))], d=4*d4..
  __shared__ float4 sq[2048];   // sq[i*64 + d4]
  __shared__ float4 sw[2048];
  __shared__ float4 sk[2048];
  __shared__ float  su[32 * 36];
  __shared__ float  su2[32 * 36];
  __shared__ float  sat[32 * 36];
  int blk = blockIdx.x;          // bh*8 + cg
  int cg = blk & 7;
  int bh = blk >> 3;
  int h = bh & 3;
  int b = bh >> 2;
  int tid = threadIdx.x;
  int c = tid & 31, rg = tid >> 5;   // 8 row-groups x 4 rows
  int i0 = rg * 4;
  int col0 = cg * 32;
  int swz = c & 7;
#pragma unroll
  for (int i = 0; i < 8; ++i) sS[tid + i * 256] = make_float4(0.f, 0.f, 0.f, 0.f);
  __syncthreads();
  for (int ci = 0; ci < NCH; ++ci) {
    long base = ((long)b * L_ + (long)ci * CHUNKSZ) * D_ + h * DH;
    // ---- stage q,w,k tiles (32 rows x 64 float4 each) ----
#pragma unroll
    for (int jj = 0; jj < 8; ++jj) {
      int idx = tid + jj * 256;
      int r = idx >> 6, d4 = idx & 63;
      sq[idx] = reinterpret_cast<const float4*>(qn + base + (long)r * D_)[d4];
      sw[idx] = reinterpret_cast<const float4*>(w  + base + (long)r * D_)[d4];
      sk[idx] = reinterpret_cast<const float4*>(kn + base + (long)r * D_)[d4];
    }
    {
      int r = tid >> 3, c4 = tid & 7;
      float4 uv = reinterpret_cast<const float4*>(u + base + (long)r * D_ + col0)[c4];
      *reinterpret_cast<float4*>(&su[r * 36 + c4 * 4]) = uv;
      float4 av = reinterpret_cast<const float4*>(attn + ((long)bh * NCH + ci) * 1024 + r * 32)[c4];
      *reinterpret_cast<float4*>(&sat[r * 36 + c4 * 4]) = av;
    }
    __syncthreads();
    // ---- fused w@S and q@S over this column group ----
    float aw0 = 0.f, aw1 = 0.f, aw2 = 0.f, aw3 = 0.f;
    float aq0 = 0.f, aq1 = 0.f, aq2 = 0.f, aq3 = 0.f;
#pragma unroll 8
    for (int d4 = 0; d4 < 64; ++d4) {
      float4 s = sS[c * 64 + (d4 ^ swz)];
      float4 w0 = sw[(i0 + 0) * 64 + d4];
      float4 w1 = sw[(i0 + 1) * 64 + d4];
      float4 w2 = sw[(i0 + 2) * 64 + d4];
      float4 w3 = sw[(i0 + 3) * 64 + d4];
      aw0 = fmaf(w0.x, s.x, fmaf(w0.y, s.y, fmaf(w0.z, s.z, fmaf(w0.w, s.w, aw0))));
      aw1 = fmaf(w1.x, s.x, fmaf(w1.y, s.y, fmaf(w1.z, s.z, fmaf(w1.w, s.w, aw1))));
      aw2 = fmaf(w2.x, s.x, fmaf(w2.y, s.y, fmaf(w2.z, s.z, fmaf(w2.w, s.w, aw2))));
      aw3 = fmaf(w3.x, s.x, fmaf(w3.y, s.y, fmaf(w3.z, s.z, fmaf(w3.w, s.w, aw3))));
      float4 q0 = sq[(i0 + 0) * 64 + d4];
      float4 q1 = sq[(i0 + 1) * 64 + d4];
      float4 q2 = sq[(i0 + 2) * 64 + d4];
      float4 q3 = sq[(i0 + 3) * 64 + d4];
      aq0 = fmaf(q0.x, s.x, fmaf(q0.y, s.y, fmaf(q0.z, s.z, fmaf(q0.w, s.w, aq0))));
      aq1 = fmaf(q1.x, s.x, fmaf(q1.y, s.y, fmaf(q1.z, s.z, fmaf(q1.w, s.w, aq1))));
      aq2 = fmaf(q2.x, s.x, fmaf(q2.y, s.y, fmaf(q2.z, s.z, fmaf(q2.w, s.w, aq2))));
      aq3 = fmaf(q3.x, s.x, fmaf(q3.y, s.y, fmaf(q3.z, s.z, fmaf(q3.w, s.w, aq3))));
    }
    su2[(i0 + 0) * 36 + c] = su[(i0 + 0) * 36 + c] - aw0;
    su2[(i0 + 1) * 36 + c] = su[(i0 + 1) * 36 + c] - aw1;
    su2[(i0 + 2) * 36 + c] = su[(i0 + 2) * 36 + c] - aw2;
    su2[(i0 + 3) * 36 + c] = su[(i0 + 3) * 36 + c] - aw3;
    __syncthreads();   // su2 ready; everyone done reading sS
    // ---- out = q@S + attn@u2 ----
    float o0 = aq0, o1 = aq1, o2 = aq2, o3 = aq3;
#pragma unroll
    for (int t = 0; t < 32; ++t) {
      float uv = su2[t * 36 + c];
      o0 = fmaf(sat[(i0 + 0) * 36 + t], uv, o0);
      o1 = fmaf(sat[(i0 + 1) * 36 + t], uv, o1);
      o2 = fmaf(sat[(i0 + 2) * 36 + t], uv, o2);
      o3 = fmaf(sat[(i0 + 3) * 36 + t], uv, o3);
    }
    out[base + (long)(i0 + 0) * D_ + col0 + c] = o0;
    out[base + (long)(i0 + 1) * D_ + col0 + c] = o1;
    out[base + (long)(i0 + 2) * D_ + col0 + c] = o2;
    out[base + (long)(i0 + 3) * D_ + col0 + c] = o3;
    // ---- S += k^T @ u2 : thread owns (col c, d4 in [rg*8, rg*8+8)) ----
    float u2c[32];
#pragma unroll
    for (int t = 0; t < 32; ++t) u2c[t] = su2[t * 36 + c];
#pragma unroll 4
    for (int j = 0; j < 8; ++j) {
      int d4 = rg * 8 + j;
      int phys = c * 64 + (d4 ^ swz);
      float4 s = sS[phys];
#pragma unroll
      for (int t = 0; t < 32; ++t) {
        float4 kv = sk[t * 64 + d4];
        s.x = fmaf(kv.x, u2c[t], s.x);
        s.y = fmaf(kv.y, u2c[t], s.y);
        s.z = fmaf(kv.z, u2c[t], s.z);
        s.w = fmaf(kv.w, u2c[t], s.w);
      }
      sS[phys] = s;
    }
    __syncthreads();   // S updated before next chunk's staging/compute
  }
}

// ---------------- head stats ----------------
__global__ __launch_bounds__(256)
void head_stats_k(const float* __restrict__ x, float* __restrict__ out,
                  int ostride, int ooff) {
  __shared__ float rs[256], rq[256], ra[256];
  long bl = blockIdx.x;
  int tid = threadIdx.x;
  float m_acc = 0, v_acc = 0, a_acc = 0, l_acc = 0;
  for (int h = 0; h < H_; ++h) {
    float v = x[bl * D_ + h * DH + tid];
    rs[tid] = v; rq[tid] = v * v; ra[tid] = fabsf(v);
    __syncthreads();
    for (int st = 128; st > 0; st >>= 1) {
      if (tid < st) { rs[tid] += rs[tid + st]; rq[tid] += rq[tid + st]; ra[tid] += ra[tid + st]; }
      __syncthreads();
    }
    if (tid == 0) {
      float mean = rs[0] / 256.f;
      m_acc += mean;
      v_acc += rq[0] / 256.f - mean * mean;
      a_acc += ra[0] / 256.f;
      l_acc += sqrtf(rq[0]);
    }
    __syncthreads();
  }
  if (tid == 0) {
    float* o = out + bl * ostride + ooff;
    o[0] = m_acc / H_; o[1] = v_acc / H_; o[2] = a_acc / H_; o[3] = l_acc / H_;
  }
}

// ---------------- g = gelu(g + bias + stats @ Wtail) ----------------
__global__ __launch_bounds__(256)
void tail_bias_gelu(float* __restrict__ g, const float* __restrict__ stats,
                    const float* __restrict__ Wt, const float* __restrict__ bias,
                    int N, int K2) {
  long idx = (long)blockIdx.x * 256 + threadIdx.x;
  if (idx >= (long)BL * N) return;
  int n = idx % N;
  long m = idx / N;
  float s = g[idx] + bias[n];
  for (int k = 0; k < K2; ++k) s += stats[m * K2 + k] * Wt[(long)k * N + n];
  g[idx] = geluf(s);
}

// ---------------- softmax with temp, clip, renorm ----------------
__global__ __launch_bounds__(256)
void softmax_p(const float* __restrict__ logits, const float* __restrict__ temp_in,
               float* __restrict__ p) {
  int bl = blockIdx.x * 256 + threadIdx.x;
  if (bl >= BL) return;
  float temp = log1pf(expf(temp_in[0]));
  float l0 = logits[bl * 4 + 0] / temp, l1 = logits[bl * 4 + 1] / temp;
  float l2 = logits[bl * 4 + 2] / temp, l3 = logits[bl * 4 + 3] / temp;
  float mx = fmaxf(fmaxf(l0, l1), fmaxf(l2, l3));
  float e0 = expf(l0 - mx), e1 = expf(l1 - mx), e2 = expf(l2 - mx), e3 = expf(l3 - mx);
  float s = e0 + e1 + e2 + e3;
  e0 /= s; e1 /= s; e2 /= s; e3 /= s;
  e0 = fmaxf(e0, 0.02f); e1 = fmaxf(e1, 0.02f); e2 = fmaxf(e2, 0.02f); e3 = fmaxf(e3, 0.02f);
  s = e0 + e1 + e2 + e3;
  p[bl * 4 + 0] = e0 / s; p[bl * 4 + 1] = e1 / s; p[bl * 4 + 2] = e2 / s; p[bl * 4 + 3] = e3 / s;
}

// ---------------- mixture combine + conv residual ----------------
__global__ __launch_bounds__(256)
void combine(const float* __restrict__ ls, const float* __restrict__ ll,
             const float* __restrict__ dd, const float* __restrict__ vd,
             const float* __restrict__ p, const float* __restrict__ resg,
             const float* __restrict__ crl, float* __restrict__ o) {
  int idx = blockIdx.x * 256 + threadIdx.x;
  if (idx >= BLD) return;
  int c = idx % D_;
  long bl = idx / D_;
  int h = c >> 8;
  const float* pp = p + bl * 4;
  float sgate = sigmf(crl[h]) * resg[bl * H_ + h];
  o[idx] = pp[0] * ls[idx] + pp[1] * ll[idx] + pp[2] * dd[idx] + pp[3] * vd[idx] + sgate * ls[idx];
}

// ---------------- o = rmsnorm(o * og) * norm_w  per (b,l,h) ----------------
__global__ __launch_bounds__(256)
void scale_rmsnorm(float* __restrict__ o, const float* __restrict__ og,
                   const float* __restrict__ nw) {
  __shared__ float red[256];
  long row = blockIdx.x;
  long bl = row >> 2;
  int tid = threadIdx.x;
  float v = o[row * 256 + tid] * og[bl];
  red[tid] = v * v;
  __syncthreads();
  for (int st = 128; st > 0; st >>= 1) {
    if (tid < st) red[tid] += red[tid + st];
    __syncthreads();
  }
  float scale = rsqrtf(red[0] / 256.f + 1e-5f);
  o[row * 256 + tid] = v * scale * nw[tid];
}

extern "C" void kernel_launch(void* const* d_in, const int* in_sizes, int n_in,
                              void* d_out, int out_size, void* d_ws, size_t ws_size,
                              hipStream_t stream) {
  const float* hs       = (const float*)d_in[0];
  const float* Wq       = (const float*)d_in[1];
  const float* Wk       = (const float*)d_in[2];
  const float* Wv       = (const float*)d_in[3];
  const float* Wb       = (const float*)d_in[4];
  const float* wq_conv  = (const float*)d_in[5];
  const float* wk_conv  = (const float*)d_in[6];
  const float* wv_conv  = (const float*)d_in[7];
  const float* fir_long = (const float*)d_in[8];
  const float* fir_short= (const float*)d_in[9];
  const float* Wg1      = (const float*)d_in[10];
  const float* bg1      = (const float*)d_in[11];
  const float* Wg2      = (const float*)d_in[12];
  const float* bg2      = (const float*)d_in[13];
  const float* logit_temp     = (const float*)d_in[14];
  const float* conv_res_logit = (const float*)d_in[15];
  const float* Wres     = (const float*)d_in[16];
  const float* bres     = (const float*)d_in[17];
  const float* Wog1     = (const float*)d_in[18];
  const float* bog1     = (const float*)d_in[19];
  const float* Wog2     = (const float*)d_in[20];
  const float* bog2     = (const float*)d_in[21];
  const float* norm_w   = (const float*)d_in[22];
  const float* Wo       = (const float*)d_in[23];
  float* out = (float*)d_out;
  float* ws = (float*)d_ws;

  float* b0 = ws;             // qlin -> kn -> gate_hidden -> o_mix
  float* b1 = ws + 1L * BLD;  // klin -> v_in (v_direct)
  float* b2 = ws + 2L * BLD;  // vlin -> u -> delta_out -> og_hidden
  float* b3 = ws + 3L * BLD;  // qn -> local_long
  float* b4 = ws + 4L * BLD;  // w -> local_short
  float* sm = ws + 5L * BLD;
  float* beta    = sm;
  float* resg    = beta + BL * H_;
  float* stats16 = resg + BL * H_;
  float* og8     = stats16 + BL * 16;
  float* logits  = og8 + BL * 8;
  float* pbuf    = logits + BL * 4;
  float* ogv     = pbuf + BL * 4;
  float* attn    = ogv + BL;

  size_t needed = (5L * BLD + BL * (H_ + H_ + 16 + 8 + 4 + 4 + 1) + (long)B_ * H_ * NCH * 1024) * 4;
  if (ws_size < needed) return;

  dim3 blk(256);
  gemm_f32<<<dim3(8, 64), blk, 0, stream>>>(hs, Wq, b0, BL, D_, D_);
  gemm_f32<<<dim3(8, 64), blk, 0, stream>>>(hs, Wk, b1, BL, D_, D_);
  gemm_f32<<<dim3(8, 64), blk, 0, stream>>>(hs, Wv, b2, BL, D_, D_);
  dwconv_k<<<BLD / 256, blk, 0, stream>>>(b0, wq_conv, b3, 4, 1);
  dwconv_k<<<BLD / 256, blk, 0, stream>>>(b1, wk_conv, b0, 4, 1);
  dwconv_k<<<BLD / 256, blk, 0, stream>>>(b2, wv_conv, b1, 4, 1);
  gemv_smallN<<<BL, blk, 0, stream>>>(hs, Wb, nullptr, beta, D_, H_, 1);
  gemv_smallN<<<BL, blk, 0, stream>>>(hs, Wres, bres, resg, D_, H_, 1);
  l2norm_inplace<<<BL * H_, blk, 0, stream>>>(b3);
  l2norm_inplace<<<BL * H_, blk, 0, stream>>>(b0);
  chunk_uw<<<B_ * H_ * NCH, blk, 0, stream>>>(b3, b0, b1, beta, b2, b4, attn);
  delta_scan<<<B_ * H_ * 8, blk, 0, stream>>>(b3, b0, b2, b4, attn, b2);
  dwconv_k<<<BLD / 256, blk, 0, stream>>>(b1, fir_long, b3, 64, 0);
  dwconv_k<<<BLD / 256, blk, 0, stream>>>(b1, fir_short, b4, 5, 0);
  head_stats_k<<<BL, blk, 0, stream>>>(b4, stats16, 16, 0);
  head_stats_k<<<BL, blk, 0, stream>>>(b3, stats16, 16, 4);
  head_stats_k<<<BL, blk, 0, stream>>>(b2, stats16, 16, 8);
  head_stats_k<<<BL, blk, 0, stream>>>(b1, stats16, 16, 12);
  gemm_f32<<<dim3(8, 64), blk, 0, stream>>>(hs, Wg1, b0, BL, D_, D_);
  tail_bias_gelu<<<(BL * D_) / 256, blk, 0, stream>>>(b0, stats16, Wg1 + 1024L * 1024, bg1, D_, 16);
  gemv_smallN<<<BL, blk, 0, stream>>>(b0, Wg2, bg2, logits, D_, 4, 0);
  softmax_p<<<BL / 256, blk, 0, stream>>>(logits, logit_temp, pbuf);
  combine<<<BLD / 256, blk, 0, stream>>>(b4, b3, b2, b1, pbuf, resg, conv_res_logit, b0);
  head_stats_k<<<BL, blk, 0, stream>>>(b0, og8, 8, 0);
  head_stats_k<<<BL, blk, 0, stream>>>(b1, og8, 8, 4);
  gemm_f32<<<dim3(4, 64), blk, 0, stream>>>(hs, Wog1, b2, BL, 512, D_);
  tail_bias_gelu<<<(BL * 512) / 256, blk, 0, stream>>>(b2, og8, Wog1 + 1024L * 512, bog1, 512, 8);
  gemv_smallN<<<BL, blk, 0, stream>>>(b2, Wog2, bog2, ogv, 512, 1, 1);
  scale_rmsnorm<<<BL * H_, blk, 0, stream>>>(b0, ogv, norm_w);
  gemm_f32<<<dim3(8, 64), blk, 0, stream>>>(b0, Wo, out, BL, D_, D_);
}

// Round 4
// 4771.999 us; speedup vs baseline: 3.0506x; 1.4456x over previous
//
#include <hip/hip_runtime.h>
#include <math.h>

#define B_ 2
#define L_ 4096
#define D_ 1024
#define H_ 4
#define DH 256
#define CHUNKSZ 32
#define NCH (L_/CHUNKSZ)      // 128
#define BL (B_*L_)            // 8192
#define BLD (B_*L_*D_)        // 8388608

typedef __attribute__((ext_vector_type(8))) short bf16x8;
typedef __attribute__((ext_vector_type(4))) float f32x4;

__device__ __forceinline__ float sigmf(float x) { return 1.f / (1.f + expf(-x)); }
__device__ __forceinline__ float geluf(float x) { return 0.5f * x * (1.f + erff(x * 0.70710678118654752f)); }
__device__ __forceinline__ unsigned short f2bf(float f) {
  unsigned int u = __float_as_uint(f);
  unsigned int r = (u + 0x7FFFu + ((u >> 16) & 1u)) >> 16;
  return (unsigned short)r;
}

// ---------------- f32 -> bf16 elementwise (n multiple of 4) ----------------
__global__ __launch_bounds__(256)
void cvt_bf16(const float* __restrict__ x, unsigned short* __restrict__ y, long n) {
  long i = ((long)blockIdx.x * 256 + threadIdx.x) * 4;
  if (i >= n) return;
  float4 v = *reinterpret_cast<const float4*>(&x[i]);
  ushort4 o;
  o.x = f2bf(v.x); o.y = f2bf(v.y); o.z = f2bf(v.z); o.w = f2bf(v.w);
  *reinterpret_cast<ushort4*>(&y[i]) = o;
}

// ---------------- W[k][n] f32 -> Wt[n][k] bf16 (32x32 tiles) ----------------
__global__ __launch_bounds__(256)
void wconv_t(const float* __restrict__ W, unsigned short* __restrict__ Wt, int N) {
  __shared__ float tile[32][33];
  int kb = blockIdx.y * 32, nb = blockIdx.x * 32;
  int tx = threadIdx.x & 31, ty = threadIdx.x >> 5;   // 8 rows per pass
  for (int i = 0; i < 32; i += 8)
    tile[ty + i][tx] = W[(long)(kb + ty + i) * N + nb + tx];
  __syncthreads();
  for (int i = 0; i < 32; i += 8)
    Wt[(long)(nb + ty + i) * 1024 + kb + tx] = f2bf(tile[tx][ty + i]);
}

// ---------------- bf16 MFMA GEMM: C[8192][N] = A[8192][1024] @ Bt[N][1024]^T ----------------
// 128x128 tile, BK=32, 4 waves (2x2 quadrants), mfma_f32_16x16x32_bf16.
__global__ __launch_bounds__(256)
void gemm_bf16(const unsigned short* __restrict__ A, const unsigned short* __restrict__ Bt,
               float* __restrict__ C, int N) {
  __shared__ unsigned short Al[128 * 32];
  __shared__ unsigned short Bl[128 * 32];
  const int K = 1024;
  int bm = blockIdx.y * 128, bn = blockIdx.x * 128;
  int tid = threadIdx.x;
  int lane = tid & 63, wid = tid >> 6;
  int wr = wid >> 1, wc = wid & 1;
  int l15 = lane & 15, l4 = lane >> 4;
  f32x4 acc[4][4];
#pragma unroll
  for (int i = 0; i < 4; ++i)
#pragma unroll
    for (int j = 0; j < 4; ++j) { acc[i][j].x = 0.f; acc[i][j].y = 0.f; acc[i][j].z = 0.f; acc[i][j].w = 0.f; }
  for (int k0 = 0; k0 < K; k0 += 32) {
    __syncthreads();
#pragma unroll
    for (int i = 0; i < 2; ++i) {
      int idx = tid + i * 256;
      int r = idx >> 2, sl = idx & 3;
      int s = sl ^ ((r >> 1) & 3);
      uint4 av = *reinterpret_cast<const uint4*>(&A[(long)(bm + r) * K + k0 + sl * 8]);
      *reinterpret_cast<uint4*>(&Al[r * 32 + s * 8]) = av;
      uint4 bv = *reinterpret_cast<const uint4*>(&Bt[(long)(bn + r) * K + k0 + sl * 8]);
      *reinterpret_cast<uint4*>(&Bl[r * 32 + s * 8]) = bv;
    }
    __syncthreads();
    bf16x8 af[4], bfr[4];
#pragma unroll
    for (int fi = 0; fi < 4; ++fi) {
      int r = wr * 64 + fi * 16 + l15;
      af[fi] = *reinterpret_cast<const bf16x8*>(&Al[r * 32 + (l4 ^ ((r >> 1) & 3)) * 8]);
    }
#pragma unroll
    for (int fj = 0; fj < 4; ++fj) {
      int r = wc * 64 + fj * 16 + l15;
      bfr[fj] = *reinterpret_cast<const bf16x8*>(&Bl[r * 32 + (l4 ^ ((r >> 1) & 3)) * 8]);
    }
#pragma unroll
    for (int fi = 0; fi < 4; ++fi)
#pragma unroll
      for (int fj = 0; fj < 4; ++fj)
        acc[fi][fj] = __builtin_amdgcn_mfma_f32_16x16x32_bf16(af[fi], bfr[fj], acc[fi][fj], 0, 0, 0);
  }
#pragma unroll
  for (int fi = 0; fi < 4; ++fi) {
    int rb = bm + wr * 64 + fi * 16 + l4 * 4;
#pragma unroll
    for (int fj = 0; fj < 4; ++fj) {
      int cb = bn + wc * 64 + fj * 16 + l15;
#pragma unroll
      for (int j = 0; j < 4; ++j)
        C[(long)(rb + j) * N + cb] = acc[fi][fj][j];
    }
  }
}

// ---------------- depthwise causal conv (+ optional silu) ----------------
__global__ __launch_bounds__(256)
void dwconv_k(const float* __restrict__ x, const float* __restrict__ w,
              float* __restrict__ y, int K, int do_silu) {
  int idx = blockIdx.x * 256 + threadIdx.x;
  if (idx >= BLD) return;
  int c = idx % D_;
  int l = (idx / D_) % L_;
  const float* wc = w + c * K;
  float acc = 0.f;
  for (int j = 0; j < K; ++j) {
    int ll = l - (K - 1) + j;
    if (ll >= 0) acc += wc[j] * x[idx + (ll - l) * D_];
  }
  if (do_silu) acc = acc * sigmf(acc);
  y[idx] = acc;
}

// ---------------- small-N GEMV ----------------
__global__ __launch_bounds__(256)
void gemv_smallN(const float* __restrict__ X, const float* __restrict__ W,
                 const float* __restrict__ bias, float* __restrict__ out,
                 int K, int N, int act) {
  __shared__ float red[256];
  long m = blockIdx.x;
  const float* x = X + m * K;
  for (int n = 0; n < N; ++n) {
    float s = 0.f;
    for (int k = threadIdx.x; k < K; k += 256) s += x[k] * W[(long)k * N + n];
    red[threadIdx.x] = s;
    __syncthreads();
    for (int st = 128; st > 0; st >>= 1) {
      if (threadIdx.x < st) red[threadIdx.x] += red[threadIdx.x + st];
      __syncthreads();
    }
    if (threadIdx.x == 0) {
      float v = red[0] + (bias ? bias[n] : 0.f);
      if (act == 1) v = sigmf(v);
      out[m * N + n] = v;
    }
    __syncthreads();
  }
}

// ---------------- l2norm in place over rows of 256 ----------------
__global__ __launch_bounds__(256)
void l2norm_inplace(float* __restrict__ x) {
  __shared__ float red[256];
  long row = blockIdx.x;
  float v = x[row * 256 + threadIdx.x];
  red[threadIdx.x] = v * v;
  __syncthreads();
  for (int st = 128; st > 0; st >>= 1) {
    if (threadIdx.x < st) red[threadIdx.x] += red[threadIdx.x + st];
    __syncthreads();
  }
  float inv = rsqrtf(red[0] + 1e-6f);
  x[row * 256 + threadIdx.x] = v * inv;
}

// ---------------- per-chunk: inv, u = inv@(v*beta), w = inv@(kn*beta), attn ----------------
__global__ __launch_bounds__(256)
void chunk_uw(const float* __restrict__ qn, const float* __restrict__ kn,
              const float* __restrict__ v, const float* __restrict__ beta,
              float* __restrict__ u, float* __restrict__ w, float* __restrict__ attn) {
  __shared__ float skT[256][33];
  __shared__ float sinv[32][33];
  __shared__ float sbeta[32];
  int blk = blockIdx.x;
  int ci = blk % NCH;
  int bh = blk / NCH;
  int h = bh % H_;
  int b = bh / H_;
  long base = ((long)b * L_ + (long)ci * CHUNKSZ) * D_ + h * DH;
  long brow = (long)b * L_ + (long)ci * CHUNKSZ;
  int tid = threadIdx.x;
  for (int i = tid; i < 32 * 256; i += 256) {
    int r = i >> 8, c = i & 255;
    skT[c][r] = kn[base + (long)r * D_ + c];
  }
  if (tid < 32) sbeta[tid] = beta[(brow + tid) * H_ + h];
  __syncthreads();
  int j = tid & 31, i0 = tid >> 5;
  for (int r = 0; r < 4; ++r) {
    int i = i0 + (r << 3);
    float acc = 0.f;
    for (int d = 0; d < 256; ++d) acc += skT[d][i] * skT[d][j];
    sinv[i][j] = (i > j) ? -acc * sbeta[i] : 0.f;
  }
  __syncthreads();
  for (int i = 1; i < 32; ++i) {
    float val = 0.f;
    if (tid < 32) {
      for (int t = 0; t < i; ++t) val += sinv[i][t] * sinv[t][tid];
    }
    __syncthreads();
    if (tid < 32) sinv[i][tid] += val;
    __syncthreads();
  }
  if (tid < 32) sinv[tid][tid] += 1.f;
  long attn_base = (long)blk * 1024;
  for (int r = 0; r < 4; ++r) {
    int i = i0 + (r << 3);
    const float* qrow = qn + base + (long)i * D_;
    float acc = 0.f;
    for (int d = 0; d < 256; ++d) acc += qrow[d] * skT[d][j];
    attn[attn_base + i * 32 + j] = (i >= j) ? acc : 0.f;
  }
  __syncthreads();
  int c = tid;
  float vt[32], kt[32];
#pragma unroll
  for (int t = 0; t < 32; ++t) {
    vt[t] = v[base + t * D_ + c] * sbeta[t];
    kt[t] = skT[c][t] * sbeta[t];
  }
#pragma unroll
  for (int i2 = 0; i2 < 32; ++i2) {
    float au = 0.f, aw = 0.f;
#pragma unroll
    for (int t = 0; t <= i2; ++t) {
      float f = sinv[i2][t];
      au += f * vt[t];
      aw += f * kt[t];
    }
    u[base + i2 * D_ + c] = au;
    w[base + i2 * D_ + c] = aw;
  }
}

// ---------------- sequential scan over chunks; block = (b,h,colgroup of 32) ----------------
__global__ __launch_bounds__(256)
void delta_scan(const float* __restrict__ qn, const float* __restrict__ kn,
                const float* u, const float* __restrict__ w,
                const float* __restrict__ attn, float* out) {
  __shared__ float4 sS[2048];
  __shared__ float4 sq[2048];
  __shared__ float4 sw[2048];
  __shared__ float4 sk[2048];
  __shared__ float  su[32 * 36];
  __shared__ float  su2[32 * 36];
  __shared__ float  sat[32 * 36];
  int blk = blockIdx.x;
  int cg = blk & 7;
  int bh = blk >> 3;
  int h = bh & 3;
  int b = bh >> 2;
  int tid = threadIdx.x;
  int c = tid & 31, rg = tid >> 5;
  int i0 = rg * 4;
  int col0 = cg * 32;
  int swz = c & 7;
#pragma unroll
  for (int i = 0; i < 8; ++i) sS[tid + i * 256] = make_float4(0.f, 0.f, 0.f, 0.f);
  __syncthreads();
  for (int ci = 0; ci < NCH; ++ci) {
    long base = ((long)b * L_ + (long)ci * CHUNKSZ) * D_ + h * DH;
#pragma unroll
    for (int jj = 0; jj < 8; ++jj) {
      int idx = tid + jj * 256;
      int r = idx >> 6, d4 = idx & 63;
      sq[idx] = reinterpret_cast<const float4*>(qn + base + (long)r * D_)[d4];
      sw[idx] = reinterpret_cast<const float4*>(w  + base + (long)r * D_)[d4];
      sk[idx] = reinterpret_cast<const float4*>(kn + base + (long)r * D_)[d4];
    }
    {
      int r = tid >> 3, c4 = tid & 7;
      float4 uv = reinterpret_cast<const float4*>(u + base + (long)r * D_ + col0)[c4];
      *reinterpret_cast<float4*>(&su[r * 36 + c4 * 4]) = uv;
      float4 av = reinterpret_cast<const float4*>(attn + ((long)bh * NCH + ci) * 1024 + r * 32)[c4];
      *reinterpret_cast<float4*>(&sat[r * 36 + c4 * 4]) = av;
    }
    __syncthreads();
    float aw0 = 0.f, aw1 = 0.f, aw2 = 0.f, aw3 = 0.f;
    float aq0 = 0.f, aq1 = 0.f, aq2 = 0.f, aq3 = 0.f;
#pragma unroll 8
    for (int d4 = 0; d4 < 64; ++d4) {
      float4 s = sS[c * 64 + (d4 ^ swz)];
      float4 w0 = sw[(i0 + 0) * 64 + d4];
      float4 w1 = sw[(i0 + 1) * 64 + d4];
      float4 w2 = sw[(i0 + 2) * 64 + d4];
      float4 w3 = sw[(i0 + 3) * 64 + d4];
      aw0 = fmaf(w0.x, s.x, fmaf(w0.y, s.y, fmaf(w0.z, s.z, fmaf(w0.w, s.w, aw0))));
      aw1 = fmaf(w1.x, s.x, fmaf(w1.y, s.y, fmaf(w1.z, s.z, fmaf(w1.w, s.w, aw1))));
      aw2 = fmaf(w2.x, s.x, fmaf(w2.y, s.y, fmaf(w2.z, s.z, fmaf(w2.w, s.w, aw2))));
      aw3 = fmaf(w3.x, s.x, fmaf(w3.y, s.y, fmaf(w3.z, s.z, fmaf(w3.w, s.w, aw3))));
      float4 q0 = sq[(i0 + 0) * 64 + d4];
      float4 q1 = sq[(i0 + 1) * 64 + d4];
      float4 q2 = sq[(i0 + 2) * 64 + d4];
      float4 q3 = sq[(i0 + 3) * 64 + d4];
      aq0 = fmaf(q0.x, s.x, fmaf(q0.y, s.y, fmaf(q0.z, s.z, fmaf(q0.w, s.w, aq0))));
      aq1 = fmaf(q1.x, s.x, fmaf(q1.y, s.y, fmaf(q1.z, s.z, fmaf(q1.w, s.w, aq1))));
      aq2 = fmaf(q2.x, s.x, fmaf(q2.y, s.y, fmaf(q2.z, s.z, fmaf(q2.w, s.w, aq2))));
      aq3 = fmaf(q3.x, s.x, fmaf(q3.y, s.y, fmaf(q3.z, s.z, fmaf(q3.w, s.w, aq3))));
    }
    su2[(i0 + 0) * 36 + c] = su[(i0 + 0) * 36 + c] - aw0;
    su2[(i0 + 1) * 36 + c] = su[(i0 + 1) * 36 + c] - aw1;
    su2[(i0 + 2) * 36 + c] = su[(i0 + 2) * 36 + c] - aw2;
    su2[(i0 + 3) * 36 + c] = su[(i0 + 3) * 36 + c] - aw3;
    __syncthreads();
    float o0 = aq0, o1 = aq1, o2 = aq2, o3 = aq3;
#pragma unroll
    for (int t = 0; t < 32; ++t) {
      float uv = su2[t * 36 + c];
      o0 = fmaf(sat[(i0 + 0) * 36 + t], uv, o0);
      o1 = fmaf(sat[(i0 + 1) * 36 + t], uv, o1);
      o2 = fmaf(sat[(i0 + 2) * 36 + t], uv, o2);
      o3 = fmaf(sat[(i0 + 3) * 36 + t], uv, o3);
    }
    out[base + (long)(i0 + 0) * D_ + col0 + c] = o0;
    out[base + (long)(i0 + 1) * D_ + col0 + c] = o1;
    out[base + (long)(i0 + 2) * D_ + col0 + c] = o2;
    out[base + (long)(i0 + 3) * D_ + col0 + c] = o3;
    float u2c[32];
#pragma unroll
    for (int t = 0; t < 32; ++t) u2c[t] = su2[t * 36 + c];
#pragma unroll 4
    for (int j = 0; j < 8; ++j) {
      int d4 = rg * 8 + j;
      int phys = c * 64 + (d4 ^ swz);
      float4 s = sS[phys];
#pragma unroll
      for (int t = 0; t < 32; ++t) {
        float4 kv = sk[t * 64 + d4];
        s.x = fmaf(kv.x, u2c[t], s.x);
        s.y = fmaf(kv.y, u2c[t], s.y);
        s.z = fmaf(kv.z, u2c[t], s.z);
        s.w = fmaf(kv.w, u2c[t], s.w);
      }
      sS[phys] = s;
    }
    __syncthreads();
  }
}

// ---------------- head stats ----------------
__global__ __launch_bounds__(256)
void head_stats_k(const float* __restrict__ x, float* __restrict__ out,
                  int ostride, int ooff) {
  __shared__ float rs[256], rq[256], ra[256];
  long bl = blockIdx.x;
  int tid = threadIdx.x;
  float m_acc = 0, v_acc = 0, a_acc = 0, l_acc = 0;
  for (int h = 0; h < H_; ++h) {
    float v = x[bl * D_ + h * DH + tid];
    rs[tid] = v; rq[tid] = v * v; ra[tid] = fabsf(v);
    __syncthreads();
    for (int st = 128; st > 0; st >>= 1) {
      if (tid < st) { rs[tid] += rs[tid + st]; rq[tid] += rq[tid + st]; ra[tid] += ra[tid + st]; }
      __syncthreads();
    }
    if (tid == 0) {
      float mean = rs[0] / 256.f;
      m_acc += mean;
      v_acc += rq[0] / 256.f - mean * mean;
      a_acc += ra[0] / 256.f;
      l_acc += sqrtf(rq[0]);
    }
    __syncthreads();
  }
  if (tid == 0) {
    float* o = out + bl * ostride + ooff;
    o[0] = m_acc / H_; o[1] = v_acc / H_; o[2] = a_acc / H_; o[3] = l_acc / H_;
  }
}

// ---------------- g = gelu(g + bias + stats @ Wtail) ----------------
__global__ __launch_bounds__(256)
void tail_bias_gelu(float* __restrict__ g, const float* __restrict__ stats,
                    const float* __restrict__ Wt, const float* __restrict__ bias,
                    int N, int K2) {
  long idx = (long)blockIdx.x * 256 + threadIdx.x;
  if (idx >= (long)BL * N) return;
  int n = idx % N;
  long m = idx / N;
  float s = g[idx] + bias[n];
  for (int k = 0; k < K2; ++k) s += stats[m * K2 + k] * Wt[(long)k * N + n];
  g[idx] = geluf(s);
}

// ---------------- softmax with temp, clip, renorm ----------------
__global__ __launch_bounds__(256)
void softmax_p(const float* __restrict__ logits, const float* __restrict__ temp_in,
               float* __restrict__ p) {
  int bl = blockIdx.x * 256 + threadIdx.x;
  if (bl >= BL) return;
  float temp = log1pf(expf(temp_in[0]));
  float l0 = logits[bl * 4 + 0] / temp, l1 = logits[bl * 4 + 1] / temp;
  float l2 = logits[bl * 4 + 2] / temp, l3 = logits[bl * 4 + 3] / temp;
  float mx = fmaxf(fmaxf(l0, l1), fmaxf(l2, l3));
  float e0 = expf(l0 - mx), e1 = expf(l1 - mx), e2 = expf(l2 - mx), e3 = expf(l3 - mx);
  float s = e0 + e1 + e2 + e3;
  e0 /= s; e1 /= s; e2 /= s; e3 /= s;
  e0 = fmaxf(e0, 0.02f); e1 = fmaxf(e1, 0.02f); e2 = fmaxf(e2, 0.02f); e3 = fmaxf(e3, 0.02f);
  s = e0 + e1 + e2 + e3;
  p[bl * 4 + 0] = e0 / s; p[bl * 4 + 1] = e1 / s; p[bl * 4 + 2] = e2 / s; p[bl * 4 + 3] = e3 / s;
}

// ---------------- mixture combine + conv residual ----------------
__global__ __launch_bounds__(256)
void combine(const float* __restrict__ ls, const float* __restrict__ ll,
             const float* __restrict__ dd, const float* __restrict__ vd,
             const float* __restrict__ p, const float* __restrict__ resg,
             const float* __restrict__ crl, float* __restrict__ o) {
  int idx = blockIdx.x * 256 + threadIdx.x;
  if (idx >= BLD) return;
  int c = idx % D_;
  long bl = idx / D_;
  int h = c >> 8;
  const float* pp = p + bl * 4;
  float sgate = sigmf(crl[h]) * resg[bl * H_ + h];
  o[idx] = pp[0] * ls[idx] + pp[1] * ll[idx] + pp[2] * dd[idx] + pp[3] * vd[idx] + sgate * ls[idx];
}

// ---------------- o = rmsnorm(o * og) * norm_w ----------------
__global__ __launch_bounds__(256)
void scale_rmsnorm(float* __restrict__ o, const float* __restrict__ og,
                   const float* __restrict__ nw) {
  __shared__ float red[256];
  long row = blockIdx.x;
  long bl = row >> 2;
  int tid = threadIdx.x;
  float v = o[row * 256 + tid] * og[bl];
  red[tid] = v * v;
  __syncthreads();
  for (int st = 128; st > 0; st >>= 1) {
    if (tid < st) red[tid] += red[tid + st];
    __syncthreads();
  }
  float scale = rsqrtf(red[0] / 256.f + 1e-5f);
  o[row * 256 + tid] = v * scale * nw[tid];
}

extern "C" void kernel_launch(void* const* d_in, const int* in_sizes, int n_in,
                              void* d_out, int out_size, void* d_ws, size_t ws_size,
                              hipStream_t stream) {
  const float* hs       = (const float*)d_in[0];
  const float* Wq       = (const float*)d_in[1];
  const float* Wk       = (const float*)d_in[2];
  const float* Wv       = (const float*)d_in[3];
  const float* Wb       = (const float*)d_in[4];
  const float* wq_conv  = (const float*)d_in[5];
  const float* wk_conv  = (const float*)d_in[6];
  const float* wv_conv  = (const float*)d_in[7];
  const float* fir_long = (const float*)d_in[8];
  const float* fir_short= (const float*)d_in[9];
  const float* Wg1      = (const float*)d_in[10];
  const float* bg1      = (const float*)d_in[11];
  const float* Wg2      = (const float*)d_in[12];
  const float* bg2      = (const float*)d_in[13];
  const float* logit_temp     = (const float*)d_in[14];
  const float* conv_res_logit = (const float*)d_in[15];
  const float* Wres     = (const float*)d_in[16];
  const float* bres     = (const float*)d_in[17];
  const float* Wog1     = (const float*)d_in[18];
  const float* bog1     = (const float*)d_in[19];
  const float* Wog2     = (const float*)d_in[20];
  const float* bog2     = (const float*)d_in[21];
  const float* norm_w   = (const float*)d_in[22];
  const float* Wo       = (const float*)d_in[23];
  float* out = (float*)d_out;
  float* ws = (float*)d_ws;

  float* b0 = ws;             // qlin -> kn -> gate_hidden -> o_mix
  float* b1 = ws + 1L * BLD;  // klin -> v_in (v_direct)
  float* b2 = ws + 2L * BLD;  // vlin -> u -> delta_out -> og_hidden
  float* b3 = ws + 3L * BLD;  // qn -> local_long
  float* b4 = ws + 4L * BLD;  // w -> local_short
  float* sm = ws + 5L * BLD;
  float* beta    = sm;
  float* resg    = beta + BL * H_;
  float* stats16 = resg + BL * H_;
  float* og8     = stats16 + BL * 16;
  float* logits  = og8 + BL * 8;
  float* pbuf    = logits + BL * 4;
  float* ogv     = pbuf + BL * 4;
  float* attn    = ogv + BL;                        // 1M floats
  unsigned short* hsb  = (unsigned short*)(attn + (long)B_ * H_ * NCH * 1024);
  unsigned short* xb   = hsb + (long)BLD;
  unsigned short* wtq  = xb + (long)BLD;            // each full Wt: 1024*1024
  unsigned short* wtk  = wtq + 1024L * 1024;
  unsigned short* wtv  = wtk + 1024L * 1024;
  unsigned short* wtg1 = wtv + 1024L * 1024;
  unsigned short* wto  = wtg1 + 1024L * 1024;
  unsigned short* wtog1= wto + 1024L * 1024;        // 512*1024

  size_t needed = (5L * BLD + BL * 41 + (long)B_ * H_ * NCH * 1024) * 4
                + (2L * BLD + 5L * 1024 * 1024 + 512L * 1024) * 2;
  if (ws_size < needed) return;

  dim3 blk(256);
  // 0. preconvert: weights -> transposed bf16; hs -> bf16
  wconv_t<<<dim3(32, 32), blk, 0, stream>>>(Wq, wtq, 1024);
  wconv_t<<<dim3(32, 32), blk, 0, stream>>>(Wk, wtk, 1024);
  wconv_t<<<dim3(32, 32), blk, 0, stream>>>(Wv, wtv, 1024);
  wconv_t<<<dim3(32, 32), blk, 0, stream>>>(Wg1, wtg1, 1024);
  wconv_t<<<dim3(32, 32), blk, 0, stream>>>(Wo, wto, 1024);
  wconv_t<<<dim3(16, 32), blk, 0, stream>>>(Wog1, wtog1, 512);
  cvt_bf16<<<BLD / 1024, blk, 0, stream>>>(hs, hsb, BLD);
  // 1. projections (bf16 MFMA)
  gemm_bf16<<<dim3(8, 64), blk, 0, stream>>>(hsb, wtq, b0, 1024);
  gemm_bf16<<<dim3(8, 64), blk, 0, stream>>>(hsb, wtk, b1, 1024);
  gemm_bf16<<<dim3(8, 64), blk, 0, stream>>>(hsb, wtv, b2, 1024);
  // 2. conv + silu
  dwconv_k<<<BLD / 256, blk, 0, stream>>>(b0, wq_conv, b3, 4, 1);
  dwconv_k<<<BLD / 256, blk, 0, stream>>>(b1, wk_conv, b0, 4, 1);
  dwconv_k<<<BLD / 256, blk, 0, stream>>>(b2, wv_conv, b1, 4, 1);
  // 3. beta, res gate
  gemv_smallN<<<BL, blk, 0, stream>>>(hs, Wb, nullptr, beta, D_, H_, 1);
  gemv_smallN<<<BL, blk, 0, stream>>>(hs, Wres, bres, resg, D_, H_, 1);
  // 4. l2norm
  l2norm_inplace<<<BL * H_, blk, 0, stream>>>(b3);
  l2norm_inplace<<<BL * H_, blk, 0, stream>>>(b0);
  // 5-6. delta rule
  chunk_uw<<<B_ * H_ * NCH, blk, 0, stream>>>(b3, b0, b1, beta, b2, b4, attn);
  delta_scan<<<B_ * H_ * 8, blk, 0, stream>>>(b3, b0, b2, b4, attn, b2);
  // 7. local convs
  dwconv_k<<<BLD / 256, blk, 0, stream>>>(b1, fir_long, b3, 64, 0);
  dwconv_k<<<BLD / 256, blk, 0, stream>>>(b1, fir_short, b4, 5, 0);
  // 8. stats16
  head_stats_k<<<BL, blk, 0, stream>>>(b4, stats16, 16, 0);
  head_stats_k<<<BL, blk, 0, stream>>>(b3, stats16, 16, 4);
  head_stats_k<<<BL, blk, 0, stream>>>(b2, stats16, 16, 8);
  head_stats_k<<<BL, blk, 0, stream>>>(b1, stats16, 16, 12);
  // 9. gate hidden
  gemm_bf16<<<dim3(8, 64), blk, 0, stream>>>(hsb, wtg1, b0, 1024);
  tail_bias_gelu<<<(BL * D_) / 256, blk, 0, stream>>>(b0, stats16, Wg1 + 1024L * 1024, bg1, D_, 16);
  // 10. logits, p
  gemv_smallN<<<BL, blk, 0, stream>>>(b0, Wg2, bg2, logits, D_, 4, 0);
  softmax_p<<<BL / 256, blk, 0, stream>>>(logits, logit_temp, pbuf);
  // 11. combine -> b0
  combine<<<BLD / 256, blk, 0, stream>>>(b4, b3, b2, b1, pbuf, resg, conv_res_logit, b0);
  // 12. og stats
  head_stats_k<<<BL, blk, 0, stream>>>(b0, og8, 8, 0);
  head_stats_k<<<BL, blk, 0, stream>>>(b1, og8, 8, 4);
  // 13. output gate
  gemm_bf16<<<dim3(4, 64), blk, 0, stream>>>(hsb, wtog1, b2, 512);
  tail_bias_gelu<<<(BL * 512) / 256, blk, 0, stream>>>(b2, og8, Wog1 + 1024L * 512, bog1, 512, 8);
  gemv_smallN<<<BL, blk, 0, stream>>>(b2, Wog2, bog2, ogv, 512, 1, 1);
  // 14. scale + rmsnorm
  scale_rmsnorm<<<BL * H_, blk, 0, stream>>>(b0, ogv, norm_w);
  // 15. final projection (bf16)
  cvt_bf16<<<BLD / 1024, blk, 0, stream>>>(b0, xb, BLD);
  gemm_bf16<<<dim3(8, 64), blk, 0, stream>>>(xb, wto, out, 1024);
}

// Round 5
// 1931.068 us; speedup vs baseline: 7.5385x; 2.4712x over previous
//
#include <hip/hip_runtime.h>
#include <math.h>

#define B_ 2
#define L_ 4096
#define D_ 1024
#define H_ 4
#define DH 256
#define CHUNKSZ 32
#define NCH (L_/CHUNKSZ)      // 128
#define BL (B_*L_)            // 8192
#define BLD (B_*L_*D_)        // 8388608

typedef __attribute__((ext_vector_type(8))) short bf16x8;
typedef __attribute__((ext_vector_type(4))) float f32x4;

__device__ __forceinline__ float sigmf(float x) { return 1.f / (1.f + expf(-x)); }
__device__ __forceinline__ float geluf(float x) { return 0.5f * x * (1.f + erff(x * 0.70710678118654752f)); }
__device__ __forceinline__ unsigned short f2bf(float f) {
  unsigned int u = __float_as_uint(f);
  unsigned int r = (u + 0x7FFFu + ((u >> 16) & 1u)) >> 16;
  return (unsigned short)r;
}

// ---------------- f32 -> bf16 elementwise (n multiple of 4) ----------------
__global__ __launch_bounds__(256)
void cvt_bf16(const float* __restrict__ x, unsigned short* __restrict__ y, long n) {
  long i = ((long)blockIdx.x * 256 + threadIdx.x) * 4;
  if (i >= n) return;
  float4 v = *reinterpret_cast<const float4*>(&x[i]);
  ushort4 o;
  o.x = f2bf(v.x); o.y = f2bf(v.y); o.z = f2bf(v.z); o.w = f2bf(v.w);
  *reinterpret_cast<ushort4*>(&y[i]) = o;
}

// ---------------- W[k][n] f32 -> Wt[n][k] bf16 (32x32 tiles) ----------------
__global__ __launch_bounds__(256)
void wconv_t(const float* __restrict__ W, unsigned short* __restrict__ Wt, int N) {
  __shared__ float tile[32][33];
  int kb = blockIdx.y * 32, nb = blockIdx.x * 32;
  int tx = threadIdx.x & 31, ty = threadIdx.x >> 5;
  for (int i = 0; i < 32; i += 8)
    tile[ty + i][tx] = W[(long)(kb + ty + i) * N + nb + tx];
  __syncthreads();
  for (int i = 0; i < 32; i += 8)
    Wt[(long)(nb + ty + i) * 1024 + kb + tx] = f2bf(tile[tx][ty + i]);
}

// ---------------- bf16 MFMA GEMM: C[8192][N] = A[8192][1024] @ Bt[N][1024]^T ----------------
__global__ __launch_bounds__(256)
void gemm_bf16(const unsigned short* __restrict__ A, const unsigned short* __restrict__ Bt,
               float* __restrict__ C, int N) {
  __shared__ unsigned short Al[128 * 32];
  __shared__ unsigned short Bl[128 * 32];
  const int K = 1024;
  int bm = blockIdx.y * 128, bn = blockIdx.x * 128;
  int tid = threadIdx.x;
  int lane = tid & 63, wid = tid >> 6;
  int wr = wid >> 1, wc = wid & 1;
  int l15 = lane & 15, l4 = lane >> 4;
  f32x4 acc[4][4];
#pragma unroll
  for (int i = 0; i < 4; ++i)
#pragma unroll
    for (int j = 0; j < 4; ++j) { acc[i][j].x = 0.f; acc[i][j].y = 0.f; acc[i][j].z = 0.f; acc[i][j].w = 0.f; }
  for (int k0 = 0; k0 < K; k0 += 32) {
    __syncthreads();
#pragma unroll
    for (int i = 0; i < 2; ++i) {
      int idx = tid + i * 256;
      int r = idx >> 2, sl = idx & 3;
      int s = sl ^ ((r >> 1) & 3);
      uint4 av = *reinterpret_cast<const uint4*>(&A[(long)(bm + r) * K + k0 + sl * 8]);
      *reinterpret_cast<uint4*>(&Al[r * 32 + s * 8]) = av;
      uint4 bv = *reinterpret_cast<const uint4*>(&Bt[(long)(bn + r) * K + k0 + sl * 8]);
      *reinterpret_cast<uint4*>(&Bl[r * 32 + s * 8]) = bv;
    }
    __syncthreads();
    bf16x8 af[4], bfr[4];
#pragma unroll
    for (int fi = 0; fi < 4; ++fi) {
      int r = wr * 64 + fi * 16 + l15;
      af[fi] = *reinterpret_cast<const bf16x8*>(&Al[r * 32 + (l4 ^ ((r >> 1) & 3)) * 8]);
    }
#pragma unroll
    for (int fj = 0; fj < 4; ++fj) {
      int r = wc * 64 + fj * 16 + l15;
      bfr[fj] = *reinterpret_cast<const bf16x8*>(&Bl[r * 32 + (l4 ^ ((r >> 1) & 3)) * 8]);
    }
#pragma unroll
    for (int fi = 0; fi < 4; ++fi)
#pragma unroll
      for (int fj = 0; fj < 4; ++fj)
        acc[fi][fj] = __builtin_amdgcn_mfma_f32_16x16x32_bf16(af[fi], bfr[fj], acc[fi][fj], 0, 0, 0);
  }
#pragma unroll
  for (int fi = 0; fi < 4; ++fi) {
    int rb = bm + wr * 64 + fi * 16 + l4 * 4;
#pragma unroll
    for (int fj = 0; fj < 4; ++fj) {
      int cb = bn + wc * 64 + fj * 16 + l15;
#pragma unroll
      for (int j = 0; j < 4; ++j)
        C[(long)(rb + j) * N + cb] = acc[fi][fj][j];
    }
  }
}

// ---------------- tiled depthwise causal conv (+ optional silu), K templated ----------------
#define CTL 128
template<int K>
__global__ __launch_bounds__(256)
void dwconv_tiled(const float* __restrict__ x, const float* __restrict__ w,
                  float* __restrict__ y, int do_silu) {
  __shared__ float tile[(CTL + K - 1) * 64];
  int bid = blockIdx.x;
  int ct = bid & 15;
  int lt = (bid >> 4) & 31;
  int b  = bid >> 9;
  int c0 = ct * 64;
  int l0 = lt * CTL;
  int tid = threadIdx.x;
  const int rows = CTL + K - 1;
  for (int i = tid; i < rows * 16; i += 256) {
    int rr = i >> 4, c4 = i & 15;
    int l = l0 - (K - 1) + rr;
    float4 v = make_float4(0.f, 0.f, 0.f, 0.f);
    if (l >= 0) v = *reinterpret_cast<const float4*>(&x[((long)b * L_ + l) * D_ + c0 + c4 * 4]);
    *reinterpret_cast<float4*>(&tile[rr * 64 + c4 * 4]) = v;
  }
  __syncthreads();
  int c = tid & 63;
  int lo0 = tid >> 6;
  float wreg[K];
#pragma unroll
  for (int j = 0; j < K; ++j) wreg[j] = w[(long)(c0 + c) * K + j];
  for (int lo = lo0; lo < CTL; lo += 4) {
    float acc = 0.f;
#pragma unroll
    for (int j = 0; j < K; ++j)
      acc = fmaf(wreg[j], tile[(lo + j) * 64 + c], acc);
    if (do_silu) acc = acc * sigmf(acc);
    y[((long)b * L_ + l0 + lo) * D_ + c0 + c] = acc;
  }
}

// ---------------- small-N GEMV ----------------
__global__ __launch_bounds__(256)
void gemv_smallN(const float* __restrict__ X, const float* __restrict__ W,
                 const float* __restrict__ bias, float* __restrict__ out,
                 int K, int N, int act) {
  __shared__ float red[256];
  long m = blockIdx.x;
  const float* x = X + m * K;
  for (int n = 0; n < N; ++n) {
    float s = 0.f;
    for (int k = threadIdx.x; k < K; k += 256) s += x[k] * W[(long)k * N + n];
    red[threadIdx.x] = s;
    __syncthreads();
    for (int st = 128; st > 0; st >>= 1) {
      if (threadIdx.x < st) red[threadIdx.x] += red[threadIdx.x + st];
      __syncthreads();
    }
    if (threadIdx.x == 0) {
      float v = red[0] + (bias ? bias[n] : 0.f);
      if (act == 1) v = sigmf(v);
      out[m * N + n] = v;
    }
    __syncthreads();
  }
}

// ---------------- l2norm in place over rows of 256 ----------------
__global__ __launch_bounds__(256)
void l2norm_inplace(float* __restrict__ x) {
  __shared__ float red[256];
  long row = blockIdx.x;
  float v = x[row * 256 + threadIdx.x];
  red[threadIdx.x] = v * v;
  __syncthreads();
  for (int st = 128; st > 0; st >>= 1) {
    if (threadIdx.x < st) red[threadIdx.x] += red[threadIdx.x + st];
    __syncthreads();
  }
  float inv = rsqrtf(red[0] + 1e-6f);
  x[row * 256 + threadIdx.x] = v * inv;
}

// ---------------- per-chunk: inv, u, w, attn ----------------
__global__ __launch_bounds__(256)
void chunk_uw(const float* __restrict__ qn, const float* __restrict__ kn,
              const float* __restrict__ v, const float* __restrict__ beta,
              float* __restrict__ u, float* __restrict__ w, float* __restrict__ attn) {
  __shared__ float skT[256][33];
  __shared__ float sinv[32][33];
  __shared__ float sbeta[32];
  int blk = blockIdx.x;
  int ci = blk % NCH;
  int bh = blk / NCH;
  int h = bh % H_;
  int b = bh / H_;
  long base = ((long)b * L_ + (long)ci * CHUNKSZ) * D_ + h * DH;
  long brow = (long)b * L_ + (long)ci * CHUNKSZ;
  int tid = threadIdx.x;
  for (int i = tid; i < 32 * 256; i += 256) {
    int r = i >> 8, c = i & 255;
    skT[c][r] = kn[base + (long)r * D_ + c];
  }
  if (tid < 32) sbeta[tid] = beta[(brow + tid) * H_ + h];
  __syncthreads();
  int j = tid & 31, i0 = tid >> 5;
  for (int r = 0; r < 4; ++r) {
    int i = i0 + (r << 3);
    float acc = 0.f;
    for (int d = 0; d < 256; ++d) acc += skT[d][i] * skT[d][j];
    sinv[i][j] = (i > j) ? -acc * sbeta[i] : 0.f;
  }
  __syncthreads();
  for (int i = 1; i < 32; ++i) {
    float val = 0.f;
    if (tid < 32) {
      for (int t = 0; t < i; ++t) val += sinv[i][t] * sinv[t][tid];
    }
    __syncthreads();
    if (tid < 32) sinv[i][tid] += val;
    __syncthreads();
  }
  if (tid < 32) sinv[tid][tid] += 1.f;
  long attn_base = (long)blk * 1024;
  for (int r = 0; r < 4; ++r) {
    int i = i0 + (r << 3);
    const float* qrow = qn + base + (long)i * D_;
    float acc = 0.f;
    for (int d = 0; d < 256; ++d) acc += qrow[d] * skT[d][j];
    attn[attn_base + i * 32 + j] = (i >= j) ? acc : 0.f;
  }
  __syncthreads();
  int c = tid;
  float vt[32], kt[32];
#pragma unroll
  for (int t = 0; t < 32; ++t) {
    vt[t] = v[base + t * D_ + c] * sbeta[t];
    kt[t] = skT[c][t] * sbeta[t];
  }
#pragma unroll
  for (int i2 = 0; i2 < 32; ++i2) {
    float au = 0.f, aw = 0.f;
#pragma unroll
    for (int t = 0; t <= i2; ++t) {
      float f = sinv[i2][t];
      au += f * vt[t];
      aw += f * kt[t];
    }
    u[base + i2 * D_ + c] = au;
    w[base + i2 * D_ + c] = aw;
  }
}

// ---------------- sequential scan; block = (b,h, colgroup of 8); 256 blocks ----------------
// Reg-staged prefetch of next chunk overlaps compute. S[256][8cols] f32 in LDS.
// `out` may alias `u` (different chunks / disjoint cols). No __restrict__ on u/out.
__global__ __launch_bounds__(256, 1)
void delta_scan(const float* __restrict__ qn, const float* __restrict__ kn,
                const float* u, const float* __restrict__ w,
                const float* __restrict__ attn, float* out) {
  __shared__ float4 sS[64 * 8];       // [d4][c]
  __shared__ float4 sq[32 * 65];      // [r][d4] pad 65
  __shared__ float4 swl[32 * 65];
  __shared__ float4 skl[32 * 65];
  __shared__ float  sat[32 * 36];     // [r][t] pad 36
  __shared__ float  su2[32 * 9];      // [t][c] pad 9
  int blk = blockIdx.x;
  int bh = blk & 7;            // same-bh blocks likely share XCD (heuristic)
  int cg = blk >> 3;           // 0..31
  int h = bh & 3, b = bh >> 2;
  int col0 = cg * 8;
  int tid = threadIdx.x;
  int c = tid & 7, r = tid >> 3;       // 32 rows x 8 cols
  sS[tid] = make_float4(0.f, 0.f, 0.f, 0.f);
  sS[tid + 256] = make_float4(0.f, 0.f, 0.f, 0.f);

  float4 pq[8], pw[8], pk[8], pat;
  float pu;
  long abase0 = (long)bh * NCH * 1024;

#define STAGE_LOAD(CI) do {                                                     \
    long nb = ((long)b * L_ + (long)(CI) * CHUNKSZ) * D_ + h * DH;              \
    _Pragma("unroll")                                                           \
    for (int j = 0; j < 8; ++j) {                                               \
      int idx = j * 256 + tid;                                                  \
      int rr = idx >> 6, d4 = idx & 63;                                         \
      pq[j] = reinterpret_cast<const float4*>(qn + nb + (long)rr * D_)[d4];     \
      pw[j] = reinterpret_cast<const float4*>(w  + nb + (long)rr * D_)[d4];     \
      pk[j] = reinterpret_cast<const float4*>(kn + nb + (long)rr * D_)[d4];     \
    }                                                                           \
    pat = reinterpret_cast<const float4*>(attn + abase0 + (long)(CI) * 1024)[tid]; \
    pu = u[nb + (long)r * D_ + col0 + c];                                       \
  } while (0)

#define STAGE_WRITE() do {                                                      \
    _Pragma("unroll")                                                           \
    for (int j = 0; j < 8; ++j) {                                               \
      int idx = j * 256 + tid;                                                  \
      int rr = idx >> 6, d4 = idx & 63;                                         \
      sq[rr * 65 + d4] = pq[j];                                                 \
      swl[rr * 65 + d4] = pw[j];                                                \
      skl[rr * 65 + d4] = pk[j];                                                \
    }                                                                           \
    { int ra = tid >> 3, ca = tid & 7;                                          \
      *reinterpret_cast<float4*>(&sat[ra * 36 + ca * 4]) = pat; }               \
  } while (0)

  STAGE_LOAD(0);
  STAGE_WRITE();
  float pu_cur = pu;
  __syncthreads();

  for (int ci = 0; ci < NCH; ++ci) {
    long base = ((long)b * L_ + (long)ci * CHUNKSZ) * D_ + h * DH;
    if (ci + 1 < NCH) STAGE_LOAD(ci + 1);
    // ---- phase 1: w@S and q@S for (row r, col c) ----
    float aw = 0.f, aq = 0.f;
#pragma unroll 8
    for (int d4 = 0; d4 < 64; ++d4) {
      float4 s = sS[d4 * 8 + c];
      float4 wv = swl[r * 65 + d4];
      float4 qv = sq[r * 65 + d4];
      aw = fmaf(wv.x, s.x, fmaf(wv.y, s.y, fmaf(wv.z, s.z, fmaf(wv.w, s.w, aw))));
      aq = fmaf(qv.x, s.x, fmaf(qv.y, s.y, fmaf(qv.z, s.z, fmaf(qv.w, s.w, aq))));
    }
    su2[r * 9 + c] = pu_cur - aw;
    __syncthreads();
    // ---- phase 2: out = q@S + attn@u2 ; S += k^T @ u2 ----
    float o = aq;
#pragma unroll
    for (int t = 0; t < 32; ++t) o = fmaf(sat[r * 36 + t], su2[t * 9 + c], o);
    out[base + (long)r * D_ + col0 + c] = o;
    float4 s0 = sS[r * 8 + c];
    float4 s1 = sS[(r + 32) * 8 + c];
#pragma unroll
    for (int t = 0; t < 32; ++t) {
      float uv = su2[t * 9 + c];
      float4 k0 = skl[t * 65 + r];
      float4 k1 = skl[t * 65 + r + 32];
      s0.x = fmaf(k0.x, uv, s0.x); s0.y = fmaf(k0.y, uv, s0.y);
      s0.z = fmaf(k0.z, uv, s0.z); s0.w = fmaf(k0.w, uv, s0.w);
      s1.x = fmaf(k1.x, uv, s1.x); s1.y = fmaf(k1.y, uv, s1.y);
      s1.z = fmaf(k1.z, uv, s1.z); s1.w = fmaf(k1.w, uv, s1.w);
    }
    sS[r * 8 + c] = s0;
    sS[(r + 32) * 8 + c] = s1;
    __syncthreads();
    if (ci + 1 < NCH) {
      STAGE_WRITE();
      pu_cur = pu;
      __syncthreads();
    }
  }
#undef STAGE_LOAD
#undef STAGE_WRITE
}

// ---------------- head stats ----------------
__global__ __launch_bounds__(256)
void head_stats_k(const float* __restrict__ x, float* __restrict__ out,
                  int ostride, int ooff) {
  __shared__ float rs[256], rq[256], ra[256];
  long bl = blockIdx.x;
  int tid = threadIdx.x;
  float m_acc = 0, v_acc = 0, a_acc = 0, l_acc = 0;
  for (int h = 0; h < H_; ++h) {
    float v = x[bl * D_ + h * DH + tid];
    rs[tid] = v; rq[tid] = v * v; ra[tid] = fabsf(v);
    __syncthreads();
    for (int st = 128; st > 0; st >>= 1) {
      if (tid < st) { rs[tid] += rs[tid + st]; rq[tid] += rq[tid + st]; ra[tid] += ra[tid + st]; }
      __syncthreads();
    }
    if (tid == 0) {
      float mean = rs[0] / 256.f;
      m_acc += mean;
      v_acc += rq[0] / 256.f - mean * mean;
      a_acc += ra[0] / 256.f;
      l_acc += sqrtf(rq[0]);
    }
    __syncthreads();
  }
  if (tid == 0) {
    float* o = out + bl * ostride + ooff;
    o[0] = m_acc / H_; o[1] = v_acc / H_; o[2] = a_acc / H_; o[3] = l_acc / H_;
  }
}

// ---------------- g = gelu(g + bias + stats @ Wtail) ----------------
__global__ __launch_bounds__(256)
void tail_bias_gelu(float* __restrict__ g, const float* __restrict__ stats,
                    const float* __restrict__ Wt, const float* __restrict__ bias,
                    int N, int K2) {
  long idx = (long)blockIdx.x * 256 + threadIdx.x;
  if (idx >= (long)BL * N) return;
  int n = idx % N;
  long m = idx / N;
  float s = g[idx] + bias[n];
  for (int k = 0; k < K2; ++k) s += stats[m * K2 + k] * Wt[(long)k * N + n];
  g[idx] = geluf(s);
}

// ---------------- softmax with temp, clip, renorm ----------------
__global__ __launch_bounds__(256)
void softmax_p(const float* __restrict__ logits, const float* __restrict__ temp_in,
               float* __restrict__ p) {
  int bl = blockIdx.x * 256 + threadIdx.x;
  if (bl >= BL) return;
  float temp = log1pf(expf(temp_in[0]));
  float l0 = logits[bl * 4 + 0] / temp, l1 = logits[bl * 4 + 1] / temp;
  float l2 = logits[bl * 4 + 2] / temp, l3 = logits[bl * 4 + 3] / temp;
  float mx = fmaxf(fmaxf(l0, l1), fmaxf(l2, l3));
  float e0 = expf(l0 - mx), e1 = expf(l1 - mx), e2 = expf(l2 - mx), e3 = expf(l3 - mx);
  float s = e0 + e1 + e2 + e3;
  e0 /= s; e1 /= s; e2 /= s; e3 /= s;
  e0 = fmaxf(e0, 0.02f); e1 = fmaxf(e1, 0.02f); e2 = fmaxf(e2, 0.02f); e3 = fmaxf(e3, 0.02f);
  s = e0 + e1 + e2 + e3;
  p[bl * 4 + 0] = e0 / s; p[bl * 4 + 1] = e1 / s; p[bl * 4 + 2] = e2 / s; p[bl * 4 + 3] = e3 / s;
}

// ---------------- mixture combine + conv residual ----------------
__global__ __launch_bounds__(256)
void combine(const float* __restrict__ ls, const float* __restrict__ ll,
             const float* __restrict__ dd, const float* __restrict__ vd,
             const float* __restrict__ p, const float* __restrict__ resg,
             const float* __restrict__ crl, float* __restrict__ o) {
  int idx = blockIdx.x * 256 + threadIdx.x;
  if (idx >= BLD) return;
  int c = idx % D_;
  long bl = idx / D_;
  int h = c >> 8;
  const float* pp = p + bl * 4;
  float sgate = sigmf(crl[h]) * resg[bl * H_ + h];
  o[idx] = pp[0] * ls[idx] + pp[1] * ll[idx] + pp[2] * dd[idx] + pp[3] * vd[idx] + sgate * ls[idx];
}

// ---------------- o = rmsnorm(o * og) * norm_w ----------------
__global__ __launch_bounds__(256)
void scale_rmsnorm(float* __restrict__ o, const float* __restrict__ og,
                   const float* __restrict__ nw) {
  __shared__ float red[256];
  long row = blockIdx.x;
  long bl = row >> 2;
  int tid = threadIdx.x;
  float v = o[row * 256 + tid] * og[bl];
  red[tid] = v * v;
  __syncthreads();
  for (int st = 128; st > 0; st >>= 1) {
    if (tid < st) red[tid] += red[tid + st];
    __syncthreads();
  }
  float scale = rsqrtf(red[0] / 256.f + 1e-5f);
  o[row * 256 + tid] = v * scale * nw[tid];
}

extern "C" void kernel_launch(void* const* d_in, const int* in_sizes, int n_in,
                              void* d_out, int out_size, void* d_ws, size_t ws_size,
                              hipStream_t stream) {
  const float* hs       = (const float*)d_in[0];
  const float* Wq       = (const float*)d_in[1];
  const float* Wk       = (const float*)d_in[2];
  const float* Wv       = (const float*)d_in[3];
  const float* Wb       = (const float*)d_in[4];
  const float* wq_conv  = (const float*)d_in[5];
  const float* wk_conv  = (const float*)d_in[6];
  const float* wv_conv  = (const float*)d_in[7];
  const float* fir_long = (const float*)d_in[8];
  const float* fir_short= (const float*)d_in[9];
  const float* Wg1      = (const float*)d_in[10];
  const float* bg1      = (const float*)d_in[11];
  const float* Wg2      = (const float*)d_in[12];
  const float* bg2      = (const float*)d_in[13];
  const float* logit_temp     = (const float*)d_in[14];
  const float* conv_res_logit = (const float*)d_in[15];
  const float* Wres     = (const float*)d_in[16];
  const float* bres     = (const float*)d_in[17];
  const float* Wog1     = (const float*)d_in[18];
  const float* bog1     = (const float*)d_in[19];
  const float* Wog2     = (const float*)d_in[20];
  const float* bog2     = (const float*)d_in[21];
  const float* norm_w   = (const float*)d_in[22];
  const float* Wo       = (const float*)d_in[23];
  float* out = (float*)d_out;
  float* ws = (float*)d_ws;

  float* b0 = ws;             // qlin -> kn -> gate_hidden -> o_mix
  float* b1 = ws + 1L * BLD;  // klin -> v_in (v_direct)
  float* b2 = ws + 2L * BLD;  // vlin -> u -> delta_out -> og_hidden
  float* b3 = ws + 3L * BLD;  // qn -> local_long
  float* b4 = ws + 4L * BLD;  // w -> local_short
  float* sm = ws + 5L * BLD;
  float* beta    = sm;
  float* resg    = beta + BL * H_;
  float* stats16 = resg + BL * H_;
  float* og8     = stats16 + BL * 16;
  float* logits  = og8 + BL * 8;
  float* pbuf    = logits + BL * 4;
  float* ogv     = pbuf + BL * 4;
  float* attn    = ogv + BL;                        // 1M floats
  unsigned short* hsb  = (unsigned short*)(attn + (long)B_ * H_ * NCH * 1024);
  unsigned short* xb   = hsb + (long)BLD;
  unsigned short* wtq  = xb + (long)BLD;
  unsigned short* wtk  = wtq + 1024L * 1024;
  unsigned short* wtv  = wtk + 1024L * 1024;
  unsigned short* wtg1 = wtv + 1024L * 1024;
  unsigned short* wto  = wtg1 + 1024L * 1024;
  unsigned short* wtog1= wto + 1024L * 1024;

  size_t needed = (5L * BLD + BL * 41 + (long)B_ * H_ * NCH * 1024) * 4
                + (2L * BLD + 5L * 1024 * 1024 + 512L * 1024) * 2;
  if (ws_size < needed) return;

  dim3 blk(256);
  // 0. preconvert
  wconv_t<<<dim3(32, 32), blk, 0, stream>>>(Wq, wtq, 1024);
  wconv_t<<<dim3(32, 32), blk, 0, stream>>>(Wk, wtk, 1024);
  wconv_t<<<dim3(32, 32), blk, 0, stream>>>(Wv, wtv, 1024);
  wconv_t<<<dim3(32, 32), blk, 0, stream>>>(Wg1, wtg1, 1024);
  wconv_t<<<dim3(32, 32), blk, 0, stream>>>(Wo, wto, 1024);
  wconv_t<<<dim3(16, 32), blk, 0, stream>>>(Wog1, wtog1, 512);
  cvt_bf16<<<BLD / 1024, blk, 0, stream>>>(hs, hsb, BLD);
  // 1. projections
  gemm_bf16<<<dim3(8, 64), blk, 0, stream>>>(hsb, wtq, b0, 1024);
  gemm_bf16<<<dim3(8, 64), blk, 0, stream>>>(hsb, wtk, b1, 1024);
  gemm_bf16<<<dim3(8, 64), blk, 0, stream>>>(hsb, wtv, b2, 1024);
  // 2. conv + silu (tiled)
  dwconv_tiled<4><<<1024, blk, 0, stream>>>(b0, wq_conv, b3, 1);
  dwconv_tiled<4><<<1024, blk, 0, stream>>>(b1, wk_conv, b0, 1);
  dwconv_tiled<4><<<1024, blk, 0, stream>>>(b2, wv_conv, b1, 1);
  // 3. beta, res gate
  gemv_smallN<<<BL, blk, 0, stream>>>(hs, Wb, nullptr, beta, D_, H_, 1);
  gemv_smallN<<<BL, blk, 0, stream>>>(hs, Wres, bres, resg, D_, H_, 1);
  // 4. l2norm
  l2norm_inplace<<<BL * H_, blk, 0, stream>>>(b3);
  l2norm_inplace<<<BL * H_, blk, 0, stream>>>(b0);
  // 5-6. delta rule
  chunk_uw<<<B_ * H_ * NCH, blk, 0, stream>>>(b3, b0, b1, beta, b2, b4, attn);
  delta_scan<<<256, blk, 0, stream>>>(b3, b0, b2, b4, attn, b2);
  // 7. local convs
  dwconv_tiled<64><<<1024, blk, 0, stream>>>(b1, fir_long, b3, 0);
  dwconv_tiled<5><<<1024, blk, 0, stream>>>(b1, fir_short, b4, 0);
  // 8. stats16
  head_stats_k<<<BL, blk, 0, stream>>>(b4, stats16, 16, 0);
  head_stats_k<<<BL, blk, 0, stream>>>(b3, stats16, 16, 4);
  head_stats_k<<<BL, blk, 0, stream>>>(b2, stats16, 16, 8);
  head_stats_k<<<BL, blk, 0, stream>>>(b1, stats16, 16, 12);
  // 9. gate hidden
  gemm_bf16<<<dim3(8, 64), blk, 0, stream>>>(hsb, wtg1, b0, 1024);
  tail_bias_gelu<<<(BL * D_) / 256, blk, 0, stream>>>(b0, stats16, Wg1 + 1024L * 1024, bg1, D_, 16);
  // 10. logits, p
  gemv_smallN<<<BL, blk, 0, stream>>>(b0, Wg2, bg2, logits, D_, 4, 0);
  softmax_p<<<BL / 256, blk, 0, stream>>>(logits, logit_temp, pbuf);
  // 11. combine -> b0
  combine<<<BLD / 256, blk, 0, stream>>>(b4, b3, b2, b1, pbuf, resg, conv_res_logit, b0);
  // 12. og stats
  head_stats_k<<<BL, blk, 0, stream>>>(b0, og8, 8, 0);
  head_stats_k<<<BL, blk, 0, stream>>>(b1, og8, 8, 4);
  // 13. output gate
  gemm_bf16<<<dim3(4, 64), blk, 0, stream>>>(hsb, wtog1, b2, 512);
  tail_bias_gelu<<<(BL * 512) / 256, blk, 0, stream>>>(b2, og8, Wog1 + 1024L * 512, bog1, 512, 8);
  gemv_smallN<<<BL, blk, 0, stream>>>(b2, Wog2, bog2, ogv, 512, 1, 1);
  // 14. scale + rmsnorm
  scale_rmsnorm<<<BL * H_, blk, 0, stream>>>(b0, ogv, norm_w);
  // 15. final projection
  cvt_bf16<<<BLD / 1024, blk, 0, stream>>>(b0, xb, BLD);
  gemm_bf16<<<dim3(8, 64), blk, 0, stream>>>(xb, wto, out, 1024);
}

// Round 6
// 1870.951 us; speedup vs baseline: 7.7807x; 1.0321x over previous
//
#include <hip/hip_runtime.h>
#include <math.h>

#define B_ 2
#define L_ 4096
#define D_ 1024
#define H_ 4
#define DH 256
#define CHUNKSZ 32
#define NCH (L_/CHUNKSZ)      // 128
#define BL (B_*L_)            // 8192
#define BLD (B_*L_*D_)        // 8388608

typedef __attribute__((ext_vector_type(8))) short bf16x8;
typedef __attribute__((ext_vector_type(4))) float f32x4;

__device__ __forceinline__ float sigmf(float x) { return 1.f / (1.f + expf(-x)); }
__device__ __forceinline__ float geluf(float x) { return 0.5f * x * (1.f + erff(x * 0.70710678118654752f)); }
__device__ __forceinline__ unsigned short f2bf(float f) {
  unsigned int u = __float_as_uint(f);
  unsigned int r = (u + 0x7FFFu + ((u >> 16) & 1u)) >> 16;
  return (unsigned short)r;
}

// ---------------- f32 -> bf16 elementwise (n multiple of 4) ----------------
__global__ __launch_bounds__(256)
void cvt_bf16(const float* __restrict__ x, unsigned short* __restrict__ y, long n) {
  long i = ((long)blockIdx.x * 256 + threadIdx.x) * 4;
  if (i >= n) return;
  float4 v = *reinterpret_cast<const float4*>(&x[i]);
  ushort4 o;
  o.x = f2bf(v.x); o.y = f2bf(v.y); o.z = f2bf(v.z); o.w = f2bf(v.w);
  *reinterpret_cast<ushort4*>(&y[i]) = o;
}

// ---------------- W[k][n] f32 -> Wt[n][k] bf16 (32x32 tiles) ----------------
__global__ __launch_bounds__(256)
void wconv_t(const float* __restrict__ W, unsigned short* __restrict__ Wt, int N) {
  __shared__ float tile[32][33];
  int kb = blockIdx.y * 32, nb = blockIdx.x * 32;
  int tx = threadIdx.x & 31, ty = threadIdx.x >> 5;
  for (int i = 0; i < 32; i += 8)
    tile[ty + i][tx] = W[(long)(kb + ty + i) * N + nb + tx];
  __syncthreads();
  for (int i = 0; i < 32; i += 8)
    Wt[(long)(nb + ty + i) * 1024 + kb + tx] = f2bf(tile[tx][ty + i]);
}

// ---------------- bf16 MFMA GEMM: C[8192][N] = A[8192][1024] @ Bt[N][1024]^T ----------------
__global__ __launch_bounds__(256)
void gemm_bf16(const unsigned short* __restrict__ A, const unsigned short* __restrict__ Bt,
               float* __restrict__ C, int N) {
  __shared__ unsigned short Al[128 * 32];
  __shared__ unsigned short Bl[128 * 32];
  const int K = 1024;
  int bm = blockIdx.y * 128, bn = blockIdx.x * 128;
  int tid = threadIdx.x;
  int lane = tid & 63, wid = tid >> 6;
  int wr = wid >> 1, wc = wid & 1;
  int l15 = lane & 15, l4 = lane >> 4;
  f32x4 acc[4][4];
#pragma unroll
  for (int i = 0; i < 4; ++i)
#pragma unroll
    for (int j = 0; j < 4; ++j) { acc[i][j].x = 0.f; acc[i][j].y = 0.f; acc[i][j].z = 0.f; acc[i][j].w = 0.f; }
  for (int k0 = 0; k0 < K; k0 += 32) {
    __syncthreads();
#pragma unroll
    for (int i = 0; i < 2; ++i) {
      int idx = tid + i * 256;
      int r = idx >> 2, sl = idx & 3;
      int s = sl ^ ((r >> 1) & 3);
      uint4 av = *reinterpret_cast<const uint4*>(&A[(long)(bm + r) * K + k0 + sl * 8]);
      *reinterpret_cast<uint4*>(&Al[r * 32 + s * 8]) = av;
      uint4 bv = *reinterpret_cast<const uint4*>(&Bt[(long)(bn + r) * K + k0 + sl * 8]);
      *reinterpret_cast<uint4*>(&Bl[r * 32 + s * 8]) = bv;
    }
    __syncthreads();
    bf16x8 af[4], bfr[4];
#pragma unroll
    for (int fi = 0; fi < 4; ++fi) {
      int r = wr * 64 + fi * 16 + l15;
      af[fi] = *reinterpret_cast<const bf16x8*>(&Al[r * 32 + (l4 ^ ((r >> 1) & 3)) * 8]);
    }
#pragma unroll
    for (int fj = 0; fj < 4; ++fj) {
      int r = wc * 64 + fj * 16 + l15;
      bfr[fj] = *reinterpret_cast<const bf16x8*>(&Bl[r * 32 + (l4 ^ ((r >> 1) & 3)) * 8]);
    }
#pragma unroll
    for (int fi = 0; fi < 4; ++fi)
#pragma unroll
      for (int fj = 0; fj < 4; ++fj)
        acc[fi][fj] = __builtin_amdgcn_mfma_f32_16x16x32_bf16(af[fi], bfr[fj], acc[fi][fj], 0, 0, 0);
  }
#pragma unroll
  for (int fi = 0; fi < 4; ++fi) {
    int rb = bm + wr * 64 + fi * 16 + l4 * 4;
#pragma unroll
    for (int fj = 0; fj < 4; ++fj) {
      int cb = bn + wc * 64 + fj * 16 + l15;
#pragma unroll
      for (int j = 0; j < 4; ++j)
        C[(long)(rb + j) * N + cb] = acc[fi][fj][j];
    }
  }
}

// ---------------- tiled depthwise causal conv (+ optional silu), K templated ----------------
#define CTL 128
template<int K>
__global__ __launch_bounds__(256)
void dwconv_tiled(const float* __restrict__ x, const float* __restrict__ w,
                  float* __restrict__ y, int do_silu) {
  __shared__ float tile[(CTL + K - 1) * 64];
  int bid = blockIdx.x;
  int ct = bid & 15;
  int lt = (bid >> 4) & 31;
  int b  = bid >> 9;
  int c0 = ct * 64;
  int l0 = lt * CTL;
  int tid = threadIdx.x;
  const int rows = CTL + K - 1;
  for (int i = tid; i < rows * 16; i += 256) {
    int rr = i >> 4, c4 = i & 15;
    int l = l0 - (K - 1) + rr;
    float4 v = make_float4(0.f, 0.f, 0.f, 0.f);
    if (l >= 0) v = *reinterpret_cast<const float4*>(&x[((long)b * L_ + l) * D_ + c0 + c4 * 4]);
    *reinterpret_cast<float4*>(&tile[rr * 64 + c4 * 4]) = v;
  }
  __syncthreads();
  int c = tid & 63;
  int lo0 = tid >> 6;
  float wreg[K];
#pragma unroll
  for (int j = 0; j < K; ++j) wreg[j] = w[(long)(c0 + c) * K + j];
  for (int lo = lo0; lo < CTL; lo += 4) {
    float acc = 0.f;
#pragma unroll
    for (int j = 0; j < K; ++j)
      acc = fmaf(wreg[j], tile[(lo + j) * 64 + c], acc);
    if (do_silu) acc = acc * sigmf(acc);
    y[((long)b * L_ + l0 + lo) * D_ + c0 + c] = acc;
  }
}

// ---------------- small-N GEMV ----------------
__global__ __launch_bounds__(256)
void gemv_smallN(const float* __restrict__ X, const float* __restrict__ W,
                 const float* __restrict__ bias, float* __restrict__ out,
                 int K, int N, int act) {
  __shared__ float red[256];
  long m = blockIdx.x;
  const float* x = X + m * K;
  for (int n = 0; n < N; ++n) {
    float s = 0.f;
    for (int k = threadIdx.x; k < K; k += 256) s += x[k] * W[(long)k * N + n];
    red[threadIdx.x] = s;
    __syncthreads();
    for (int st = 128; st > 0; st >>= 1) {
      if (threadIdx.x < st) red[threadIdx.x] += red[threadIdx.x + st];
      __syncthreads();
    }
    if (threadIdx.x == 0) {
      float v = red[0] + (bias ? bias[n] : 0.f);
      if (act == 1) v = sigmf(v);
      out[m * N + n] = v;
    }
    __syncthreads();
  }
}

// ---------------- l2norm in place over rows of 256 ----------------
__global__ __launch_bounds__(256)
void l2norm_inplace(float* __restrict__ x) {
  __shared__ float red[256];
  long row = blockIdx.x;
  float v = x[row * 256 + threadIdx.x];
  red[threadIdx.x] = v * v;
  __syncthreads();
  for (int st = 128; st > 0; st >>= 1) {
    if (threadIdx.x < st) red[threadIdx.x] += red[threadIdx.x + st];
    __syncthreads();
  }
  float inv = rsqrtf(red[0] + 1e-6f);
  x[row * 256 + threadIdx.x] = v * inv;
}

// ---------------- per-chunk: inv, u, w, attn ----------------
__global__ __launch_bounds__(256)
void chunk_uw(const float* __restrict__ qn, const float* __restrict__ kn,
              const float* __restrict__ v, const float* __restrict__ beta,
              float* __restrict__ u, float* __restrict__ w, float* __restrict__ attn) {
  __shared__ float skT[256][33];
  __shared__ float sinv[32][33];
  __shared__ float sbeta[32];
  int blk = blockIdx.x;
  int ci = blk % NCH;
  int bh = blk / NCH;
  int h = bh % H_;
  int b = bh / H_;
  long base = ((long)b * L_ + (long)ci * CHUNKSZ) * D_ + h * DH;
  long brow = (long)b * L_ + (long)ci * CHUNKSZ;
  int tid = threadIdx.x;
  for (int i = tid; i < 32 * 256; i += 256) {
    int r = i >> 8, c = i & 255;
    skT[c][r] = kn[base + (long)r * D_ + c];
  }
  if (tid < 32) sbeta[tid] = beta[(brow + tid) * H_ + h];
  __syncthreads();
  int j = tid & 31, i0 = tid >> 5;
  for (int r = 0; r < 4; ++r) {
    int i = i0 + (r << 3);
    float acc = 0.f;
    for (int d = 0; d < 256; ++d) acc += skT[d][i] * skT[d][j];
    sinv[i][j] = (i > j) ? -acc * sbeta[i] : 0.f;
  }
  __syncthreads();
  for (int i = 1; i < 32; ++i) {
    float val = 0.f;
    if (tid < 32) {
      for (int t = 0; t < i; ++t) val += sinv[i][t] * sinv[t][tid];
    }
    __syncthreads();
    if (tid < 32) sinv[i][tid] += val;
    __syncthreads();
  }
  if (tid < 32) sinv[tid][tid] += 1.f;
  long attn_base = (long)blk * 1024;
  for (int r = 0; r < 4; ++r) {
    int i = i0 + (r << 3);
    const float* qrow = qn + base + (long)i * D_;
    float acc = 0.f;
    for (int d = 0; d < 256; ++d) acc += qrow[d] * skT[d][j];
    attn[attn_base + i * 32 + j] = (i >= j) ? acc : 0.f;
  }
  __syncthreads();
  int c = tid;
  float vt[32], kt[32];
#pragma unroll
  for (int t = 0; t < 32; ++t) {
    vt[t] = v[base + t * D_ + c] * sbeta[t];
    kt[t] = skT[c][t] * sbeta[t];
  }
#pragma unroll
  for (int i2 = 0; i2 < 32; ++i2) {
    float au = 0.f, aw = 0.f;
#pragma unroll
    for (int t = 0; t <= i2; ++t) {
      float f = sinv[i2][t];
      au += f * vt[t];
      aw += f * kt[t];
    }
    u[base + i2 * D_ + c] = au;
    w[base + i2 * D_ + c] = aw;
  }
}

// ---------------- sequential scan; block = (b,h, colgroup of 8); 256 blocks ----------------
// 2 barriers/chunk; staging writes overlapped with compute phases:
//   phase1 reads {sS, sq, swl}; phase2 reads {sS, skl, sat, su2}
//   -> write next sq/swl during phase2; write next skl/sat during next phase1.
// `out` may alias `u` (different chunks / disjoint cols). No __restrict__ on u/out.
__global__ __launch_bounds__(256, 1)
void delta_scan(const float* __restrict__ qn, const float* __restrict__ kn,
                const float* u, const float* __restrict__ w,
                const float* __restrict__ attn, float* out) {
  __shared__ float4 sS[64 * 8];       // [d4][c]
  __shared__ float4 sq[32 * 65];      // [r][d4] pad 65
  __shared__ float4 swl[32 * 65];
  __shared__ float4 skl[32 * 65];
  __shared__ float  sat[32 * 36];     // [r][t] pad 36
  __shared__ float  su2[32 * 9];      // [t][c] pad 9
  int blk = blockIdx.x;
  int bh = blk & 7;
  int cg = blk >> 3;
  int h = bh & 3, b = bh >> 2;
  int col0 = cg * 8;
  int tid = threadIdx.x;
  int c = tid & 7, r = tid >> 3;       // 32 rows x 8 cols; note tid == r*8+c
  sS[tid] = make_float4(0.f, 0.f, 0.f, 0.f);
  sS[tid + 256] = make_float4(0.f, 0.f, 0.f, 0.f);

  float4 pq[8], pw[8], pk[8], pat;
  float pu;
  long abase0 = (long)bh * NCH * 1024;

#define STAGE_LOAD(CI) do {                                                     \
    long nb = ((long)b * L_ + (long)(CI) * CHUNKSZ) * D_ + h * DH;              \
    _Pragma("unroll")                                                           \
    for (int j = 0; j < 8; ++j) {                                               \
      int idx = j * 256 + tid;                                                  \
      int rr = idx >> 6, d4 = idx & 63;                                         \
      pq[j] = reinterpret_cast<const float4*>(qn + nb + (long)rr * D_)[d4];     \
      pw[j] = reinterpret_cast<const float4*>(w  + nb + (long)rr * D_)[d4];     \
      pk[j] = reinterpret_cast<const float4*>(kn + nb + (long)rr * D_)[d4];     \
    }                                                                           \
    pat = reinterpret_cast<const float4*>(attn + abase0 + (long)(CI) * 1024)[tid]; \
    pu = u[nb + (long)r * D_ + col0 + c];                                       \
  } while (0)

#define WRITE_QW() do {                                                         \
    _Pragma("unroll")                                                           \
    for (int j = 0; j < 8; ++j) {                                               \
      int idx = j * 256 + tid;                                                  \
      int rr = idx >> 6, d4 = idx & 63;                                         \
      sq[rr * 65 + d4] = pq[j];                                                 \
      swl[rr * 65 + d4] = pw[j];                                                \
    }                                                                           \
  } while (0)

#define WRITE_KA() do {                                                         \
    _Pragma("unroll")                                                           \
    for (int j = 0; j < 8; ++j) {                                               \
      int idx = j * 256 + tid;                                                  \
      int rr = idx >> 6, d4 = idx & 63;                                         \
      skl[rr * 65 + d4] = pk[j];                                                \
    }                                                                           \
    { int ra = tid >> 3, ca = tid & 7;                                          \
      *reinterpret_cast<float4*>(&sat[ra * 36 + ca * 4]) = pat; }               \
  } while (0)

  STAGE_LOAD(0);
  WRITE_QW();
  WRITE_KA();
  float pu_cur = pu;
  __syncthreads();

  for (int ci = 0; ci < NCH; ++ci) {
    long base = ((long)b * L_ + (long)ci * CHUNKSZ) * D_ + h * DH;
    bool more = (ci + 1 < NCH);
    if (more) STAGE_LOAD(ci + 1);
    // ---- phase 1: w@S and q@S for (row r, col c) ----
    float aw = 0.f, aq = 0.f;
#pragma unroll 8
    for (int d4 = 0; d4 < 64; ++d4) {
      float4 s = sS[d4 * 8 + c];
      float4 wv = swl[r * 65 + d4];
      float4 qv = sq[r * 65 + d4];
      aw = fmaf(wv.x, s.x, fmaf(wv.y, s.y, fmaf(wv.z, s.z, fmaf(wv.w, s.w, aw))));
      aq = fmaf(qv.x, s.x, fmaf(qv.y, s.y, fmaf(qv.z, s.z, fmaf(qv.w, s.w, aq))));
    }
    su2[r * 9 + c] = pu_cur - aw;
    __syncthreads();
    // ---- phase 2 (merged): out = q@S + attn@u2 ; S += k^T @ u2 ----
    float o = aq;
    float4 s0 = sS[tid];
    float4 s1 = sS[tid + 256];
#pragma unroll 8
    for (int t = 0; t < 32; ++t) {
      float uv = su2[t * 9 + c];
      o = fmaf(sat[r * 36 + t], uv, o);
      float4 k0 = skl[t * 65 + r];
      float4 k1 = skl[t * 65 + r + 32];
      s0.x = fmaf(k0.x, uv, s0.x); s0.y = fmaf(k0.y, uv, s0.y);
      s0.z = fmaf(k0.z, uv, s0.z); s0.w = fmaf(k0.w, uv, s0.w);
      s1.x = fmaf(k1.x, uv, s1.x); s1.y = fmaf(k1.y, uv, s1.y);
      s1.z = fmaf(k1.z, uv, s1.z); s1.w = fmaf(k1.w, uv, s1.w);
    }
    out[base + (long)r * D_ + col0 + c] = o;
    sS[tid] = s0;
    sS[tid + 256] = s1;
    if (more) WRITE_QW();          // next chunk's q/w: phase1 done (bar above)
    __syncthreads();
    if (more) {                    // next chunk's k/attn: phase2 done (bar above);
      WRITE_KA();                  // overlaps next phase1 (which doesn't read them)
      pu_cur = pu;
    }
  }
#undef STAGE_LOAD
#undef WRITE_QW
#undef WRITE_KA
}

// ---------------- head stats ----------------
__global__ __launch_bounds__(256)
void head_stats_k(const float* __restrict__ x, float* __restrict__ out,
                  int ostride, int ooff) {
  __shared__ float rs[256], rq[256], ra[256];
  long bl = blockIdx.x;
  int tid = threadIdx.x;
  float m_acc = 0, v_acc = 0, a_acc = 0, l_acc = 0;
  for (int h = 0; h < H_; ++h) {
    float v = x[bl * D_ + h * DH + tid];
    rs[tid] = v; rq[tid] = v * v; ra[tid] = fabsf(v);
    __syncthreads();
    for (int st = 128; st > 0; st >>= 1) {
      if (tid < st) { rs[tid] += rs[tid + st]; rq[tid] += rq[tid + st]; ra[tid] += ra[tid + st]; }
      __syncthreads();
    }
    if (tid == 0) {
      float mean = rs[0] / 256.f;
      m_acc += mean;
      v_acc += rq[0] / 256.f - mean * mean;
      a_acc += ra[0] / 256.f;
      l_acc += sqrtf(rq[0]);
    }
    __syncthreads();
  }
  if (tid == 0) {
    float* o = out + bl * ostride + ooff;
    o[0] = m_acc / H_; o[1] = v_acc / H_; o[2] = a_acc / H_; o[3] = l_acc / H_;
  }
}

// ---------------- g = gelu(g + bias + stats @ Wtail) ----------------
__global__ __launch_bounds__(256)
void tail_bias_gelu(float* __restrict__ g, const float* __restrict__ stats,
                    const float* __restrict__ Wt, const float* __restrict__ bias,
                    int N, int K2) {
  long idx = (long)blockIdx.x * 256 + threadIdx.x;
  if (idx >= (long)BL * N) return;
  int n = idx % N;
  long m = idx / N;
  float s = g[idx] + bias[n];
  for (int k = 0; k < K2; ++k) s += stats[m * K2 + k] * Wt[(long)k * N + n];
  g[idx] = geluf(s);
}

// ---------------- softmax with temp, clip, renorm ----------------
__global__ __launch_bounds__(256)
void softmax_p(const float* __restrict__ logits, const float* __restrict__ temp_in,
               float* __restrict__ p) {
  int bl = blockIdx.x * 256 + threadIdx.x;
  if (bl >= BL) return;
  float temp = log1pf(expf(temp_in[0]));
  float l0 = logits[bl * 4 + 0] / temp, l1 = logits[bl * 4 + 1] / temp;
  float l2 = logits[bl * 4 + 2] / temp, l3 = logits[bl * 4 + 3] / temp;
  float mx = fmaxf(fmaxf(l0, l1), fmaxf(l2, l3));
  float e0 = expf(l0 - mx), e1 = expf(l1 - mx), e2 = expf(l2 - mx), e3 = expf(l3 - mx);
  float s = e0 + e1 + e2 + e3;
  e0 /= s; e1 /= s; e2 /= s; e3 /= s;
  e0 = fmaxf(e0, 0.02f); e1 = fmaxf(e1, 0.02f); e2 = fmaxf(e2, 0.02f); e3 = fmaxf(e3, 0.02f);
  s = e0 + e1 + e2 + e3;
  p[bl * 4 + 0] = e0 / s; p[bl * 4 + 1] = e1 / s; p[bl * 4 + 2] = e2 / s; p[bl * 4 + 3] = e3 / s;
}

// ---------------- mixture combine + conv residual ----------------
__global__ __launch_bounds__(256)
void combine(const float* __restrict__ ls, const float* __restrict__ ll,
             const float* __restrict__ dd, const float* __restrict__ vd,
             const float* __restrict__ p, const float* __restrict__ resg,
             const float* __restrict__ crl, float* __restrict__ o) {
  int idx = blockIdx.x * 256 + threadIdx.x;
  if (idx >= BLD) return;
  int c = idx % D_;
  long bl = idx / D_;
  int h = c >> 8;
  const float* pp = p + bl * 4;
  float sgate = sigmf(crl[h]) * resg[bl * H_ + h];
  o[idx] = pp[0] * ls[idx] + pp[1] * ll[idx] + pp[2] * dd[idx] + pp[3] * vd[idx] + sgate * ls[idx];
}

// ---------------- o = rmsnorm(o * og) * norm_w ----------------
__global__ __launch_bounds__(256)
void scale_rmsnorm(float* __restrict__ o, const float* __restrict__ og,
                   const float* __restrict__ nw) {
  __shared__ float red[256];
  long row = blockIdx.x;
  long bl = row >> 2;
  int tid = threadIdx.x;
  float v = o[row * 256 + tid] * og[bl];
  red[tid] = v * v;
  __syncthreads();
  for (int st = 128; st > 0; st >>= 1) {
    if (tid < st) red[tid] += red[tid + st];
    __syncthreads();
  }
  float scale = rsqrtf(red[0] / 256.f + 1e-5f);
  o[row * 256 + tid] = v * scale * nw[tid];
}

extern "C" void kernel_launch(void* const* d_in, const int* in_sizes, int n_in,
                              void* d_out, int out_size, void* d_ws, size_t ws_size,
                              hipStream_t stream) {
  const float* hs       = (const float*)d_in[0];
  const float* Wq       = (const float*)d_in[1];
  const float* Wk       = (const float*)d_in[2];
  const float* Wv       = (const float*)d_in[3];
  const float* Wb       = (const float*)d_in[4];
  const float* wq_conv  = (const float*)d_in[5];
  const float* wk_conv  = (const float*)d_in[6];
  const float* wv_conv  = (const float*)d_in[7];
  const float* fir_long = (const float*)d_in[8];
  const float* fir_short= (const float*)d_in[9];
  const float* Wg1      = (const float*)d_in[10];
  const float* bg1      = (const float*)d_in[11];
  const float* Wg2      = (const float*)d_in[12];
  const float* bg2      = (const float*)d_in[13];
  const float* logit_temp     = (const float*)d_in[14];
  const float* conv_res_logit = (const float*)d_in[15];
  const float* Wres     = (const float*)d_in[16];
  const float* bres     = (const float*)d_in[17];
  const float* Wog1     = (const float*)d_in[18];
  const float* bog1     = (const float*)d_in[19];
  const float* Wog2     = (const float*)d_in[20];
  const float* bog2     = (const float*)d_in[21];
  const float* norm_w   = (const float*)d_in[22];
  const float* Wo       = (const float*)d_in[23];
  float* out = (float*)d_out;
  float* ws = (float*)d_ws;

  float* b0 = ws;             // qlin -> kn -> gate_hidden -> o_mix
  float* b1 = ws + 1L * BLD;  // klin -> v_in (v_direct)
  float* b2 = ws + 2L * BLD;  // vlin -> u -> delta_out -> og_hidden
  float* b3 = ws + 3L * BLD;  // qn -> local_long
  float* b4 = ws + 4L * BLD;  // w -> local_short
  float* sm = ws + 5L * BLD;
  float* beta    = sm;
  float* resg    = beta + BL * H_;
  float* stats16 = resg + BL * H_;
  float* og8     = stats16 + BL * 16;
  float* logits  = og8 + BL * 8;
  float* pbuf    = logits + BL * 4;
  float* ogv     = pbuf + BL * 4;
  float* attn    = ogv + BL;                        // 1M floats
  unsigned short* hsb  = (unsigned short*)(attn + (long)B_ * H_ * NCH * 1024);
  unsigned short* xb   = hsb + (long)BLD;
  unsigned short* wtq  = xb + (long)BLD;
  unsigned short* wtk  = wtq + 1024L * 1024;
  unsigned short* wtv  = wtk + 1024L * 1024;
  unsigned short* wtg1 = wtv + 1024L * 1024;
  unsigned short* wto  = wtg1 + 1024L * 1024;
  unsigned short* wtog1= wto + 1024L * 1024;

  size_t needed = (5L * BLD + BL * 41 + (long)B_ * H_ * NCH * 1024) * 4
                + (2L * BLD + 5L * 1024 * 1024 + 512L * 1024) * 2;
  if (ws_size < needed) return;

  dim3 blk(256);
  // 0. preconvert
  wconv_t<<<dim3(32, 32), blk, 0, stream>>>(Wq, wtq, 1024);
  wconv_t<<<dim3(32, 32), blk, 0, stream>>>(Wk, wtk, 1024);
  wconv_t<<<dim3(32, 32), blk, 0, stream>>>(Wv, wtv, 1024);
  wconv_t<<<dim3(32, 32), blk, 0, stream>>>(Wg1, wtg1, 1024);
  wconv_t<<<dim3(32, 32), blk, 0, stream>>>(Wo, wto, 1024);
  wconv_t<<<dim3(16, 32), blk, 0, stream>>>(Wog1, wtog1, 512);
  cvt_bf16<<<BLD / 1024, blk, 0, stream>>>(hs, hsb, BLD);
  // 1. projections
  gemm_bf16<<<dim3(8, 64), blk, 0, stream>>>(hsb, wtq, b0, 1024);
  gemm_bf16<<<dim3(8, 64), blk, 0, stream>>>(hsb, wtk, b1, 1024);
  gemm_bf16<<<dim3(8, 64), blk, 0, stream>>>(hsb, wtv, b2, 1024);
  // 2. conv + silu (tiled)
  dwconv_tiled<4><<<1024, blk, 0, stream>>>(b0, wq_conv, b3, 1);
  dwconv_tiled<4><<<1024, blk, 0, stream>>>(b1, wk_conv, b0, 1);
  dwconv_tiled<4><<<1024, blk, 0, stream>>>(b2, wv_conv, b1, 1);
  // 3. beta, res gate
  gemv_smallN<<<BL, blk, 0, stream>>>(hs, Wb, nullptr, beta, D_, H_, 1);
  gemv_smallN<<<BL, blk, 0, stream>>>(hs, Wres, bres, resg, D_, H_, 1);
  // 4. l2norm
  l2norm_inplace<<<BL * H_, blk, 0, stream>>>(b3);
  l2norm_inplace<<<BL * H_, blk, 0, stream>>>(b0);
  // 5-6. delta rule
  chunk_uw<<<B_ * H_ * NCH, blk, 0, stream>>>(b3, b0, b1, beta, b2, b4, attn);
  delta_scan<<<256, blk, 0, stream>>>(b3, b0, b2, b4, attn, b2);
  // 7. local convs
  dwconv_tiled<64><<<1024, blk, 0, stream>>>(b1, fir_long, b3, 0);
  dwconv_tiled<5><<<1024, blk, 0, stream>>>(b1, fir_short, b4, 0);
  // 8. stats16
  head_stats_k<<<BL, blk, 0, stream>>>(b4, stats16, 16, 0);
  head_stats_k<<<BL, blk, 0, stream>>>(b3, stats16, 16, 4);
  head_stats_k<<<BL, blk, 0, stream>>>(b2, stats16, 16, 8);
  head_stats_k<<<BL, blk, 0, stream>>>(b1, stats16, 16, 12);
  // 9. gate hidden
  gemm_bf16<<<dim3(8, 64), blk, 0, stream>>>(hsb, wtg1, b0, 1024);
  tail_bias_gelu<<<(BL * D_) / 256, blk, 0, stream>>>(b0, stats16, Wg1 + 1024L * 1024, bg1, D_, 16);
  // 10. logits, p
  gemv_smallN<<<BL, blk, 0, stream>>>(b0, Wg2, bg2, logits, D_, 4, 0);
  softmax_p<<<BL / 256, blk, 0, stream>>>(logits, logit_temp, pbuf);
  // 11. combine -> b0
  combine<<<BLD / 256, blk, 0, stream>>>(b4, b3, b2, b1, pbuf, resg, conv_res_logit, b0);
  // 12. og stats
  head_stats_k<<<BL, blk, 0, stream>>>(b0, og8, 8, 0);
  head_stats_k<<<BL, blk, 0, stream>>>(b1, og8, 8, 4);
  // 13. output gate
  gemm_bf16<<<dim3(4, 64), blk, 0, stream>>>(hsb, wtog1, b2, 512);
  tail_bias_gelu<<<(BL * 512) / 256, blk, 0, stream>>>(b2, og8, Wog1 + 1024L * 512, bog1, 512, 8);
  gemv_smallN<<<BL, blk, 0, stream>>>(b2, Wog2, bog2, ogv, 512, 1, 1);
  // 14. scale + rmsnorm
  scale_rmsnorm<<<BL * H_, blk, 0, stream>>>(b0, ogv, norm_w);
  // 15. final projection
  cvt_bf16<<<BLD / 1024, blk, 0, stream>>>(b0, xb, BLD);
  gemm_bf16<<<dim3(8, 64), blk, 0, stream>>>(xb, wto, out, 1024);
}

// Round 7
// 1370.099 us; speedup vs baseline: 10.6250x; 1.3656x over previous
//
#include <hip/hip_runtime.h>
#include <math.h>

#define B_ 2
#define L_ 4096
#define D_ 1024
#define H_ 4
#define DH 256
#define CHUNKSZ 32
#define NCH (L_/CHUNKSZ)      // 128
#define BL (B_*L_)            // 8192
#define BLD (B_*L_*D_)        // 8388608

typedef __attribute__((ext_vector_type(8))) short bf16x8;
typedef __attribute__((ext_vector_type(4))) float f32x4;

__device__ __forceinline__ float sigmf(float x) { return 1.f / (1.f + expf(-x)); }
__device__ __forceinline__ float geluf(float x) { return 0.5f * x * (1.f + erff(x * 0.70710678118654752f)); }
__device__ __forceinline__ unsigned short f2bf(float f) {
  unsigned int u = __float_as_uint(f);
  unsigned int r = (u + 0x7FFFu + ((u >> 16) & 1u)) >> 16;
  return (unsigned short)r;
}
__device__ __forceinline__ unsigned int pk2bf(float a, float b) {
  return ((unsigned int)f2bf(b) << 16) | (unsigned int)f2bf(a);
}

// ---------------- f32 -> bf16 elementwise (n multiple of 4) ----------------
__global__ __launch_bounds__(256)
void cvt_bf16(const float* __restrict__ x, unsigned short* __restrict__ y, long n) {
  long i = ((long)blockIdx.x * 256 + threadIdx.x) * 4;
  if (i >= n) return;
  float4 v = *reinterpret_cast<const float4*>(&x[i]);
  ushort4 o;
  o.x = f2bf(v.x); o.y = f2bf(v.y); o.z = f2bf(v.z); o.w = f2bf(v.w);
  *reinterpret_cast<ushort4*>(&y[i]) = o;
}

// ---------------- W[k][n] f32 -> Wt[n][k] bf16 (32x32 tiles) ----------------
__global__ __launch_bounds__(256)
void wconv_t(const float* __restrict__ W, unsigned short* __restrict__ Wt, int N) {
  __shared__ float tile[32][33];
  int kb = blockIdx.y * 32, nb = blockIdx.x * 32;
  int tx = threadIdx.x & 31, ty = threadIdx.x >> 5;
  for (int i = 0; i < 32; i += 8)
    tile[ty + i][tx] = W[(long)(kb + ty + i) * N + nb + tx];
  __syncthreads();
  for (int i = 0; i < 32; i += 8)
    Wt[(long)(nb + ty + i) * 1024 + kb + tx] = f2bf(tile[tx][ty + i]);
}

// ---------------- bf16 MFMA GEMM: C[8192][N] = A[8192][1024] @ Bt[N][1024]^T ----------------
__global__ __launch_bounds__(256)
void gemm_bf16(const unsigned short* __restrict__ A, const unsigned short* __restrict__ Bt,
               float* __restrict__ C, int N) {
  __shared__ unsigned short Al[128 * 32];
  __shared__ unsigned short Bl[128 * 32];
  const int K = 1024;
  int bm = blockIdx.y * 128, bn = blockIdx.x * 128;
  int tid = threadIdx.x;
  int lane = tid & 63, wid = tid >> 6;
  int wr = wid >> 1, wc = wid & 1;
  int l15 = lane & 15, l4 = lane >> 4;
  f32x4 acc[4][4];
#pragma unroll
  for (int i = 0; i < 4; ++i)
#pragma unroll
    for (int j = 0; j < 4; ++j) { acc[i][j].x = 0.f; acc[i][j].y = 0.f; acc[i][j].z = 0.f; acc[i][j].w = 0.f; }
  for (int k0 = 0; k0 < K; k0 += 32) {
    __syncthreads();
#pragma unroll
    for (int i = 0; i < 2; ++i) {
      int idx = tid + i * 256;
      int r = idx >> 2, sl = idx & 3;
      int s = sl ^ ((r >> 1) & 3);
      uint4 av = *reinterpret_cast<const uint4*>(&A[(long)(bm + r) * K + k0 + sl * 8]);
      *reinterpret_cast<uint4*>(&Al[r * 32 + s * 8]) = av;
      uint4 bv = *reinterpret_cast<const uint4*>(&Bt[(long)(bn + r) * K + k0 + sl * 8]);
      *reinterpret_cast<uint4*>(&Bl[r * 32 + s * 8]) = bv;
    }
    __syncthreads();
    bf16x8 af[4], bfr[4];
#pragma unroll
    for (int fi = 0; fi < 4; ++fi) {
      int r = wr * 64 + fi * 16 + l15;
      af[fi] = *reinterpret_cast<const bf16x8*>(&Al[r * 32 + (l4 ^ ((r >> 1) & 3)) * 8]);
    }
#pragma unroll
    for (int fj = 0; fj < 4; ++fj) {
      int r = wc * 64 + fj * 16 + l15;
      bfr[fj] = *reinterpret_cast<const bf16x8*>(&Bl[r * 32 + (l4 ^ ((r >> 1) & 3)) * 8]);
    }
#pragma unroll
    for (int fi = 0; fi < 4; ++fi)
#pragma unroll
      for (int fj = 0; fj < 4; ++fj)
        acc[fi][fj] = __builtin_amdgcn_mfma_f32_16x16x32_bf16(af[fi], bfr[fj], acc[fi][fj], 0, 0, 0);
  }
#pragma unroll
  for (int fi = 0; fi < 4; ++fi) {
    int rb = bm + wr * 64 + fi * 16 + l4 * 4;
#pragma unroll
    for (int fj = 0; fj < 4; ++fj) {
      int cb = bn + wc * 64 + fj * 16 + l15;
#pragma unroll
      for (int j = 0; j < 4; ++j)
        C[(long)(rb + j) * N + cb] = acc[fi][fj][j];
    }
  }
}

// ---------------- tiled depthwise causal conv (+ optional silu), K templated ----------------
#define CTL 128
template<int K>
__global__ __launch_bounds__(256)
void dwconv_tiled(const float* __restrict__ x, const float* __restrict__ w,
                  float* __restrict__ y, int do_silu) {
  __shared__ float tile[(CTL + K - 1) * 64];
  int bid = blockIdx.x;
  int ct = bid & 15;
  int lt = (bid >> 4) & 31;
  int b  = bid >> 9;
  int c0 = ct * 64;
  int l0 = lt * CTL;
  int tid = threadIdx.x;
  const int rows = CTL + K - 1;
  for (int i = tid; i < rows * 16; i += 256) {
    int rr = i >> 4, c4 = i & 15;
    int l = l0 - (K - 1) + rr;
    float4 v = make_float4(0.f, 0.f, 0.f, 0.f);
    if (l >= 0) v = *reinterpret_cast<const float4*>(&x[((long)b * L_ + l) * D_ + c0 + c4 * 4]);
    *reinterpret_cast<float4*>(&tile[rr * 64 + c4 * 4]) = v;
  }
  __syncthreads();
  int c = tid & 63;
  int lo0 = tid >> 6;
  float wreg[K];
#pragma unroll
  for (int j = 0; j < K; ++j) wreg[j] = w[(long)(c0 + c) * K + j];
  for (int lo = lo0; lo < CTL; lo += 4) {
    float acc = 0.f;
#pragma unroll
    for (int j = 0; j < K; ++j)
      acc = fmaf(wreg[j], tile[(lo + j) * 64 + c], acc);
    if (do_silu) acc = acc * sigmf(acc);
    y[((long)b * L_ + l0 + lo) * D_ + c0 + c] = acc;
  }
}

// ---------------- small-N GEMV ----------------
__global__ __launch_bounds__(256)
void gemv_smallN(const float* __restrict__ X, const float* __restrict__ W,
                 const float* __restrict__ bias, float* __restrict__ out,
                 int K, int N, int act) {
  __shared__ float red[256];
  long m = blockIdx.x;
  const float* x = X + m * K;
  for (int n = 0; n < N; ++n) {
    float s = 0.f;
    for (int k = threadIdx.x; k < K; k += 256) s += x[k] * W[(long)k * N + n];
    red[threadIdx.x] = s;
    __syncthreads();
    for (int st = 128; st > 0; st >>= 1) {
      if (threadIdx.x < st) red[threadIdx.x] += red[threadIdx.x + st];
      __syncthreads();
    }
    if (threadIdx.x == 0) {
      float v = red[0] + (bias ? bias[n] : 0.f);
      if (act == 1) v = sigmf(v);
      out[m * N + n] = v;
    }
    __syncthreads();
  }
}

// ---------------- l2norm in place over rows of 256 ----------------
__global__ __launch_bounds__(256)
void l2norm_inplace(float* __restrict__ x) {
  __shared__ float red[256];
  long row = blockIdx.x;
  float v = x[row * 256 + threadIdx.x];
  red[threadIdx.x] = v * v;
  __syncthreads();
  for (int st = 128; st > 0; st >>= 1) {
    if (threadIdx.x < st) red[threadIdx.x] += red[threadIdx.x + st];
    __syncthreads();
  }
  float inv = rsqrtf(red[0] + 1e-6f);
  x[row * 256 + threadIdx.x] = v * inv;
}

// ---------------- per-chunk: inv, u (f32), and bf16 operands for the scan ----------------
// emits: u f32 [B,L,D]; q_bf [bh][ci][32][256]; w_bf same; kT_bf [bh][ci][256][32]; at_bf [bh][ci][32][32]
__global__ __launch_bounds__(256)
void chunk_uw(const float* __restrict__ qn, const float* __restrict__ kn,
              const float* __restrict__ v, const float* __restrict__ beta,
              float* __restrict__ u,
              unsigned short* __restrict__ q_bf, unsigned short* __restrict__ w_bf,
              unsigned short* __restrict__ kT_bf, unsigned short* __restrict__ at_bf) {
  __shared__ float skT[256][33];
  __shared__ float sinv[32][33];
  __shared__ float sbeta[32];
  int blk = blockIdx.x;
  int ci = blk % NCH;
  int bh = blk / NCH;
  int h = bh % H_;
  int b = bh / H_;
  long base = ((long)b * L_ + (long)ci * CHUNKSZ) * D_ + h * DH;
  long brow = (long)b * L_ + (long)ci * CHUNKSZ;
  long obase = (long)blk * 8192;   // blk == bh*NCH+ci
  int tid = threadIdx.x;
  for (int i = tid; i < 32 * 256; i += 256) {
    int r = i >> 8, c = i & 255;
    skT[c][r] = kn[base + (long)r * D_ + c];
  }
  if (tid < 32) sbeta[tid] = beta[(brow + tid) * H_ + h];
  __syncthreads();
  // kT_bf [d][t]
  for (int i = tid; i < 8192; i += 256)
    kT_bf[obase + i] = f2bf(skT[i >> 5][i & 31]);
  // q_bf [r][d]
  for (int i = tid; i < 8192; i += 256)
    q_bf[obase + i] = f2bf(qn[base + (long)(i >> 8) * D_ + (i & 255)]);
  int j = tid & 31, i0 = tid >> 5;
  for (int r = 0; r < 4; ++r) {
    int i = i0 + (r << 3);
    float acc = 0.f;
    for (int d = 0; d < 256; ++d) acc += skT[d][i] * skT[d][j];
    sinv[i][j] = (i > j) ? -acc * sbeta[i] : 0.f;
  }
  __syncthreads();
  for (int i = 1; i < 32; ++i) {
    float val = 0.f;
    if (tid < 32) {
      for (int t = 0; t < i; ++t) val += sinv[i][t] * sinv[t][tid];
    }
    __syncthreads();
    if (tid < 32) sinv[i][tid] += val;
    __syncthreads();
  }
  if (tid < 32) sinv[tid][tid] += 1.f;
  // attn bf16 = (qn @ kn^T) * lower_incl
  long abase = (long)blk * 1024;
  for (int r = 0; r < 4; ++r) {
    int i = i0 + (r << 3);
    const float* qrow = qn + base + (long)i * D_;
    float acc = 0.f;
    for (int d = 0; d < 256; ++d) acc += qrow[d] * skT[d][j];
    at_bf[abase + i * 32 + j] = f2bf((i >= j) ? acc : 0.f);
  }
  __syncthreads();
  int c = tid;
  float vt[32], kt[32];
#pragma unroll
  for (int t = 0; t < 32; ++t) {
    vt[t] = v[base + t * D_ + c] * sbeta[t];
    kt[t] = skT[c][t] * sbeta[t];
  }
#pragma unroll
  for (int i2 = 0; i2 < 32; ++i2) {
    float au = 0.f, aw = 0.f;
#pragma unroll
    for (int t = 0; t <= i2; ++t) {
      float f = sinv[i2][t];
      au += f * vt[t];
      aw += f * kt[t];
    }
    u[base + i2 * D_ + c] = au;
    w_bf[obase + i2 * 256 + c] = f2bf(aw);
  }
}

// ---------------- MFMA sequential scan; block = (bh, colgroup of 8); 256 blocks ----------------
// S[256x16] stays f32 in MFMA accumulators (cols 8-15 identically zero).
// Per chunk: wS,qS partials per wave (own 64-d slice) -> reduce -> u2 ->
// out = qS + attn@u2 (MFMA, C-in=qS) ; S += kT@u2 (MFMA into acc).
// `out` may alias `u` (u[ci+1] loads issued before out[ci] stores; disjoint cols across blocks).
__global__ __launch_bounds__(256, 1)
void delta_scan(const unsigned short* __restrict__ qb, const unsigned short* __restrict__ wbf,
                const unsigned short* __restrict__ ktb, const unsigned short* __restrict__ atb,
                const float* u, float* out) {
  __shared__ unsigned short q_l[2][32 * 264];
  __shared__ unsigned short w_l[2][32 * 264];
  __shared__ unsigned short kT_l[2][256 * 40];
  __shared__ unsigned short at_l[2][32 * 40];
  __shared__ float u_l[2][32 * 16];
  __shared__ float sS[4][16 * 64];     // per-wave S^T [col][row-4blk ^ col]
  __shared__ float pw[4][2][16 * 20];  // [wave][m][col][row]
  __shared__ float pq[4][2][16 * 20];
  __shared__ float qt[2][16 * 20];
  __shared__ unsigned short u2_l[16 * 40];  // u2^T [col][t]

  int blk = blockIdx.x;
  int bh = blk & 7, cg = blk >> 3;
  int h = bh & 3, b = bh >> 2;
  int col0 = cg * 8;
  int tid = threadIdx.x;
  int g = tid >> 6, lane = tid & 63;
  int l15 = lane & 15, l4 = lane >> 4;
  float* sSg = sS[g];

  f32x4 acc[4];
#pragma unroll
  for (int t = 0; t < 4; ++t) { acc[t].x = 0.f; acc[t].y = 0.f; acc[t].z = 0.f; acc[t].w = 0.f; }

  uint4 rq[4], rw[4], rk[4], rat;
  f32x4 ru;
  f32x4 zero4; zero4.x = 0.f; zero4.y = 0.f; zero4.z = 0.f; zero4.w = 0.f;

#define SLOAD(CI) do {                                                          \
    long cb8 = ((long)bh * NCH + (CI)) * 8192;                                  \
    _Pragma("unroll")                                                           \
    for (int jj = 0; jj < 4; ++jj) {                                            \
      int gi = jj * 256 + tid;                                                  \
      rq[jj] = *reinterpret_cast<const uint4*>(&qb [cb8 + (gi >> 5) * 256 + (gi & 31) * 8]); \
      rw[jj] = *reinterpret_cast<const uint4*>(&wbf[cb8 + (gi >> 5) * 256 + (gi & 31) * 8]); \
      rk[jj] = *reinterpret_cast<const uint4*>(&ktb[cb8 + (gi >> 2) * 32 + (gi & 3) * 8]);   \
    }                                                                           \
    if (tid < 128)                                                              \
      rat = *reinterpret_cast<const uint4*>(&atb[((long)bh * NCH + (CI)) * 1024 + (tid >> 2) * 32 + (tid & 3) * 8]); \
    if (tid < 64) {                                                             \
      long ub = ((long)b * L_ + (long)(CI) * CHUNKSZ) * D_ + h * DH;            \
      ru = *reinterpret_cast<const f32x4*>(&u[ub + (long)(tid >> 1) * D_ + col0 + (tid & 1) * 4]); \
    }                                                                           \
  } while (0)

#define SWRITE(NB) do {                                                         \
    _Pragma("unroll")                                                           \
    for (int jj = 0; jj < 4; ++jj) {                                            \
      int gi = jj * 256 + tid;                                                  \
      *reinterpret_cast<uint4*>(&q_l[NB][(gi >> 5) * 264 + (gi & 31) * 8]) = rq[jj]; \
      *reinterpret_cast<uint4*>(&w_l[NB][(gi >> 5) * 264 + (gi & 31) * 8]) = rw[jj]; \
      *reinterpret_cast<uint4*>(&kT_l[NB][(gi >> 2) * 40 + (gi & 3) * 8]) = rk[jj]; \
    }                                                                           \
    if (tid < 128)                                                              \
      *reinterpret_cast<uint4*>(&at_l[NB][(tid >> 2) * 40 + (tid & 3) * 8]) = rat; \
    if (tid < 64)                                                               \
      *reinterpret_cast<f32x4*>(&u_l[NB][(tid >> 1) * 16 + (tid & 1) * 4]) = ru; \
    else if (tid < 128) {                                                       \
      int t2 = tid - 64;                                                        \
      *reinterpret_cast<f32x4*>(&u_l[NB][(t2 >> 1) * 16 + 8 + (t2 & 1) * 4]) = zero4; \
    }                                                                           \
  } while (0)

  SLOAD(0);
  SWRITE(0);
  __syncthreads();

  for (int ci = 0; ci < NCH; ++ci) {
    int cur = ci & 1, nb = cur ^ 1;
    bool more = (ci + 1 < NCH);
    if (more) SLOAD(ci + 1);
    // phase 0: S tiles -> wave-local LDS (swizzled col-major)
#pragma unroll
    for (int t = 0; t < 4; ++t) {
      int r4s = (t * 4 + l4) ^ l15;
      *reinterpret_cast<f32x4*>(&sSg[l15 * 64 + r4s * 4]) = acc[t];
    }
    // phase A: partial wS, qS over own 64-d slice
    f32x4 pwa[2], pqa[2];
#pragma unroll
    for (int m = 0; m < 2; ++m) { pwa[m] = zero4; pqa[m] = zero4; }
#pragma unroll
    for (int kkl = 0; kkl < 2; ++kkl) {
      int r4a = kkl * 8 + l4 * 2;
      f32x4 s0 = *reinterpret_cast<f32x4*>(&sSg[l15 * 64 + (r4a ^ l15) * 4]);
      f32x4 s1 = *reinterpret_cast<f32x4*>(&sSg[l15 * 64 + ((r4a + 1) ^ l15) * 4]);
      uint4 sp;
      sp.x = pk2bf(s0.x, s0.y); sp.y = pk2bf(s0.z, s0.w);
      sp.z = pk2bf(s1.x, s1.y); sp.w = pk2bf(s1.z, s1.w);
      bf16x8 sf = *reinterpret_cast<bf16x8*>(&sp);
      int dcol = 64 * g + kkl * 32 + l4 * 8;
#pragma unroll
      for (int m = 0; m < 2; ++m) {
        bf16x8 wf = *reinterpret_cast<bf16x8*>(&w_l[cur][(16 * m + l15) * 264 + dcol]);
        bf16x8 qf = *reinterpret_cast<bf16x8*>(&q_l[cur][(16 * m + l15) * 264 + dcol]);
        pwa[m] = __builtin_amdgcn_mfma_f32_16x16x32_bf16(wf, sf, pwa[m], 0, 0, 0);
        pqa[m] = __builtin_amdgcn_mfma_f32_16x16x32_bf16(qf, sf, pqa[m], 0, 0, 0);
      }
    }
#pragma unroll
    for (int m = 0; m < 2; ++m) {
      *reinterpret_cast<f32x4*>(&pw[g][m][l15 * 20 + l4 * 4]) = pwa[m];
      *reinterpret_cast<f32x4*>(&pq[g][m][l15 * 20 + l4 * 4]) = pqa[m];
    }
    __syncthreads();
    // reduce: u2 = u - sum_g wS ; qt = sum_g qS ; u2 -> bf16 [col][t]
#pragma unroll
    for (int rr = 0; rr < 2; ++rr) {
      int idx = rr * 256 + tid;
      int t = idx >> 4, col = idx & 15;
      int m = t >> 4, tr = t & 15;
      int po = col * 20 + tr;
      float wsum = pw[0][m][po] + pw[1][m][po] + pw[2][m][po] + pw[3][m][po];
      float qsum = pq[0][m][po] + pq[1][m][po] + pq[2][m][po] + pq[3][m][po];
      qt[m][po] = qsum;
      float u2v = u_l[cur][t * 16 + col] - wsum;
      u2_l[col * 40 + t] = f2bf(u2v);
    }
    __syncthreads();
    // phase B (waves 0,1): out = qt + attn@u2 ; phase C (all): S += kT@u2
    bf16x8 u2f = *reinterpret_cast<bf16x8*>(&u2_l[l15 * 40 + l4 * 8]);
    if (g < 2) {
      int m = g;
      f32x4 cin = *reinterpret_cast<f32x4*>(&qt[m][l15 * 20 + l4 * 4]);
      bf16x8 af = *reinterpret_cast<bf16x8*>(&at_l[cur][(16 * m + l15) * 40 + l4 * 8]);
      f32x4 dv = __builtin_amdgcn_mfma_f32_16x16x32_bf16(af, u2f, cin, 0, 0, 0);
      if (l15 < 8) {
        long ob = ((long)b * L_ + (long)ci * CHUNKSZ) * D_ + h * DH;
#pragma unroll
        for (int reg = 0; reg < 4; ++reg)
          out[ob + (long)(16 * m + l4 * 4 + reg) * D_ + col0 + l15] = dv[reg];
      }
    }
#pragma unroll
    for (int t = 0; t < 4; ++t) {
      bf16x8 kf = *reinterpret_cast<bf16x8*>(&kT_l[cur][(64 * g + 16 * t + l15) * 40 + l4 * 8]);
      acc[t] = __builtin_amdgcn_mfma_f32_16x16x32_bf16(kf, u2f, acc[t], 0, 0, 0);
    }
    if (more) SWRITE(nb);
    __syncthreads();
  }
#undef SLOAD
#undef SWRITE
}

// ---------------- head stats ----------------
__global__ __launch_bounds__(256)
void head_stats_k(const float* __restrict__ x, float* __restrict__ out,
                  int ostride, int ooff) {
  __shared__ float rs[256], rq[256], ra[256];
  long bl = blockIdx.x;
  int tid = threadIdx.x;
  float m_acc = 0, v_acc = 0, a_acc = 0, l_acc = 0;
  for (int h = 0; h < H_; ++h) {
    float v = x[bl * D_ + h * DH + tid];
    rs[tid] = v; rq[tid] = v * v; ra[tid] = fabsf(v);
    __syncthreads();
    for (int st = 128; st > 0; st >>= 1) {
      if (tid < st) { rs[tid] += rs[tid + st]; rq[tid] += rq[tid + st]; ra[tid] += ra[tid + st]; }
      __syncthreads();
    }
    if (tid == 0) {
      float mean = rs[0] / 256.f;
      m_acc += mean;
      v_acc += rq[0] / 256.f - mean * mean;
      a_acc += ra[0] / 256.f;
      l_acc += sqrtf(rq[0]);
    }
    __syncthreads();
  }
  if (tid == 0) {
    float* o = out + bl * ostride + ooff;
    o[0] = m_acc / H_; o[1] = v_acc / H_; o[2] = a_acc / H_; o[3] = l_acc / H_;
  }
}

// ---------------- g = gelu(g + bias + stats @ Wtail) ----------------
__global__ __launch_bounds__(256)
void tail_bias_gelu(float* __restrict__ g, const float* __restrict__ stats,
                    const float* __restrict__ Wt, const float* __restrict__ bias,
                    int N, int K2) {
  long idx = (long)blockIdx.x * 256 + threadIdx.x;
  if (idx >= (long)BL * N) return;
  int n = idx % N;
  long m = idx / N;
  float s = g[idx] + bias[n];
  for (int k = 0; k < K2; ++k) s += stats[m * K2 + k] * Wt[(long)k * N + n];
  g[idx] = geluf(s);
}

// ---------------- softmax with temp, clip, renorm ----------------
__global__ __launch_bounds__(256)
void softmax_p(const float* __restrict__ logits, const float* __restrict__ temp_in,
               float* __restrict__ p) {
  int bl = blockIdx.x * 256 + threadIdx.x;
  if (bl >= BL) return;
  float temp = log1pf(expf(temp_in[0]));
  float l0 = logits[bl * 4 + 0] / temp, l1 = logits[bl * 4 + 1] / temp;
  float l2 = logits[bl * 4 + 2] / temp, l3 = logits[bl * 4 + 3] / temp;
  float mx = fmaxf(fmaxf(l0, l1), fmaxf(l2, l3));
  float e0 = expf(l0 - mx), e1 = expf(l1 - mx), e2 = expf(l2 - mx), e3 = expf(l3 - mx);
  float s = e0 + e1 + e2 + e3;
  e0 /= s; e1 /= s; e2 /= s; e3 /= s;
  e0 = fmaxf(e0, 0.02f); e1 = fmaxf(e1, 0.02f); e2 = fmaxf(e2, 0.02f); e3 = fmaxf(e3, 0.02f);
  s = e0 + e1 + e2 + e3;
  p[bl * 4 + 0] = e0 / s; p[bl * 4 + 1] = e1 / s; p[bl * 4 + 2] = e2 / s; p[bl * 4 + 3] = e3 / s;
}

// ---------------- mixture combine + conv residual ----------------
__global__ __launch_bounds__(256)
void combine(const float* __restrict__ ls, const float* __restrict__ ll,
             const float* __restrict__ dd, const float* __restrict__ vd,
             const float* __restrict__ p, const float* __restrict__ resg,
             const float* __restrict__ crl, float* __restrict__ o) {
  int idx = blockIdx.x * 256 + threadIdx.x;
  if (idx >= BLD) return;
  int c = idx % D_;
  long bl = idx / D_;
  int h = c >> 8;
  const float* pp = p + bl * 4;
  float sgate = sigmf(crl[h]) * resg[bl * H_ + h];
  o[idx] = pp[0] * ls[idx] + pp[1] * ll[idx] + pp[2] * dd[idx] + pp[3] * vd[idx] + sgate * ls[idx];
}

// ---------------- o = rmsnorm(o * og) * norm_w ----------------
__global__ __launch_bounds__(256)
void scale_rmsnorm(float* __restrict__ o, const float* __restrict__ og,
                   const float* __restrict__ nw) {
  __shared__ float red[256];
  long row = blockIdx.x;
  long bl = row >> 2;
  int tid = threadIdx.x;
  float v = o[row * 256 + tid] * og[bl];
  red[tid] = v * v;
  __syncthreads();
  for (int st = 128; st > 0; st >>= 1) {
    if (tid < st) red[tid] += red[tid + st];
    __syncthreads();
  }
  float scale = rsqrtf(red[0] / 256.f + 1e-5f);
  o[row * 256 + tid] = v * scale * nw[tid];
}

extern "C" void kernel_launch(void* const* d_in, const int* in_sizes, int n_in,
                              void* d_out, int out_size, void* d_ws, size_t ws_size,
                              hipStream_t stream) {
  const float* hs       = (const float*)d_in[0];
  const float* Wq       = (const float*)d_in[1];
  const float* Wk       = (const float*)d_in[2];
  const float* Wv       = (const float*)d_in[3];
  const float* Wb       = (const float*)d_in[4];
  const float* wq_conv  = (const float*)d_in[5];
  const float* wk_conv  = (const float*)d_in[6];
  const float* wv_conv  = (const float*)d_in[7];
  const float* fir_long = (const float*)d_in[8];
  const float* fir_short= (const float*)d_in[9];
  const float* Wg1      = (const float*)d_in[10];
  const float* bg1      = (const float*)d_in[11];
  const float* Wg2      = (const float*)d_in[12];
  const float* bg2      = (const float*)d_in[13];
  const float* logit_temp     = (const float*)d_in[14];
  const float* conv_res_logit = (const float*)d_in[15];
  const float* Wres     = (const float*)d_in[16];
  const float* bres     = (const float*)d_in[17];
  const float* Wog1     = (const float*)d_in[18];
  const float* bog1     = (const float*)d_in[19];
  const float* Wog2     = (const float*)d_in[20];
  const float* bog2     = (const float*)d_in[21];
  const float* norm_w   = (const float*)d_in[22];
  const float* Wo       = (const float*)d_in[23];
  float* out = (float*)d_out;
  float* ws = (float*)d_ws;

  float* b0 = ws;             // qlin -> kn -> gate_hidden -> o_mix
  float* b1 = ws + 1L * BLD;  // klin -> v_in (v_direct)
  float* b2 = ws + 2L * BLD;  // vlin -> u -> delta_out -> og_hidden
  float* b3 = ws + 3L * BLD;  // qn -> local_long
  float* b4 = ws + 4L * BLD;  // w_bf (bf16, first half) -> local_short
  float* sm = ws + 5L * BLD;
  float* beta    = sm;
  float* resg    = beta + BL * H_;
  float* stats16 = resg + BL * H_;
  float* og8     = stats16 + BL * 16;
  float* logits  = og8 + BL * 8;
  float* pbuf    = logits + BL * 4;
  float* ogv     = pbuf + BL * 4;
  unsigned short* q_bfg  = (unsigned short*)(ogv + BL);   // BLD bf16
  unsigned short* kT_bfg = q_bfg + (long)BLD;             // BLD bf16
  unsigned short* at_bfg = kT_bfg + (long)BLD;            // 1M bf16
  unsigned short* hsb  = at_bfg + 1024L * 1024;           // BLD bf16
  unsigned short* wtq  = hsb + (long)BLD;
  unsigned short* wtk  = wtq + 1024L * 1024;
  unsigned short* wtv  = wtk + 1024L * 1024;
  unsigned short* wtg1 = wtv + 1024L * 1024;
  unsigned short* wto  = wtg1 + 1024L * 1024;
  unsigned short* wtog1= wto + 1024L * 1024;
  unsigned short* w_bfg = (unsigned short*)b4;            // bf16 w inside b4
  unsigned short* xb    = q_bfg;                          // reuse (q_bf dead after scan)

  size_t needed = (5L * BLD + BL * 41) * 4
                + (3L * BLD + 1024L * 1024 + 5L * 1024 * 1024 + 512L * 1024) * 2;
  if (ws_size < needed) return;

  dim3 blk(256);
  // 0. preconvert
  wconv_t<<<dim3(32, 32), blk, 0, stream>>>(Wq, wtq, 1024);
  wconv_t<<<dim3(32, 32), blk, 0, stream>>>(Wk, wtk, 1024);
  wconv_t<<<dim3(32, 32), blk, 0, stream>>>(Wv, wtv, 1024);
  wconv_t<<<dim3(32, 32), blk, 0, stream>>>(Wg1, wtg1, 1024);
  wconv_t<<<dim3(32, 32), blk, 0, stream>>>(Wo, wto, 1024);
  wconv_t<<<dim3(16, 32), blk, 0, stream>>>(Wog1, wtog1, 512);
  cvt_bf16<<<BLD / 1024, blk, 0, stream>>>(hs, hsb, BLD);
  // 1. projections
  gemm_bf16<<<dim3(8, 64), blk, 0, stream>>>(hsb, wtq, b0, 1024);
  gemm_bf16<<<dim3(8, 64), blk, 0, stream>>>(hsb, wtk, b1, 1024);
  gemm_bf16<<<dim3(8, 64), blk, 0, stream>>>(hsb, wtv, b2, 1024);
  // 2. conv + silu (tiled)
  dwconv_tiled<4><<<1024, blk, 0, stream>>>(b0, wq_conv, b3, 1);
  dwconv_tiled<4><<<1024, blk, 0, stream>>>(b1, wk_conv, b0, 1);
  dwconv_tiled<4><<<1024, blk, 0, stream>>>(b2, wv_conv, b1, 1);
  // 3. beta, res gate
  gemv_smallN<<<BL, blk, 0, stream>>>(hs, Wb, nullptr, beta, D_, H_, 1);
  gemv_smallN<<<BL, blk, 0, stream>>>(hs, Wres, bres, resg, D_, H_, 1);
  // 4. l2norm
  l2norm_inplace<<<BL * H_, blk, 0, stream>>>(b3);
  l2norm_inplace<<<BL * H_, blk, 0, stream>>>(b0);
  // 5-6. delta rule (u->b2; bf16 operands; scan writes delta_out in place over u)
  chunk_uw<<<B_ * H_ * NCH, blk, 0, stream>>>(b3, b0, b1, beta, b2, q_bfg, w_bfg, kT_bfg, at_bfg);
  delta_scan<<<256, blk, 0, stream>>>(q_bfg, w_bfg, kT_bfg, at_bfg, b2, b2);
  // 7. local convs
  dwconv_tiled<64><<<1024, blk, 0, stream>>>(b1, fir_long, b3, 0);
  dwconv_tiled<5><<<1024, blk, 0, stream>>>(b1, fir_short, b4, 0);
  // 8. stats16
  head_stats_k<<<BL, blk, 0, stream>>>(b4, stats16, 16, 0);
  head_stats_k<<<BL, blk, 0, stream>>>(b3, stats16, 16, 4);
  head_stats_k<<<BL, blk, 0, stream>>>(b2, stats16, 16, 8);
  head_stats_k<<<BL, blk, 0, stream>>>(b1, stats16, 16, 12);
  // 9. gate hidden
  gemm_bf16<<<dim3(8, 64), blk, 0, stream>>>(hsb, wtg1, b0, 1024);
  tail_bias_gelu<<<(BL * D_) / 256, blk, 0, stream>>>(b0, stats16, Wg1 + 1024L * 1024, bg1, D_, 16);
  // 10. logits, p
  gemv_smallN<<<BL, blk, 0, stream>>>(b0, Wg2, bg2, logits, D_, 4, 0);
  softmax_p<<<BL / 256, blk, 0, stream>>>(logits, logit_temp, pbuf);
  // 11. combine -> b0
  combine<<<BLD / 256, blk, 0, stream>>>(b4, b3, b2, b1, pbuf, resg, conv_res_logit, b0);
  // 12. og stats
  head_stats_k<<<BL, blk, 0, stream>>>(b0, og8, 8, 0);
  head_stats_k<<<BL, blk, 0, stream>>>(b1, og8, 8, 4);
  // 13. output gate
  gemm_bf16<<<dim3(4, 64), blk, 0, stream>>>(hsb, wtog1, b2, 512);
  tail_bias_gelu<<<(BL * 512) / 256, blk, 0, stream>>>(b2, og8, Wog1 + 1024L * 512, bog1, 512, 8);
  gemv_smallN<<<BL, blk, 0, stream>>>(b2, Wog2, bog2, ogv, 512, 1, 1);
  // 14. scale + rmsnorm
  scale_rmsnorm<<<BL * H_, blk, 0, stream>>>(b0, ogv, norm_w);
  // 15. final projection
  cvt_bf16<<<BLD / 1024, blk, 0, stream>>>(b0, xb, BLD);
  gemm_bf16<<<dim3(8, 64), blk, 0, stream>>>(xb, wto, out, 1024);
}

// Round 8
// 1313.364 us; speedup vs baseline: 11.0840x; 1.0432x over previous
//
#include <hip/hip_runtime.h>
#include <math.h>

#define B_ 2
#define L_ 4096
#define D_ 1024
#define H_ 4
#define DH 256
#define CHUNKSZ 32
#define NCH (L_/CHUNKSZ)      // 128
#define BL (B_*L_)            // 8192
#define BLD (B_*L_*D_)        // 8388608

typedef __attribute__((ext_vector_type(8))) short bf16x8;
typedef __attribute__((ext_vector_type(4))) float f32x4;

__device__ __forceinline__ float sigmf(float x) { return 1.f / (1.f + expf(-x)); }
__device__ __forceinline__ float geluf(float x) { return 0.5f * x * (1.f + erff(x * 0.70710678118654752f)); }
__device__ __forceinline__ unsigned short f2bf(float f) {
  unsigned int u = __float_as_uint(f);
  unsigned int r = (u + 0x7FFFu + ((u >> 16) & 1u)) >> 16;
  return (unsigned short)r;
}
__device__ __forceinline__ unsigned int pk2bf(float a, float b) {
  return ((unsigned int)f2bf(b) << 16) | (unsigned int)f2bf(a);
}

// ---------------- f32 -> bf16 elementwise (n multiple of 4) ----------------
__global__ __launch_bounds__(256)
void cvt_bf16(const float* __restrict__ x, unsigned short* __restrict__ y, long n) {
  long i = ((long)blockIdx.x * 256 + threadIdx.x) * 4;
  if (i >= n) return;
  float4 v = *reinterpret_cast<const float4*>(&x[i]);
  ushort4 o;
  o.x = f2bf(v.x); o.y = f2bf(v.y); o.z = f2bf(v.z); o.w = f2bf(v.w);
  *reinterpret_cast<ushort4*>(&y[i]) = o;
}

// ---------------- W[k][n] f32 -> Wt[n][k] bf16 (32x32 tiles) ----------------
__global__ __launch_bounds__(256)
void wconv_t(const float* __restrict__ W, unsigned short* __restrict__ Wt, int N) {
  __shared__ float tile[32][33];
  int kb = blockIdx.y * 32, nb = blockIdx.x * 32;
  int tx = threadIdx.x & 31, ty = threadIdx.x >> 5;
  for (int i = 0; i < 32; i += 8)
    tile[ty + i][tx] = W[(long)(kb + ty + i) * N + nb + tx];
  __syncthreads();
  for (int i = 0; i < 32; i += 8)
    Wt[(long)(nb + ty + i) * 1024 + kb + tx] = f2bf(tile[tx][ty + i]);
}

// ---------------- bf16 MFMA GEMM: C[8192][N] = A[8192][1024] @ Bt[N][1024]^T ----------------
__global__ __launch_bounds__(256)
void gemm_bf16(const unsigned short* __restrict__ A, const unsigned short* __restrict__ Bt,
               float* __restrict__ C, int N) {
  __shared__ unsigned short Al[128 * 32];
  __shared__ unsigned short Bl[128 * 32];
  const int K = 1024;
  int bm = blockIdx.y * 128, bn = blockIdx.x * 128;
  int tid = threadIdx.x;
  int lane = tid & 63, wid = tid >> 6;
  int wr = wid >> 1, wc = wid & 1;
  int l15 = lane & 15, l4 = lane >> 4;
  f32x4 acc[4][4];
#pragma unroll
  for (int i = 0; i < 4; ++i)
#pragma unroll
    for (int j = 0; j < 4; ++j) { acc[i][j].x = 0.f; acc[i][j].y = 0.f; acc[i][j].z = 0.f; acc[i][j].w = 0.f; }
  for (int k0 = 0; k0 < K; k0 += 32) {
    __syncthreads();
#pragma unroll
    for (int i = 0; i < 2; ++i) {
      int idx = tid + i * 256;
      int r = idx >> 2, sl = idx & 3;
      int s = sl ^ ((r >> 1) & 3);
      uint4 av = *reinterpret_cast<const uint4*>(&A[(long)(bm + r) * K + k0 + sl * 8]);
      *reinterpret_cast<uint4*>(&Al[r * 32 + s * 8]) = av;
      uint4 bv = *reinterpret_cast<const uint4*>(&Bt[(long)(bn + r) * K + k0 + sl * 8]);
      *reinterpret_cast<uint4*>(&Bl[r * 32 + s * 8]) = bv;
    }
    __syncthreads();
    bf16x8 af[4], bfr[4];
#pragma unroll
    for (int fi = 0; fi < 4; ++fi) {
      int r = wr * 64 + fi * 16 + l15;
      af[fi] = *reinterpret_cast<const bf16x8*>(&Al[r * 32 + (l4 ^ ((r >> 1) & 3)) * 8]);
    }
#pragma unroll
    for (int fj = 0; fj < 4; ++fj) {
      int r = wc * 64 + fj * 16 + l15;
      bfr[fj] = *reinterpret_cast<const bf16x8*>(&Bl[r * 32 + (l4 ^ ((r >> 1) & 3)) * 8]);
    }
#pragma unroll
    for (int fi = 0; fi < 4; ++fi)
#pragma unroll
      for (int fj = 0; fj < 4; ++fj)
        acc[fi][fj] = __builtin_amdgcn_mfma_f32_16x16x32_bf16(af[fi], bfr[fj], acc[fi][fj], 0, 0, 0);
  }
#pragma unroll
  for (int fi = 0; fi < 4; ++fi) {
    int rb = bm + wr * 64 + fi * 16 + l4 * 4;
#pragma unroll
    for (int fj = 0; fj < 4; ++fj) {
      int cb = bn + wc * 64 + fj * 16 + l15;
#pragma unroll
      for (int j = 0; j < 4; ++j)
        C[(long)(rb + j) * N + cb] = acc[fi][fj][j];
    }
  }
}

// ---------------- tiled depthwise causal conv (+ optional silu), K templated ----------------
#define CTL 128
template<int K>
__global__ __launch_bounds__(256)
void dwconv_tiled(const float* __restrict__ x, const float* __restrict__ w,
                  float* __restrict__ y, int do_silu) {
  __shared__ float tile[(CTL + K - 1) * 64];
  int bid = blockIdx.x;
  int ct = bid & 15;
  int lt = (bid >> 4) & 31;
  int b  = bid >> 9;
  int c0 = ct * 64;
  int l0 = lt * CTL;
  int tid = threadIdx.x;
  const int rows = CTL + K - 1;
  for (int i = tid; i < rows * 16; i += 256) {
    int rr = i >> 4, c4 = i & 15;
    int l = l0 - (K - 1) + rr;
    float4 v = make_float4(0.f, 0.f, 0.f, 0.f);
    if (l >= 0) v = *reinterpret_cast<const float4*>(&x[((long)b * L_ + l) * D_ + c0 + c4 * 4]);
    *reinterpret_cast<float4*>(&tile[rr * 64 + c4 * 4]) = v;
  }
  __syncthreads();
  int c = tid & 63;
  int lo0 = tid >> 6;
  float wreg[K];
#pragma unroll
  for (int j = 0; j < K; ++j) wreg[j] = w[(long)(c0 + c) * K + j];
  for (int lo = lo0; lo < CTL; lo += 4) {
    float acc = 0.f;
#pragma unroll
    for (int j = 0; j < K; ++j)
      acc = fmaf(wreg[j], tile[(lo + j) * 64 + c], acc);
    if (do_silu) acc = acc * sigmf(acc);
    y[((long)b * L_ + l0 + lo) * D_ + c0 + c] = acc;
  }
}

// ---------------- small-N GEMV ----------------
__global__ __launch_bounds__(256)
void gemv_smallN(const float* __restrict__ X, const float* __restrict__ W,
                 const float* __restrict__ bias, float* __restrict__ out,
                 int K, int N, int act) {
  __shared__ float red[256];
  long m = blockIdx.x;
  const float* x = X + m * K;
  for (int n = 0; n < N; ++n) {
    float s = 0.f;
    for (int k = threadIdx.x; k < K; k += 256) s += x[k] * W[(long)k * N + n];
    red[threadIdx.x] = s;
    __syncthreads();
    for (int st = 128; st > 0; st >>= 1) {
      if (threadIdx.x < st) red[threadIdx.x] += red[threadIdx.x + st];
      __syncthreads();
    }
    if (threadIdx.x == 0) {
      float v = red[0] + (bias ? bias[n] : 0.f);
      if (act == 1) v = sigmf(v);
      out[m * N + n] = v;
    }
    __syncthreads();
  }
}

// ---------------- l2norm in place over rows of 256 ----------------
__global__ __launch_bounds__(256)
void l2norm_inplace(float* __restrict__ x) {
  __shared__ float red[256];
  long row = blockIdx.x;
  float v = x[row * 256 + threadIdx.x];
  red[threadIdx.x] = v * v;
  __syncthreads();
  for (int st = 128; st > 0; st >>= 1) {
    if (threadIdx.x < st) red[threadIdx.x] += red[threadIdx.x + st];
    __syncthreads();
  }
  float inv = rsqrtf(red[0] + 1e-6f);
  x[row * 256 + threadIdx.x] = v * inv;
}

// ---------------- per-chunk: inv, u (f32), and bf16 operands for the scan ----------------
// emits: u f32 [B,L,D]; q_bf [bh][ci][32][256]; w_bf same; kT_bf [bh][ci][256][32]; at_bf [bh][ci][32][32]
__global__ __launch_bounds__(256)
void chunk_uw(const float* __restrict__ qn, const float* __restrict__ kn,
              const float* __restrict__ v, const float* __restrict__ beta,
              float* __restrict__ u,
              unsigned short* __restrict__ q_bf, unsigned short* __restrict__ w_bf,
              unsigned short* __restrict__ kT_bf, unsigned short* __restrict__ at_bf) {
  __shared__ float skT[256][33];
  __shared__ float sinv[32][33];
  __shared__ float sbeta[32];
  int blk = blockIdx.x;
  int ci = blk % NCH;
  int bh = blk / NCH;
  int h = bh % H_;
  int b = bh / H_;
  long base = ((long)b * L_ + (long)ci * CHUNKSZ) * D_ + h * DH;
  long brow = (long)b * L_ + (long)ci * CHUNKSZ;
  long obase = (long)blk * 8192;   // blk == bh*NCH+ci
  int tid = threadIdx.x;
  for (int i = tid; i < 32 * 256; i += 256) {
    int r = i >> 8, c = i & 255;
    skT[c][r] = kn[base + (long)r * D_ + c];
  }
  if (tid < 32) sbeta[tid] = beta[(brow + tid) * H_ + h];
  __syncthreads();
  // kT_bf [d][t]
  for (int i = tid; i < 8192; i += 256)
    kT_bf[obase + i] = f2bf(skT[i >> 5][i & 31]);
  // q_bf [r][d]
  for (int i = tid; i < 8192; i += 256)
    q_bf[obase + i] = f2bf(qn[base + (long)(i >> 8) * D_ + (i & 255)]);
  int j = tid & 31, i0 = tid >> 5;
  for (int r = 0; r < 4; ++r) {
    int i = i0 + (r << 3);
    float acc = 0.f;
    for (int d = 0; d < 256; ++d) acc += skT[d][i] * skT[d][j];
    sinv[i][j] = (i > j) ? -acc * sbeta[i] : 0.f;
  }
  __syncthreads();
  for (int i = 1; i < 32; ++i) {
    float val = 0.f;
    if (tid < 32) {
      for (int t = 0; t < i; ++t) val += sinv[i][t] * sinv[t][tid];
    }
    __syncthreads();
    if (tid < 32) sinv[i][tid] += val;
    __syncthreads();
  }
  if (tid < 32) sinv[tid][tid] += 1.f;
  // attn bf16 = (qn @ kn^T) * lower_incl
  long abase = (long)blk * 1024;
  for (int r = 0; r < 4; ++r) {
    int i = i0 + (r << 3);
    const float* qrow = qn + base + (long)i * D_;
    float acc = 0.f;
    for (int d = 0; d < 256; ++d) acc += qrow[d] * skT[d][j];
    at_bf[abase + i * 32 + j] = f2bf((i >= j) ? acc : 0.f);
  }
  __syncthreads();
  int c = tid;
  float vt[32], kt[32];
#pragma unroll
  for (int t = 0; t < 32; ++t) {
    vt[t] = v[base + t * D_ + c] * sbeta[t];
    kt[t] = skT[c][t] * sbeta[t];
  }
#pragma unroll
  for (int i2 = 0; i2 < 32; ++i2) {
    float au = 0.f, aw = 0.f;
#pragma unroll
    for (int t = 0; t <= i2; ++t) {
      float f = sinv[i2][t];
      au += f * vt[t];
      aw += f * kt[t];
    }
    u[base + i2 * D_ + c] = au;
    w_bf[obase + i2 * 256 + c] = f2bf(aw);
  }
}

// ---------------- MFMA scan, barrier-free: 128 blocks x 1 wave; wave owns 16 cols, full K ----------------
// S[256x16] f32 in accumulators. Per chunk: pack S->LDS->B-frags; w@S,q@S (A-frags direct from
// global); u2 = u - wS -> LDS -> B-frag; S += kT@u2; out = qS + attn@u2. No __syncthreads.
// `out` aliases `u`: u[ci] is consumed (data dep) before out[ci] stores issue; blocks own disjoint cols.
__global__ __launch_bounds__(64, 1)
void delta_scan(const unsigned short* __restrict__ qb, const unsigned short* __restrict__ wbf,
                const unsigned short* __restrict__ ktb, const unsigned short* __restrict__ atb,
                const float* u, float* out) {
  __shared__ unsigned short sB[16 * 264];   // S^T staging: [n=16][d=256] pad 264
  __shared__ unsigned short su2[16 * 40];   // u2^T: [n=16][t=32] pad 40
  int blk = blockIdx.x;          // bh = blk&7 (same-bh blocks land on one XCD), cg = blk>>3
  int bh = blk & 7, cg = blk >> 3;
  int h = bh & 3, b = bh >> 2;
  int lane = threadIdx.x;
  int l15 = lane & 15, l4 = lane >> 4;
  int colw = cg * 16;

  f32x4 zero4; zero4.x = 0.f; zero4.y = 0.f; zero4.z = 0.f; zero4.w = 0.f;
  f32x4 acc[16];
#pragma unroll
  for (int t = 0; t < 16; ++t) acc[t] = zero4;

  for (int ci = 0; ci < NCH; ++ci) {
    long o8 = ((long)bh * NCH + ci) * 8192;
    long oa = ((long)bh * NCH + ci) * 1024;
    long ub = ((long)b * L_ + (long)ci * CHUNKSZ) * D_ + h * DH + colw;
    // ---- issue w-frag + u loads (global) ----
    uint4 wf[2][8];
    float ru[2][4];
#pragma unroll
    for (int m = 0; m < 2; ++m) {
#pragma unroll
      for (int kc = 0; kc < 8; ++kc)
        wf[m][kc] = *reinterpret_cast<const uint4*>(&wbf[o8 + (16 * m + l15) * 256 + kc * 32 + l4 * 8]);
#pragma unroll
      for (int r = 0; r < 4; ++r)
        ru[m][r] = u[ub + (long)(16 * m + 4 * l4 + r) * D_ + l15];
    }
    // ---- pack S -> sB (wave-local), read B-frags ----
#pragma unroll
    for (int dt = 0; dt < 16; ++dt) {
      uint2 pv;
      pv.x = pk2bf(acc[dt].x, acc[dt].y);
      pv.y = pk2bf(acc[dt].z, acc[dt].w);
      *reinterpret_cast<uint2*>(&sB[l15 * 264 + dt * 16 + l4 * 4]) = pv;
    }
    bf16x8 sf[8];
#pragma unroll
    for (int kc = 0; kc < 8; ++kc)
      sf[kc] = *reinterpret_cast<const bf16x8*>(&sB[l15 * 264 + kc * 32 + l4 * 8]);
    // ---- w@S ----
    f32x4 wacc[2]; wacc[0] = zero4; wacc[1] = zero4;
#pragma unroll
    for (int kc = 0; kc < 8; ++kc)
#pragma unroll
      for (int m = 0; m < 2; ++m)
        wacc[m] = __builtin_amdgcn_mfma_f32_16x16x32_bf16(
            *reinterpret_cast<bf16x8*>(&wf[m][kc]), sf[kc], wacc[m], 0, 0, 0);
    // ---- issue q-frag loads ----
    uint4 qf[2][8];
#pragma unroll
    for (int m = 0; m < 2; ++m)
#pragma unroll
      for (int kc = 0; kc < 8; ++kc)
        qf[m][kc] = *reinterpret_cast<const uint4*>(&qb[o8 + (16 * m + l15) * 256 + kc * 32 + l4 * 8]);
    // ---- u2 = u - wS -> su2 -> B-frag ----
#pragma unroll
    for (int m = 0; m < 2; ++m) {
      uint2 pv;
      pv.x = pk2bf(ru[m][0] - wacc[m].x, ru[m][1] - wacc[m].y);
      pv.y = pk2bf(ru[m][2] - wacc[m].z, ru[m][3] - wacc[m].w);
      *reinterpret_cast<uint2*>(&su2[l15 * 40 + m * 16 + l4 * 4]) = pv;
    }
    bf16x8 u2f = *reinterpret_cast<const bf16x8*>(&su2[l15 * 40 + l4 * 8]);
    // ---- issue kT/attn frag loads ----
    uint4 kf[16], af[2];
#pragma unroll
    for (int dt = 0; dt < 16; ++dt)
      kf[dt] = *reinterpret_cast<const uint4*>(&ktb[o8 + (16 * dt + l15) * 32 + l4 * 8]);
#pragma unroll
    for (int m = 0; m < 2; ++m)
      af[m] = *reinterpret_cast<const uint4*>(&atb[oa + (16 * m + l15) * 32 + l4 * 8]);
    // ---- q@S (qf landed during u2 round trip) ----
    f32x4 qacc[2]; qacc[0] = zero4; qacc[1] = zero4;
#pragma unroll
    for (int kc = 0; kc < 8; ++kc)
#pragma unroll
      for (int m = 0; m < 2; ++m)
        qacc[m] = __builtin_amdgcn_mfma_f32_16x16x32_bf16(
            *reinterpret_cast<bf16x8*>(&qf[m][kc]), sf[kc], qacc[m], 0, 0, 0);
    // ---- S += kT @ u2 ----
#pragma unroll
    for (int dt = 0; dt < 16; ++dt)
      acc[dt] = __builtin_amdgcn_mfma_f32_16x16x32_bf16(
          *reinterpret_cast<bf16x8*>(&kf[dt]), u2f, acc[dt], 0, 0, 0);
    // ---- out = qS + attn@u2 ----
#pragma unroll
    for (int m = 0; m < 2; ++m) {
      f32x4 dv = __builtin_amdgcn_mfma_f32_16x16x32_bf16(
          *reinterpret_cast<bf16x8*>(&af[m]), u2f, qacc[m], 0, 0, 0);
#pragma unroll
      for (int r = 0; r < 4; ++r)
        out[ub + (long)(16 * m + 4 * l4 + r) * D_ + l15] = dv[r];
    }
  }
}

// ---------------- head stats ----------------
__global__ __launch_bounds__(256)
void head_stats_k(const float* __restrict__ x, float* __restrict__ out,
                  int ostride, int ooff) {
  __shared__ float rs[256], rq[256], ra[256];
  long bl = blockIdx.x;
  int tid = threadIdx.x;
  float m_acc = 0, v_acc = 0, a_acc = 0, l_acc = 0;
  for (int h = 0; h < H_; ++h) {
    float v = x[bl * D_ + h * DH + tid];
    rs[tid] = v; rq[tid] = v * v; ra[tid] = fabsf(v);
    __syncthreads();
    for (int st = 128; st > 0; st >>= 1) {
      if (tid < st) { rs[tid] += rs[tid + st]; rq[tid] += rq[tid + st]; ra[tid] += ra[tid + st]; }
      __syncthreads();
    }
    if (tid == 0) {
      float mean = rs[0] / 256.f;
      m_acc += mean;
      v_acc += rq[0] / 256.f - mean * mean;
      a_acc += ra[0] / 256.f;
      l_acc += sqrtf(rq[0]);
    }
    __syncthreads();
  }
  if (tid == 0) {
    float* o = out + bl * ostride + ooff;
    o[0] = m_acc / H_; o[1] = v_acc / H_; o[2] = a_acc / H_; o[3] = l_acc / H_;
  }
}

// ---------------- g = gelu(g + bias + stats @ Wtail) ----------------
__global__ __launch_bounds__(256)
void tail_bias_gelu(float* __restrict__ g, const float* __restrict__ stats,
                    const float* __restrict__ Wt, const float* __restrict__ bias,
                    int N, int K2) {
  long idx = (long)blockIdx.x * 256 + threadIdx.x;
  if (idx >= (long)BL * N) return;
  int n = idx % N;
  long m = idx / N;
  float s = g[idx] + bias[n];
  for (int k = 0; k < K2; ++k) s += stats[m * K2 + k] * Wt[(long)k * N + n];
  g[idx] = geluf(s);
}

// ---------------- softmax with temp, clip, renorm ----------------
__global__ __launch_bounds__(256)
void softmax_p(const float* __restrict__ logits, const float* __restrict__ temp_in,
               float* __restrict__ p) {
  int bl = blockIdx.x * 256 + threadIdx.x;
  if (bl >= BL) return;
  float temp = log1pf(expf(temp_in[0]));
  float l0 = logits[bl * 4 + 0] / temp, l1 = logits[bl * 4 + 1] / temp;
  float l2 = logits[bl * 4 + 2] / temp, l3 = logits[bl * 4 + 3] / temp;
  float mx = fmaxf(fmaxf(l0, l1), fmaxf(l2, l3));
  float e0 = expf(l0 - mx), e1 = expf(l1 - mx), e2 = expf(l2 - mx), e3 = expf(l3 - mx);
  float s = e0 + e1 + e2 + e3;
  e0 /= s; e1 /= s; e2 /= s; e3 /= s;
  e0 = fmaxf(e0, 0.02f); e1 = fmaxf(e1, 0.02f); e2 = fmaxf(e2, 0.02f); e3 = fmaxf(e3, 0.02f);
  s = e0 + e1 + e2 + e3;
  p[bl * 4 + 0] = e0 / s; p[bl * 4 + 1] = e1 / s; p[bl * 4 + 2] = e2 / s; p[bl * 4 + 3] = e3 / s;
}

// ---------------- mixture combine + conv residual ----------------
__global__ __launch_bounds__(256)
void combine(const float* __restrict__ ls, const float* __restrict__ ll,
             const float* __restrict__ dd, const float* __restrict__ vd,
             const float* __restrict__ p, const float* __restrict__ resg,
             const float* __restrict__ crl, float* __restrict__ o) {
  int idx = blockIdx.x * 256 + threadIdx.x;
  if (idx >= BLD) return;
  int c = idx % D_;
  long bl = idx / D_;
  int h = c >> 8;
  const float* pp = p + bl * 4;
  float sgate = sigmf(crl[h]) * resg[bl * H_ + h];
  o[idx] = pp[0] * ls[idx] + pp[1] * ll[idx] + pp[2] * dd[idx] + pp[3] * vd[idx] + sgate * ls[idx];
}

// ---------------- o = rmsnorm(o * og) * norm_w ----------------
__global__ __launch_bounds__(256)
void scale_rmsnorm(float* __restrict__ o, const float* __restrict__ og,
                   const float* __restrict__ nw) {
  __shared__ float red[256];
  long row = blockIdx.x;
  long bl = row >> 2;
  int tid = threadIdx.x;
  float v = o[row * 256 + tid] * og[bl];
  red[tid] = v * v;
  __syncthreads();
  for (int st = 128; st > 0; st >>= 1) {
    if (tid < st) red[tid] += red[tid + st];
    __syncthreads();
  }
  float scale = rsqrtf(red[0] / 256.f + 1e-5f);
  o[row * 256 + tid] = v * scale * nw[tid];
}

extern "C" void kernel_launch(void* const* d_in, const int* in_sizes, int n_in,
                              void* d_out, int out_size, void* d_ws, size_t ws_size,
                              hipStream_t stream) {
  const float* hs       = (const float*)d_in[0];
  const float* Wq       = (const float*)d_in[1];
  const float* Wk       = (const float*)d_in[2];
  const float* Wv       = (const float*)d_in[3];
  const float* Wb       = (const float*)d_in[4];
  const float* wq_conv  = (const float*)d_in[5];
  const float* wk_conv  = (const float*)d_in[6];
  const float* wv_conv  = (const float*)d_in[7];
  const float* fir_long = (const float*)d_in[8];
  const float* fir_short= (const float*)d_in[9];
  const float* Wg1      = (const float*)d_in[10];
  const float* bg1      = (const float*)d_in[11];
  const float* Wg2      = (const float*)d_in[12];
  const float* bg2      = (const float*)d_in[13];
  const float* logit_temp     = (const float*)d_in[14];
  const float* conv_res_logit = (const float*)d_in[15];
  const float* Wres     = (const float*)d_in[16];
  const float* bres     = (const float*)d_in[17];
  const float* Wog1     = (const float*)d_in[18];
  const float* bog1     = (const float*)d_in[19];
  const float* Wog2     = (const float*)d_in[20];
  const float* bog2     = (const float*)d_in[21];
  const float* norm_w   = (const float*)d_in[22];
  const float* Wo       = (const float*)d_in[23];
  float* out = (float*)d_out;
  float* ws = (float*)d_ws;

  float* b0 = ws;             // qlin -> kn -> gate_hidden -> o_mix
  float* b1 = ws + 1L * BLD;  // klin -> v_in (v_direct)
  float* b2 = ws + 2L * BLD;  // vlin -> u -> delta_out -> og_hidden
  float* b3 = ws + 3L * BLD;  // qn -> local_long
  float* b4 = ws + 4L * BLD;  // w_bf (bf16, first half) -> local_short
  float* sm = ws + 5L * BLD;
  float* beta    = sm;
  float* resg    = beta + BL * H_;
  float* stats16 = resg + BL * H_;
  float* og8     = stats16 + BL * 16;
  float* logits  = og8 + BL * 8;
  float* pbuf    = logits + BL * 4;
  float* ogv     = pbuf + BL * 4;
  unsigned short* q_bfg  = (unsigned short*)(ogv + BL);   // BLD bf16
  unsigned short* kT_bfg = q_bfg + (long)BLD;             // BLD bf16
  unsigned short* at_bfg = kT_bfg + (long)BLD;            // 1M bf16
  unsigned short* hsb  = at_bfg + 1024L * 1024;           // BLD bf16
  unsigned short* wtq  = hsb + (long)BLD;
  unsigned short* wtk  = wtq + 1024L * 1024;
  unsigned short* wtv  = wtk + 1024L * 1024;
  unsigned short* wtg1 = wtv + 1024L * 1024;
  unsigned short* wto  = wtg1 + 1024L * 1024;
  unsigned short* wtog1= wto + 1024L * 1024;
  unsigned short* w_bfg = (unsigned short*)b4;            // bf16 w inside b4
  unsigned short* xb    = q_bfg;                          // reuse (q_bf dead after scan)

  size_t needed = (5L * BLD + BL * 41) * 4
                + (3L * BLD + 1024L * 1024 + 5L * 1024 * 1024 + 512L * 1024) * 2;
  if (ws_size < needed) return;

  dim3 blk(256);
  // 0. preconvert
  wconv_t<<<dim3(32, 32), blk, 0, stream>>>(Wq, wtq, 1024);
  wconv_t<<<dim3(32, 32), blk, 0, stream>>>(Wk, wtk, 1024);
  wconv_t<<<dim3(32, 32), blk, 0, stream>>>(Wv, wtv, 1024);
  wconv_t<<<dim3(32, 32), blk, 0, stream>>>(Wg1, wtg1, 1024);
  wconv_t<<<dim3(32, 32), blk, 0, stream>>>(Wo, wto, 1024);
  wconv_t<<<dim3(16, 32), blk, 0, stream>>>(Wog1, wtog1, 512);
  cvt_bf16<<<BLD / 1024, blk, 0, stream>>>(hs, hsb, BLD);
  // 1. projections
  gemm_bf16<<<dim3(8, 64), blk, 0, stream>>>(hsb, wtq, b0, 1024);
  gemm_bf16<<<dim3(8, 64), blk, 0, stream>>>(hsb, wtk, b1, 1024);
  gemm_bf16<<<dim3(8, 64), blk, 0, stream>>>(hsb, wtv, b2, 1024);
  // 2. conv + silu (tiled)
  dwconv_tiled<4><<<1024, blk, 0, stream>>>(b0, wq_conv, b3, 1);
  dwconv_tiled<4><<<1024, blk, 0, stream>>>(b1, wk_conv, b0, 1);
  dwconv_tiled<4><<<1024, blk, 0, stream>>>(b2, wv_conv, b1, 1);
  // 3. beta, res gate
  gemv_smallN<<<BL, blk, 0, stream>>>(hs, Wb, nullptr, beta, D_, H_, 1);
  gemv_smallN<<<BL, blk, 0, stream>>>(hs, Wres, bres, resg, D_, H_, 1);
  // 4. l2norm
  l2norm_inplace<<<BL * H_, blk, 0, stream>>>(b3);
  l2norm_inplace<<<BL * H_, blk, 0, stream>>>(b0);
  // 5-6. delta rule (u->b2; bf16 operands; scan writes delta_out in place over u)
  chunk_uw<<<B_ * H_ * NCH, blk, 0, stream>>>(b3, b0, b1, beta, b2, q_bfg, w_bfg, kT_bfg, at_bfg);
  delta_scan<<<128, dim3(64), 0, stream>>>(q_bfg, w_bfg, kT_bfg, at_bfg, b2, b2);
  // 7. local convs
  dwconv_tiled<64><<<1024, blk, 0, stream>>>(b1, fir_long, b3, 0);
  dwconv_tiled<5><<<1024, blk, 0, stream>>>(b1, fir_short, b4, 0);
  // 8. stats16
  head_stats_k<<<BL, blk, 0, stream>>>(b4, stats16, 16, 0);
  head_stats_k<<<BL, blk, 0, stream>>>(b3, stats16, 16, 4);
  head_stats_k<<<BL, blk, 0, stream>>>(b2, stats16, 16, 8);
  head_stats_k<<<BL, blk, 0, stream>>>(b1, stats16, 16, 12);
  // 9. gate hidden
  gemm_bf16<<<dim3(8, 64), blk, 0, stream>>>(hsb, wtg1, b0, 1024);
  tail_bias_gelu<<<(BL * D_) / 256, blk, 0, stream>>>(b0, stats16, Wg1 + 1024L * 1024, bg1, D_, 16);
  // 10. logits, p
  gemv_smallN<<<BL, blk, 0, stream>>>(b0, Wg2, bg2, logits, D_, 4, 0);
  softmax_p<<<BL / 256, blk, 0, stream>>>(logits, logit_temp, pbuf);
  // 11. combine -> b0
  combine<<<BLD / 256, blk, 0, stream>>>(b4, b3, b2, b1, pbuf, resg, conv_res_logit, b0);
  // 12. og stats
  head_stats_k<<<BL, blk, 0, stream>>>(b0, og8, 8, 0);
  head_stats_k<<<BL, blk, 0, stream>>>(b1, og8, 8, 4);
  // 13. output gate
  gemm_bf16<<<dim3(4, 64), blk, 0, stream>>>(hsb, wtog1, b2, 512);
  tail_bias_gelu<<<(BL * 512) / 256, blk, 0, stream>>>(b2, og8, Wog1 + 1024L * 512, bog1, 512, 8);
  gemv_smallN<<<BL, blk, 0, stream>>>(b2, Wog2, bog2, ogv, 512, 1, 1);
  // 14. scale + rmsnorm
  scale_rmsnorm<<<BL * H_, blk, 0, stream>>>(b0, ogv, norm_w);
  // 15. final projection
  cvt_bf16<<<BLD / 1024, blk, 0, stream>>>(b0, xb, BLD);
  gemm_bf16<<<dim3(8, 64), blk, 0, stream>>>(xb, wto, out, 1024);
}

// Round 9
// 1124.365 us; speedup vs baseline: 12.9472x; 1.1681x over previous
//
#include <hip/hip_runtime.h>
#include <math.h>

#define B_ 2
#define L_ 4096
#define D_ 1024
#define H_ 4
#define DH 256
#define CHUNKSZ 32
#define NCH (L_/CHUNKSZ)      // 128
#define BL (B_*L_)            // 8192
#define BLD (B_*L_*D_)        // 8388608

typedef __attribute__((ext_vector_type(8))) short bf16x8;
typedef __attribute__((ext_vector_type(4))) float f32x4;

__device__ __forceinline__ float sigmf(float x) { return 1.f / (1.f + expf(-x)); }
__device__ __forceinline__ float geluf(float x) { return 0.5f * x * (1.f + erff(x * 0.70710678118654752f)); }
__device__ __forceinline__ unsigned short f2bf(float f) {
  unsigned int u = __float_as_uint(f);
  unsigned int r = (u + 0x7FFFu + ((u >> 16) & 1u)) >> 16;
  return (unsigned short)r;
}
__device__ __forceinline__ unsigned int pk2bf(float a, float b) {
  return ((unsigned int)f2bf(b) << 16) | (unsigned int)f2bf(a);
}

// ---------------- f32 -> bf16 elementwise (n multiple of 4) ----------------
__global__ __launch_bounds__(256)
void cvt_bf16(const float* __restrict__ x, unsigned short* __restrict__ y, long n) {
  long i = ((long)blockIdx.x * 256 + threadIdx.x) * 4;
  if (i >= n) return;
  float4 v = *reinterpret_cast<const float4*>(&x[i]);
  ushort4 o;
  o.x = f2bf(v.x); o.y = f2bf(v.y); o.z = f2bf(v.z); o.w = f2bf(v.w);
  *reinterpret_cast<ushort4*>(&y[i]) = o;
}

// ---------------- W[k][n] f32 -> Wt[n][k] bf16 (32x32 tiles) ----------------
__global__ __launch_bounds__(256)
void wconv_t(const float* __restrict__ W, unsigned short* __restrict__ Wt, int N) {
  __shared__ float tile[32][33];
  int kb = blockIdx.y * 32, nb = blockIdx.x * 32;
  int tx = threadIdx.x & 31, ty = threadIdx.x >> 5;
  for (int i = 0; i < 32; i += 8)
    tile[ty + i][tx] = W[(long)(kb + ty + i) * N + nb + tx];
  __syncthreads();
  for (int i = 0; i < 32; i += 8)
    Wt[(long)(nb + ty + i) * 1024 + kb + tx] = f2bf(tile[tx][ty + i]);
}

// ---------------- bf16 MFMA GEMM: C[8192][N] = A[8192][1024] @ Bt[N][1024]^T ----------------
// Staging via global_load_lds (width 16); source column pre-swizzled so linear LDS dest
// reproduces the swizzled layout (XOR is an involution); frag reads unchanged.
__global__ __launch_bounds__(256)
void gemm_bf16(const unsigned short* __restrict__ A, const unsigned short* __restrict__ Bt,
               float* __restrict__ C, int N) {
  __shared__ unsigned short Al[128 * 32];
  __shared__ unsigned short Bl[128 * 32];
  const int K = 1024;
  int bm = blockIdx.y * 128, bn = blockIdx.x * 128;
  int tid = threadIdx.x;
  int lane = tid & 63, wid = tid >> 6;
  int wr = wid >> 1, wc = wid & 1;
  int l15 = lane & 15, l4 = lane >> 4;
  f32x4 acc[4][4];
#pragma unroll
  for (int i = 0; i < 4; ++i)
#pragma unroll
    for (int j = 0; j < 4; ++j) { acc[i][j].x = 0.f; acc[i][j].y = 0.f; acc[i][j].z = 0.f; acc[i][j].w = 0.f; }
  for (int k0 = 0; k0 < K; k0 += 32) {
    __syncthreads();
#pragma unroll
    for (int i = 0; i < 2; ++i) {
      int idx = tid + i * 256;
      int r = idx >> 2, sl = idx & 3;
      int src = sl ^ ((r >> 1) & 3);
      __builtin_amdgcn_global_load_lds(
          (const __attribute__((address_space(1))) unsigned int*)&A[(long)(bm + r) * K + k0 + src * 8],
          (__attribute__((address_space(3))) unsigned int*)&Al[idx * 8], 16, 0, 0);
      __builtin_amdgcn_global_load_lds(
          (const __attribute__((address_space(1))) unsigned int*)&Bt[(long)(bn + r) * K + k0 + src * 8],
          (__attribute__((address_space(3))) unsigned int*)&Bl[idx * 8], 16, 0, 0);
    }
    __syncthreads();
    bf16x8 af[4], bfr[4];
#pragma unroll
    for (int fi = 0; fi < 4; ++fi) {
      int r = wr * 64 + fi * 16 + l15;
      af[fi] = *reinterpret_cast<const bf16x8*>(&Al[r * 32 + (l4 ^ ((r >> 1) & 3)) * 8]);
    }
#pragma unroll
    for (int fj = 0; fj < 4; ++fj) {
      int r = wc * 64 + fj * 16 + l15;
      bfr[fj] = *reinterpret_cast<const bf16x8*>(&Bl[r * 32 + (l4 ^ ((r >> 1) & 3)) * 8]);
    }
#pragma unroll
    for (int fi = 0; fi < 4; ++fi)
#pragma unroll
      for (int fj = 0; fj < 4; ++fj)
        acc[fi][fj] = __builtin_amdgcn_mfma_f32_16x16x32_bf16(af[fi], bfr[fj], acc[fi][fj], 0, 0, 0);
  }
#pragma unroll
  for (int fi = 0; fi < 4; ++fi) {
    int rb = bm + wr * 64 + fi * 16 + l4 * 4;
#pragma unroll
    for (int fj = 0; fj < 4; ++fj) {
      int cb = bn + wc * 64 + fj * 16 + l15;
#pragma unroll
      for (int j = 0; j < 4; ++j)
        C[(long)(rb + j) * N + cb] = acc[fi][fj][j];
    }
  }
}

// ---------------- tiled depthwise causal conv (+ optional silu), K templated ----------------
#define CTL 128
template<int K>
__global__ __launch_bounds__(256)
void dwconv_tiled(const float* __restrict__ x, const float* __restrict__ w,
                  float* __restrict__ y, int do_silu) {
  __shared__ float tile[(CTL + K - 1) * 64];
  int bid = blockIdx.x;
  int ct = bid & 15;
  int lt = (bid >> 4) & 31;
  int b  = bid >> 9;
  int c0 = ct * 64;
  int l0 = lt * CTL;
  int tid = threadIdx.x;
  const int rows = CTL + K - 1;
  for (int i = tid; i < rows * 16; i += 256) {
    int rr = i >> 4, c4 = i & 15;
    int l = l0 - (K - 1) + rr;
    float4 v = make_float4(0.f, 0.f, 0.f, 0.f);
    if (l >= 0) v = *reinterpret_cast<const float4*>(&x[((long)b * L_ + l) * D_ + c0 + c4 * 4]);
    *reinterpret_cast<float4*>(&tile[rr * 64 + c4 * 4]) = v;
  }
  __syncthreads();
  int c = tid & 63;
  int lo0 = tid >> 6;
  float wreg[K];
#pragma unroll
  for (int j = 0; j < K; ++j) wreg[j] = w[(long)(c0 + c) * K + j];
  for (int lo = lo0; lo < CTL; lo += 4) {
    float acc = 0.f;
#pragma unroll
    for (int j = 0; j < K; ++j)
      acc = fmaf(wreg[j], tile[(lo + j) * 64 + c], acc);
    if (do_silu) acc = acc * sigmf(acc);
    y[((long)b * L_ + l0 + lo) * D_ + c0 + c] = acc;
  }
}

// ---------------- small-N GEMV ----------------
__global__ __launch_bounds__(256)
void gemv_smallN(const float* __restrict__ X, const float* __restrict__ W,
                 const float* __restrict__ bias, float* __restrict__ out,
                 int K, int N, int act) {
  __shared__ float red[256];
  long m = blockIdx.x;
  const float* x = X + m * K;
  for (int n = 0; n < N; ++n) {
    float s = 0.f;
    for (int k = threadIdx.x; k < K; k += 256) s += x[k] * W[(long)k * N + n];
    red[threadIdx.x] = s;
    __syncthreads();
    for (int st = 128; st > 0; st >>= 1) {
      if (threadIdx.x < st) red[threadIdx.x] += red[threadIdx.x + st];
      __syncthreads();
    }
    if (threadIdx.x == 0) {
      float v = red[0] + (bias ? bias[n] : 0.f);
      if (act == 1) v = sigmf(v);
      out[m * N + n] = v;
    }
    __syncthreads();
  }
}

// ---------------- l2norm in place over rows of 256 ----------------
__global__ __launch_bounds__(256)
void l2norm_inplace(float* __restrict__ x) {
  __shared__ float red[256];
  long row = blockIdx.x;
  float v = x[row * 256 + threadIdx.x];
  red[threadIdx.x] = v * v;
  __syncthreads();
  for (int st = 128; st > 0; st >>= 1) {
    if (threadIdx.x < st) red[threadIdx.x] += red[threadIdx.x + st];
    __syncthreads();
  }
  float inv = rsqrtf(red[0] + 1e-6f);
  x[row * 256 + threadIdx.x] = v * inv;
}

// ---------------- per-chunk: inv, u (f32), and bf16 operands for the scan ----------------
__global__ __launch_bounds__(256)
void chunk_uw(const float* __restrict__ qn, const float* __restrict__ kn,
              const float* __restrict__ v, const float* __restrict__ beta,
              float* __restrict__ u,
              unsigned short* __restrict__ q_bf, unsigned short* __restrict__ w_bf,
              unsigned short* __restrict__ kT_bf, unsigned short* __restrict__ at_bf) {
  __shared__ float skT[256][33];
  __shared__ float sinv[32][33];
  __shared__ float sbeta[32];
  int blk = blockIdx.x;
  int ci = blk % NCH;
  int bh = blk / NCH;
  int h = bh % H_;
  int b = bh / H_;
  long base = ((long)b * L_ + (long)ci * CHUNKSZ) * D_ + h * DH;
  long brow = (long)b * L_ + (long)ci * CHUNKSZ;
  long obase = (long)blk * 8192;   // blk == bh*NCH+ci
  int tid = threadIdx.x;
  for (int i = tid; i < 32 * 256; i += 256) {
    int r = i >> 8, c = i & 255;
    skT[c][r] = kn[base + (long)r * D_ + c];
  }
  if (tid < 32) sbeta[tid] = beta[(brow + tid) * H_ + h];
  __syncthreads();
  for (int i = tid; i < 8192; i += 256)
    kT_bf[obase + i] = f2bf(skT[i >> 5][i & 31]);
  for (int i = tid; i < 8192; i += 256)
    q_bf[obase + i] = f2bf(qn[base + (long)(i >> 8) * D_ + (i & 255)]);
  int j = tid & 31, i0 = tid >> 5;
  for (int r = 0; r < 4; ++r) {
    int i = i0 + (r << 3);
    float acc = 0.f;
    for (int d = 0; d < 256; ++d) acc += skT[d][i] * skT[d][j];
    sinv[i][j] = (i > j) ? -acc * sbeta[i] : 0.f;
  }
  __syncthreads();
  for (int i = 1; i < 32; ++i) {
    float val = 0.f;
    if (tid < 32) {
      for (int t = 0; t < i; ++t) val += sinv[i][t] * sinv[t][tid];
    }
    __syncthreads();
    if (tid < 32) sinv[i][tid] += val;
    __syncthreads();
  }
  if (tid < 32) sinv[tid][tid] += 1.f;
  long abase = (long)blk * 1024;
  for (int r = 0; r < 4; ++r) {
    int i = i0 + (r << 3);
    const float* qrow = qn + base + (long)i * D_;
    float acc = 0.f;
    for (int d = 0; d < 256; ++d) acc += qrow[d] * skT[d][j];
    at_bf[abase + i * 32 + j] = f2bf((i >= j) ? acc : 0.f);
  }
  __syncthreads();
  int c = tid;
  float vt[32], kt[32];
#pragma unroll
  for (int t = 0; t < 32; ++t) {
    vt[t] = v[base + t * D_ + c] * sbeta[t];
    kt[t] = skT[c][t] * sbeta[t];
  }
#pragma unroll
  for (int i2 = 0; i2 < 32; ++i2) {
    float au = 0.f, aw = 0.f;
#pragma unroll
    for (int t = 0; t <= i2; ++t) {
      float f = sinv[i2][t];
      au += f * vt[t];
      aw += f * kt[t];
    }
    u[base + i2 * D_ + c] = au;
    w_bf[obase + i2 * 256 + c] = f2bf(aw);
  }
}

// ---------------- MFMA scan, barrier-free, register-resident operand pipeline ----------------
// 128 blocks x 1 wave; wave owns 16 cols, full K. S f32 in accumulators.
// Schedule per chunk: [q/kT/attn loads issue] -> S-pack->LDS->B-frags -> w@S
// -> [next chunk w/u loads issue] -> u2 round trip -> q@S ; S+=kT@u2 ; out stores.
// Every global wait has ~600cy of covered slack. No __syncthreads.
// `out` aliases `u` (u reads precede out stores in program order; disjoint cols across blocks).
__global__ __launch_bounds__(64, 1)
void delta_scan(const unsigned short* __restrict__ qb, const unsigned short* __restrict__ wbf,
                const unsigned short* __restrict__ ktb, const unsigned short* __restrict__ atb,
                const float* u, float* out) {
  __shared__ unsigned short sB[16 * 264];   // S^T staging: [n=16][d=256] pad 264
  __shared__ unsigned short su2[16 * 40];   // u2^T: [n=16][t=32] pad 40
  int blk = blockIdx.x;
  int bh = blk & 7, cg = blk >> 3;          // same-bh blocks land on one XCD
  int h = bh & 3, b = bh >> 2;
  int lane = threadIdx.x;
  int l15 = lane & 15, l4 = lane >> 4;
  int colw = cg * 16;

  f32x4 zero4; zero4.x = 0.f; zero4.y = 0.f; zero4.z = 0.f; zero4.w = 0.f;
  f32x4 acc[16];
#pragma unroll
  for (int t = 0; t < 16; ++t) acc[t] = zero4;

  uint4 wf[2][8];
  float ru[2][4];
  uint4 qf[2][8];
  uint4 kf[16];
  uint4 af[2];

#define LOAD_WU(CI) do {                                                         \
    long o8_ = ((long)bh * NCH + (CI)) * 8192;                                   \
    long ub_ = ((long)b * L_ + (long)(CI) * CHUNKSZ) * D_ + h * DH + colw;       \
    _Pragma("unroll")                                                            \
    for (int m_ = 0; m_ < 2; ++m_) {                                             \
      _Pragma("unroll")                                                          \
      for (int kc_ = 0; kc_ < 8; ++kc_)                                          \
        wf[m_][kc_] = *reinterpret_cast<const uint4*>(                           \
            &wbf[o8_ + (16 * m_ + l15) * 256 + kc_ * 32 + l4 * 8]);              \
      _Pragma("unroll")                                                          \
      for (int r_ = 0; r_ < 4; ++r_)                                             \
        ru[m_][r_] = u[ub_ + (long)(16 * m_ + 4 * l4 + r_) * D_ + l15];          \
    }                                                                            \
  } while (0)

#define LOAD_QKA(CI) do {                                                        \
    long o8_ = ((long)bh * NCH + (CI)) * 8192;                                   \
    long oa_ = ((long)bh * NCH + (CI)) * 1024;                                   \
    _Pragma("unroll")                                                            \
    for (int m_ = 0; m_ < 2; ++m_)                                               \
      _Pragma("unroll")                                                          \
      for (int kc_ = 0; kc_ < 8; ++kc_)                                          \
        qf[m_][kc_] = *reinterpret_cast<const uint4*>(                           \
            &qb[o8_ + (16 * m_ + l15) * 256 + kc_ * 32 + l4 * 8]);               \
    _Pragma("unroll")                                                            \
    for (int dt_ = 0; dt_ < 16; ++dt_)                                           \
      kf[dt_] = *reinterpret_cast<const uint4*>(                                 \
          &ktb[o8_ + (16 * dt_ + l15) * 32 + l4 * 8]);                           \
    _Pragma("unroll")                                                            \
    for (int m_ = 0; m_ < 2; ++m_)                                               \
      af[m_] = *reinterpret_cast<const uint4*>(                                  \
          &atb[oa_ + (16 * m_ + l15) * 32 + l4 * 8]);                            \
  } while (0)

  LOAD_WU(0);

  for (int ci = 0; ci < NCH; ++ci) {
    long ub = ((long)b * L_ + (long)ci * CHUNKSZ) * D_ + h * DH + colw;
    // ---- issue this chunk's q/kT/attn loads (consumed after ~600cy) ----
    LOAD_QKA(ci);
    // snapshot u so next-chunk LOAD_WU can reuse ru registers
    float ruc[2][4];
#pragma unroll
    for (int m = 0; m < 2; ++m)
#pragma unroll
      for (int r = 0; r < 4; ++r) ruc[m][r] = ru[m][r];
    // ---- pack S -> sB (wave-local), read B-frags ----
#pragma unroll
    for (int dt = 0; dt < 16; ++dt) {
      uint2 pv;
      pv.x = pk2bf(acc[dt].x, acc[dt].y);
      pv.y = pk2bf(acc[dt].z, acc[dt].w);
      *reinterpret_cast<uint2*>(&sB[l15 * 264 + dt * 16 + l4 * 4]) = pv;
    }
    bf16x8 sf[8];
#pragma unroll
    for (int kc = 0; kc < 8; ++kc)
      sf[kc] = *reinterpret_cast<const bf16x8*>(&sB[l15 * 264 + kc * 32 + l4 * 8]);
    // ---- w@S (4 interleaved partial chains) ----
    f32x4 wa[2][2];
    wa[0][0] = zero4; wa[0][1] = zero4; wa[1][0] = zero4; wa[1][1] = zero4;
#pragma unroll
    for (int kc = 0; kc < 8; ++kc) {
#pragma unroll
      for (int m = 0; m < 2; ++m)
        wa[m][kc & 1] = __builtin_amdgcn_mfma_f32_16x16x32_bf16(
            *reinterpret_cast<bf16x8*>(&wf[m][kc]), sf[kc], wa[m][kc & 1], 0, 0, 0);
    }
    // ---- prefetch next chunk's w,u (slack: u2 + q@S + S-update) ----
    if (ci + 1 < NCH) LOAD_WU(ci + 1);
    // ---- u2 = u - wS -> su2 -> B-frag ----
#pragma unroll
    for (int m = 0; m < 2; ++m) {
      f32x4 ws = wa[m][0] + wa[m][1];
      uint2 pv;
      pv.x = pk2bf(ruc[m][0] - ws.x, ruc[m][1] - ws.y);
      pv.y = pk2bf(ruc[m][2] - ws.z, ruc[m][3] - ws.w);
      *reinterpret_cast<uint2*>(&su2[l15 * 40 + m * 16 + l4 * 4]) = pv;
    }
    bf16x8 u2f = *reinterpret_cast<const bf16x8*>(&su2[l15 * 40 + l4 * 8]);
    // ---- q@S (qf loads landed during w@S + u2) ----
    f32x4 qa[2][2];
    qa[0][0] = zero4; qa[0][1] = zero4; qa[1][0] = zero4; qa[1][1] = zero4;
#pragma unroll
    for (int kc = 0; kc < 8; ++kc) {
#pragma unroll
      for (int m = 0; m < 2; ++m)
        qa[m][kc & 1] = __builtin_amdgcn_mfma_f32_16x16x32_bf16(
            *reinterpret_cast<bf16x8*>(&qf[m][kc]), sf[kc], qa[m][kc & 1], 0, 0, 0);
    }
    // ---- S += kT @ u2 ----
#pragma unroll
    for (int dt = 0; dt < 16; ++dt)
      acc[dt] = __builtin_amdgcn_mfma_f32_16x16x32_bf16(
          *reinterpret_cast<bf16x8*>(&kf[dt]), u2f, acc[dt], 0, 0, 0);
    // ---- out = qS + attn@u2 ----
#pragma unroll
    for (int m = 0; m < 2; ++m) {
      f32x4 qacc = qa[m][0] + qa[m][1];
      f32x4 dv = __builtin_amdgcn_mfma_f32_16x16x32_bf16(
          *reinterpret_cast<bf16x8*>(&af[m]), u2f, qacc, 0, 0, 0);
#pragma unroll
      for (int r = 0; r < 4; ++r)
        out[ub + (long)(16 * m + 4 * l4 + r) * D_ + l15] = dv[r];
    }
  }
#undef LOAD_WU
#undef LOAD_QKA
}

// ---------------- head stats ----------------
__global__ __launch_bounds__(256)
void head_stats_k(const float* __restrict__ x, float* __restrict__ out,
                  int ostride, int ooff) {
  __shared__ float rs[256], rq[256], ra[256];
  long bl = blockIdx.x;
  int tid = threadIdx.x;
  float m_acc = 0, v_acc = 0, a_acc = 0, l_acc = 0;
  for (int h = 0; h < H_; ++h) {
    float v = x[bl * D_ + h * DH + tid];
    rs[tid] = v; rq[tid] = v * v; ra[tid] = fabsf(v);
    __syncthreads();
    for (int st = 128; st > 0; st >>= 1) {
      if (tid < st) { rs[tid] += rs[tid + st]; rq[tid] += rq[tid + st]; ra[tid] += ra[tid + st]; }
      __syncthreads();
    }
    if (tid == 0) {
      float mean = rs[0] / 256.f;
      m_acc += mean;
      v_acc += rq[0] / 256.f - mean * mean;
      a_acc += ra[0] / 256.f;
      l_acc += sqrtf(rq[0]);
    }
    __syncthreads();
  }
  if (tid == 0) {
    float* o = out + bl * ostride + ooff;
    o[0] = m_acc / H_; o[1] = v_acc / H_; o[2] = a_acc / H_; o[3] = l_acc / H_;
  }
}

// ---------------- g = gelu(g + bias + stats @ Wtail) ----------------
__global__ __launch_bounds__(256)
void tail_bias_gelu(float* __restrict__ g, const float* __restrict__ stats,
                    const float* __restrict__ Wt, const float* __restrict__ bias,
                    int N, int K2) {
  long idx = (long)blockIdx.x * 256 + threadIdx.x;
  if (idx >= (long)BL * N) return;
  int n = idx % N;
  long m = idx / N;
  float s = g[idx] + bias[n];
  for (int k = 0; k < K2; ++k) s += stats[m * K2 + k] * Wt[(long)k * N + n];
  g[idx] = geluf(s);
}

// ---------------- softmax with temp, clip, renorm ----------------
__global__ __launch_bounds__(256)
void softmax_p(const float* __restrict__ logits, const float* __restrict__ temp_in,
               float* __restrict__ p) {
  int bl = blockIdx.x * 256 + threadIdx.x;
  if (bl >= BL) return;
  float temp = log1pf(expf(temp_in[0]));
  float l0 = logits[bl * 4 + 0] / temp, l1 = logits[bl * 4 + 1] / temp;
  float l2 = logits[bl * 4 + 2] / temp, l3 = logits[bl * 4 + 3] / temp;
  float mx = fmaxf(fmaxf(l0, l1), fmaxf(l2, l3));
  float e0 = expf(l0 - mx), e1 = expf(l1 - mx), e2 = expf(l2 - mx), e3 = expf(l3 - mx);
  float s = e0 + e1 + e2 + e3;
  e0 /= s; e1 /= s; e2 /= s; e3 /= s;
  e0 = fmaxf(e0, 0.02f); e1 = fmaxf(e1, 0.02f); e2 = fmaxf(e2, 0.02f); e3 = fmaxf(e3, 0.02f);
  s = e0 + e1 + e2 + e3;
  p[bl * 4 + 0] = e0 / s; p[bl * 4 + 1] = e1 / s; p[bl * 4 + 2] = e2 / s; p[bl * 4 + 3] = e3 / s;
}

// ---------------- mixture combine + conv residual ----------------
__global__ __launch_bounds__(256)
void combine(const float* __restrict__ ls, const float* __restrict__ ll,
             const float* __restrict__ dd, const float* __restrict__ vd,
             const float* __restrict__ p, const float* __restrict__ resg,
             const float* __restrict__ crl, float* __restrict__ o) {
  int idx = blockIdx.x * 256 + threadIdx.x;
  if (idx >= BLD) return;
  int c = idx % D_;
  long bl = idx / D_;
  int h = c >> 8;
  const float* pp = p + bl * 4;
  float sgate = sigmf(crl[h]) * resg[bl * H_ + h];
  o[idx] = pp[0] * ls[idx] + pp[1] * ll[idx] + pp[2] * dd[idx] + pp[3] * vd[idx] + sgate * ls[idx];
}

// ---------------- o = rmsnorm(o * og) * norm_w ----------------
__global__ __launch_bounds__(256)
void scale_rmsnorm(float* __restrict__ o, const float* __restrict__ og,
                   const float* __restrict__ nw) {
  __shared__ float red[256];
  long row = blockIdx.x;
  long bl = row >> 2;
  int tid = threadIdx.x;
  float v = o[row * 256 + tid] * og[bl];
  red[tid] = v * v;
  __syncthreads();
  for (int st = 128; st > 0; st >>= 1) {
    if (tid < st) red[tid] += red[tid + st];
    __syncthreads();
  }
  float scale = rsqrtf(red[0] / 256.f + 1e-5f);
  o[row * 256 + tid] = v * scale * nw[tid];
}

extern "C" void kernel_launch(void* const* d_in, const int* in_sizes, int n_in,
                              void* d_out, int out_size, void* d_ws, size_t ws_size,
                              hipStream_t stream) {
  const float* hs       = (const float*)d_in[0];
  const float* Wq       = (const float*)d_in[1];
  const float* Wk       = (const float*)d_in[2];
  const float* Wv       = (const float*)d_in[3];
  const float* Wb       = (const float*)d_in[4];
  const float* wq_conv  = (const float*)d_in[5];
  const float* wk_conv  = (const float*)d_in[6];
  const float* wv_conv  = (const float*)d_in[7];
  const float* fir_long = (const float*)d_in[8];
  const float* fir_short= (const float*)d_in[9];
  const float* Wg1      = (const float*)d_in[10];
  const float* bg1      = (const float*)d_in[11];
  const float* Wg2      = (const float*)d_in[12];
  const float* bg2      = (const float*)d_in[13];
  const float* logit_temp     = (const float*)d_in[14];
  const float* conv_res_logit = (const float*)d_in[15];
  const float* Wres     = (const float*)d_in[16];
  const float* bres     = (const float*)d_in[17];
  const float* Wog1     = (const float*)d_in[18];
  const float* bog1     = (const float*)d_in[19];
  const float* Wog2     = (const float*)d_in[20];
  const float* bog2     = (const float*)d_in[21];
  const float* norm_w   = (const float*)d_in[22];
  const float* Wo       = (const float*)d_in[23];
  float* out = (float*)d_out;
  float* ws = (float*)d_ws;

  float* b0 = ws;             // qlin -> kn -> gate_hidden -> o_mix
  float* b1 = ws + 1L * BLD;  // klin -> v_in (v_direct)
  float* b2 = ws + 2L * BLD;  // vlin -> u -> delta_out -> og_hidden
  float* b3 = ws + 3L * BLD;  // qn -> local_long
  float* b4 = ws + 4L * BLD;  // w_bf (bf16, first half) -> local_short
  float* sm = ws + 5L * BLD;
  float* beta    = sm;
  float* resg    = beta + BL * H_;
  float* stats16 = resg + BL * H_;
  float* og8     = stats16 + BL * 16;
  float* logits  = og8 + BL * 8;
  float* pbuf    = logits + BL * 4;
  float* ogv     = pbuf + BL * 4;
  unsigned short* q_bfg  = (unsigned short*)(ogv + BL);   // BLD bf16
  unsigned short* kT_bfg = q_bfg + (long)BLD;             // BLD bf16
  unsigned short* at_bfg = kT_bfg + (long)BLD;            // 1M bf16
  unsigned short* hsb  = at_bfg + 1024L * 1024;           // BLD bf16
  unsigned short* wtq  = hsb + (long)BLD;
  unsigned short* wtk  = wtq + 1024L * 1024;
  unsigned short* wtv  = wtk + 1024L * 1024;
  unsigned short* wtg1 = wtv + 1024L * 1024;
  unsigned short* wto  = wtg1 + 1024L * 1024;
  unsigned short* wtog1= wto + 1024L * 1024;
  unsigned short* w_bfg = (unsigned short*)b4;            // bf16 w inside b4
  unsigned short* xb    = q_bfg;                          // reuse (q_bf dead after scan)

  size_t needed = (5L * BLD + BL * 41) * 4
                + (3L * BLD + 1024L * 1024 + 5L * 1024 * 1024 + 512L * 1024) * 2;
  if (ws_size < needed) return;

  dim3 blk(256);
  // 0. preconvert
  wconv_t<<<dim3(32, 32), blk, 0, stream>>>(Wq, wtq, 1024);
  wconv_t<<<dim3(32, 32), blk, 0, stream>>>(Wk, wtk, 1024);
  wconv_t<<<dim3(32, 32), blk, 0, stream>>>(Wv, wtv, 1024);
  wconv_t<<<dim3(32, 32), blk, 0, stream>>>(Wg1, wtg1, 1024);
  wconv_t<<<dim3(32, 32), blk, 0, stream>>>(Wo, wto, 1024);
  wconv_t<<<dim3(16, 32), blk, 0, stream>>>(Wog1, wtog1, 512);
  cvt_bf16<<<BLD / 1024, blk, 0, stream>>>(hs, hsb, BLD);
  // 1. projections
  gemm_bf16<<<dim3(8, 64), blk, 0, stream>>>(hsb, wtq, b0, 1024);
  gemm_bf16<<<dim3(8, 64), blk, 0, stream>>>(hsb, wtk, b1, 1024);
  gemm_bf16<<<dim3(8, 64), blk, 0, stream>>>(hsb, wtv, b2, 1024);
  // 2. conv + silu (tiled)
  dwconv_tiled<4><<<1024, blk, 0, stream>>>(b0, wq_conv, b3, 1);
  dwconv_tiled<4><<<1024, blk, 0, stream>>>(b1, wk_conv, b0, 1);
  dwconv_tiled<4><<<1024, blk, 0, stream>>>(b2, wv_conv, b1, 1);
  // 3. beta, res gate
  gemv_smallN<<<BL, blk, 0, stream>>>(hs, Wb, nullptr, beta, D_, H_, 1);
  gemv_smallN<<<BL, blk, 0, stream>>>(hs, Wres, bres, resg, D_, H_, 1);
  // 4. l2norm
  l2norm_inplace<<<BL * H_, blk, 0, stream>>>(b3);
  l2norm_inplace<<<BL * H_, blk, 0, stream>>>(b0);
  // 5-6. delta rule (u->b2; bf16 operands; scan writes delta_out in place over u)
  chunk_uw<<<B_ * H_ * NCH, blk, 0, stream>>>(b3, b0, b1, beta, b2, q_bfg, w_bfg, kT_bfg, at_bfg);
  delta_scan<<<128, dim3(64), 0, stream>>>(q_bfg, w_bfg, kT_bfg, at_bfg, b2, b2);
  // 7. local convs
  dwconv_tiled<64><<<1024, blk, 0, stream>>>(b1, fir_long, b3, 0);
  dwconv_tiled<5><<<1024, blk, 0, stream>>>(b1, fir_short, b4, 0);
  // 8. stats16
  head_stats_k<<<BL, blk, 0, stream>>>(b4, stats16, 16, 0);
  head_stats_k<<<BL, blk, 0, stream>>>(b3, stats16, 16, 4);
  head_stats_k<<<BL, blk, 0, stream>>>(b2, stats16, 16, 8);
  head_stats_k<<<BL, blk, 0, stream>>>(b1, stats16, 16, 12);
  // 9. gate hidden
  gemm_bf16<<<dim3(8, 64), blk, 0, stream>>>(hsb, wtg1, b0, 1024);
  tail_bias_gelu<<<(BL * D_) / 256, blk, 0, stream>>>(b0, stats16, Wg1 + 1024L * 1024, bg1, D_, 16);
  // 10. logits, p
  gemv_smallN<<<BL, blk, 0, stream>>>(b0, Wg2, bg2, logits, D_, 4, 0);
  softmax_p<<<BL / 256, blk, 0, stream>>>(logits, logit_temp, pbuf);
  // 11. combine -> b0
  combine<<<BLD / 256, blk, 0, stream>>>(b4, b3, b2, b1, pbuf, resg, conv_res_logit, b0);
  // 12. og stats
  head_stats_k<<<BL, blk, 0, stream>>>(b0, og8, 8, 0);
  head_stats_k<<<BL, blk, 0, stream>>>(b1, og8, 8, 4);
  // 13. output gate
  gemm_bf16<<<dim3(4, 64), blk, 0, stream>>>(hsb, wtog1, b2, 512);
  tail_bias_gelu<<<(BL * 512) / 256, blk, 0, stream>>>(b2, og8, Wog1 + 1024L * 512, bog1, 512, 8);
  gemv_smallN<<<BL, blk, 0, stream>>>(b2, Wog2, bog2, ogv, 512, 1, 1);
  // 14. scale + rmsnorm
  scale_rmsnorm<<<BL * H_, blk, 0, stream>>>(b0, ogv, norm_w);
  // 15. final projection
  cvt_bf16<<<BLD / 1024, blk, 0, stream>>>(b0, xb, BLD);
  gemm_bf16<<<dim3(8, 64), blk, 0, stream>>>(xb, wto, out, 1024);
}

// Round 10
// 1031.015 us; speedup vs baseline: 14.1194x; 1.0905x over previous
//
#include <hip/hip_runtime.h>
#include <math.h>

#define B_ 2
#define L_ 4096
#define D_ 1024
#define H_ 4
#define DH 256
#define CHUNKSZ 32
#define NCH (L_/CHUNKSZ)      // 128
#define BL (B_*L_)            // 8192
#define BLD (B_*L_*D_)        // 8388608

typedef __attribute__((ext_vector_type(8))) short bf16x8;
typedef __attribute__((ext_vector_type(4))) float f32x4;

__device__ __forceinline__ float sigmf(float x) { return 1.f / (1.f + expf(-x)); }
__device__ __forceinline__ float geluf(float x) { return 0.5f * x * (1.f + erff(x * 0.70710678118654752f)); }
__device__ __forceinline__ unsigned short f2bf(float f) {
  unsigned int u = __float_as_uint(f);
  unsigned int r = (u + 0x7FFFu + ((u >> 16) & 1u)) >> 16;
  return (unsigned short)r;
}
__device__ __forceinline__ unsigned int pk2bf(float a, float b) {
  return ((unsigned int)f2bf(b) << 16) | (unsigned int)f2bf(a);
}

// ---------------- f32 -> bf16 elementwise (n multiple of 4) ----------------
__global__ __launch_bounds__(256)
void cvt_bf16(const float* __restrict__ x, unsigned short* __restrict__ y, long n) {
  long i = ((long)blockIdx.x * 256 + threadIdx.x) * 4;
  if (i >= n) return;
  float4 v = *reinterpret_cast<const float4*>(&x[i]);
  ushort4 o;
  o.x = f2bf(v.x); o.y = f2bf(v.y); o.z = f2bf(v.z); o.w = f2bf(v.w);
  *reinterpret_cast<ushort4*>(&y[i]) = o;
}

// ---------------- W[k][n] f32 -> Wt[n][k] bf16 (32x32 tiles) ----------------
__global__ __launch_bounds__(256)
void wconv_t(const float* __restrict__ W, unsigned short* __restrict__ Wt, int N) {
  __shared__ float tile[32][33];
  int kb = blockIdx.y * 32, nb = blockIdx.x * 32;
  int tx = threadIdx.x & 31, ty = threadIdx.x >> 5;
  for (int i = 0; i < 32; i += 8)
    tile[ty + i][tx] = W[(long)(kb + ty + i) * N + nb + tx];
  __syncthreads();
  for (int i = 0; i < 32; i += 8)
    Wt[(long)(nb + ty + i) * 1024 + kb + tx] = f2bf(tile[tx][ty + i]);
}

// ---------------- bf16 MFMA GEMM: C[8192][N] = A[8192][1024] @ Bt[N][1024]^T ----------------
__global__ __launch_bounds__(256)
void gemm_bf16(const unsigned short* __restrict__ A, const unsigned short* __restrict__ Bt,
               float* __restrict__ C, int N) {
  __shared__ unsigned short Al[128 * 32];
  __shared__ unsigned short Bl[128 * 32];
  const int K = 1024;
  int bm = blockIdx.y * 128, bn = blockIdx.x * 128;
  int tid = threadIdx.x;
  int lane = tid & 63, wid = tid >> 6;
  int wr = wid >> 1, wc = wid & 1;
  int l15 = lane & 15, l4 = lane >> 4;
  f32x4 acc[4][4];
#pragma unroll
  for (int i = 0; i < 4; ++i)
#pragma unroll
    for (int j = 0; j < 4; ++j) { acc[i][j].x = 0.f; acc[i][j].y = 0.f; acc[i][j].z = 0.f; acc[i][j].w = 0.f; }
  for (int k0 = 0; k0 < K; k0 += 32) {
    __syncthreads();
#pragma unroll
    for (int i = 0; i < 2; ++i) {
      int idx = tid + i * 256;
      int r = idx >> 2, sl = idx & 3;
      int src = sl ^ ((r >> 1) & 3);
      __builtin_amdgcn_global_load_lds(
          (const __attribute__((address_space(1))) unsigned int*)&A[(long)(bm + r) * K + k0 + src * 8],
          (__attribute__((address_space(3))) unsigned int*)&Al[idx * 8], 16, 0, 0);
      __builtin_amdgcn_global_load_lds(
          (const __attribute__((address_space(1))) unsigned int*)&Bt[(long)(bn + r) * K + k0 + src * 8],
          (__attribute__((address_space(3))) unsigned int*)&Bl[idx * 8], 16, 0, 0);
    }
    __syncthreads();
    bf16x8 af[4], bfr[4];
#pragma unroll
    for (int fi = 0; fi < 4; ++fi) {
      int r = wr * 64 + fi * 16 + l15;
      af[fi] = *reinterpret_cast<const bf16x8*>(&Al[r * 32 + (l4 ^ ((r >> 1) & 3)) * 8]);
    }
#pragma unroll
    for (int fj = 0; fj < 4; ++fj) {
      int r = wc * 64 + fj * 16 + l15;
      bfr[fj] = *reinterpret_cast<const bf16x8*>(&Bl[r * 32 + (l4 ^ ((r >> 1) & 3)) * 8]);
    }
#pragma unroll
    for (int fi = 0; fi < 4; ++fi)
#pragma unroll
      for (int fj = 0; fj < 4; ++fj)
        acc[fi][fj] = __builtin_amdgcn_mfma_f32_16x16x32_bf16(af[fi], bfr[fj], acc[fi][fj], 0, 0, 0);
  }
#pragma unroll
  for (int fi = 0; fi < 4; ++fi) {
    int rb = bm + wr * 64 + fi * 16 + l4 * 4;
#pragma unroll
    for (int fj = 0; fj < 4; ++fj) {
      int cb = bn + wc * 64 + fj * 16 + l15;
#pragma unroll
      for (int j = 0; j < 4; ++j)
        C[(long)(rb + j) * N + cb] = acc[fi][fj][j];
    }
  }
}

// ---------------- tiled depthwise causal conv (+ optional silu), K templated ----------------
#define CTL 128
template<int K>
__global__ __launch_bounds__(256)
void dwconv_tiled(const float* __restrict__ x, const float* __restrict__ w,
                  float* __restrict__ y, int do_silu) {
  __shared__ float tile[(CTL + K - 1) * 64];
  int bid = blockIdx.x;
  int ct = bid & 15;
  int lt = (bid >> 4) & 31;
  int b  = bid >> 9;
  int c0 = ct * 64;
  int l0 = lt * CTL;
  int tid = threadIdx.x;
  const int rows = CTL + K - 1;
  for (int i = tid; i < rows * 16; i += 256) {
    int rr = i >> 4, c4 = i & 15;
    int l = l0 - (K - 1) + rr;
    float4 v = make_float4(0.f, 0.f, 0.f, 0.f);
    if (l >= 0) v = *reinterpret_cast<const float4*>(&x[((long)b * L_ + l) * D_ + c0 + c4 * 4]);
    *reinterpret_cast<float4*>(&tile[rr * 64 + c4 * 4]) = v;
  }
  __syncthreads();
  int c = tid & 63;
  int lo0 = tid >> 6;
  float wreg[K];
#pragma unroll
  for (int j = 0; j < K; ++j) wreg[j] = w[(long)(c0 + c) * K + j];
  for (int lo = lo0; lo < CTL; lo += 4) {
    float acc = 0.f;
#pragma unroll
    for (int j = 0; j < K; ++j)
      acc = fmaf(wreg[j], tile[(lo + j) * 64 + c], acc);
    if (do_silu) acc = acc * sigmf(acc);
    y[((long)b * L_ + l0 + lo) * D_ + c0 + c] = acc;
  }
}

// ---------------- wave-parallel l2norm: 4 rows/block, shuffle reduce ----------------
__global__ __launch_bounds__(256)
void l2norm_wave(float* __restrict__ x) {
  long row = (long)blockIdx.x * 4 + (threadIdx.x >> 6);
  int lane = threadIdx.x & 63;
  float4 v = *reinterpret_cast<const float4*>(&x[row * 256 + lane * 4]);
  float q = v.x * v.x + v.y * v.y + v.z * v.z + v.w * v.w;
#pragma unroll
  for (int st = 32; st > 0; st >>= 1) q += __shfl_xor(q, st);
  float inv = rsqrtf(q + 1e-6f);
  v.x *= inv; v.y *= inv; v.z *= inv; v.w *= inv;
  *reinterpret_cast<float4*>(&x[row * 256 + lane * 4]) = v;
}

// ---------------- fused beta/resg GEMV: wave n computes both dots ----------------
__global__ __launch_bounds__(256)
void beta_res_gemv(const float* __restrict__ hs, const float* __restrict__ Wb,
                   const float* __restrict__ Wres, const float* __restrict__ bres,
                   float* __restrict__ beta, float* __restrict__ resg) {
  long m = blockIdx.x;
  int n = threadIdx.x >> 6, lane = threadIdx.x & 63;
  float ab = 0.f, ar = 0.f;
  for (int k0 = lane * 4; k0 < 1024; k0 += 256) {
    float4 x = *reinterpret_cast<const float4*>(&hs[m * 1024 + k0]);
    ab += x.x * Wb[(k0 + 0) * 4 + n] + x.y * Wb[(k0 + 1) * 4 + n]
        + x.z * Wb[(k0 + 2) * 4 + n] + x.w * Wb[(k0 + 3) * 4 + n];
    ar += x.x * Wres[(k0 + 0) * 4 + n] + x.y * Wres[(k0 + 1) * 4 + n]
        + x.z * Wres[(k0 + 2) * 4 + n] + x.w * Wres[(k0 + 3) * 4 + n];
  }
#pragma unroll
  for (int st = 32; st > 0; st >>= 1) { ab += __shfl_xor(ab, st); ar += __shfl_xor(ar, st); }
  if (lane == 0) {
    beta[m * 4 + n] = sigmf(ab);
    resg[m * 4 + n] = sigmf(ar + bres[n]);
  }
}

// ---------------- wave GEMV N=4 (logits) ----------------
__global__ __launch_bounds__(256)
void gemv4(const float* __restrict__ X, const float* __restrict__ W,
           const float* __restrict__ bias, float* __restrict__ out) {
  long m = blockIdx.x;
  int n = threadIdx.x >> 6, lane = threadIdx.x & 63;
  float a = 0.f;
  for (int k0 = lane * 4; k0 < 1024; k0 += 256) {
    float4 x = *reinterpret_cast<const float4*>(&X[m * 1024 + k0]);
    a += x.x * W[(k0 + 0) * 4 + n] + x.y * W[(k0 + 1) * 4 + n]
       + x.z * W[(k0 + 2) * 4 + n] + x.w * W[(k0 + 3) * 4 + n];
  }
#pragma unroll
  for (int st = 32; st > 0; st >>= 1) a += __shfl_xor(a, st);
  if (lane == 0) out[m * 4 + n] = a + bias[n];
}

// ---------------- wave GEMV N=1 K=512 + sigmoid (og) ----------------
__global__ __launch_bounds__(64)
void gemv1_sig(const float* __restrict__ X, const float* __restrict__ W,
               const float* __restrict__ bias, float* __restrict__ out) {
  long m = blockIdx.x;
  int lane = threadIdx.x;
  float a = 0.f;
  for (int k0 = lane * 4; k0 < 512; k0 += 256) {
    float4 x = *reinterpret_cast<const float4*>(&X[m * 512 + k0]);
    a += x.x * W[k0] + x.y * W[k0 + 1] + x.z * W[k0 + 2] + x.w * W[k0 + 3];
  }
#pragma unroll
  for (int st = 32; st > 0; st >>= 1) a += __shfl_xor(a, st);
  if (lane == 0) out[m] = sigmf(a + bias[0]);
}

// ---------------- per-chunk: inv, u (f32), and bf16 operands for the scan ----------------
__global__ __launch_bounds__(256)
void chunk_uw(const float* __restrict__ qn, const float* __restrict__ kn,
              const float* __restrict__ v, const float* __restrict__ beta,
              float* __restrict__ u,
              unsigned short* __restrict__ q_bf, unsigned short* __restrict__ w_bf,
              unsigned short* __restrict__ kT_bf, unsigned short* __restrict__ at_bf) {
  __shared__ float skT[256][33];
  __shared__ float sinv[32][33];
  __shared__ float sbeta[32];
  int blk = blockIdx.x;
  int ci = blk % NCH;
  int bh = blk / NCH;
  int h = bh % H_;
  int b = bh / H_;
  long base = ((long)b * L_ + (long)ci * CHUNKSZ) * D_ + h * DH;
  long brow = (long)b * L_ + (long)ci * CHUNKSZ;
  long obase = (long)blk * 8192;   // blk == bh*NCH+ci
  int tid = threadIdx.x;
  for (int i = tid; i < 32 * 256; i += 256) {
    int r = i >> 8, c = i & 255;
    skT[c][r] = kn[base + (long)r * D_ + c];
  }
  if (tid < 32) sbeta[tid] = beta[(brow + tid) * H_ + h];
  __syncthreads();
  for (int i = tid; i < 8192; i += 256)
    kT_bf[obase + i] = f2bf(skT[i >> 5][i & 31]);
  for (int i = tid; i < 8192; i += 256)
    q_bf[obase + i] = f2bf(qn[base + (long)(i >> 8) * D_ + (i & 255)]);
  int j = tid & 31, i0 = tid >> 5;
  for (int r = 0; r < 4; ++r) {
    int i = i0 + (r << 3);
    float acc = 0.f;
    for (int d = 0; d < 256; ++d) acc += skT[d][i] * skT[d][j];
    sinv[i][j] = (i > j) ? -acc * sbeta[i] : 0.f;
  }
  __syncthreads();
  for (int i = 1; i < 32; ++i) {
    float val = 0.f;
    if (tid < 32) {
      for (int t = 0; t < i; ++t) val += sinv[i][t] * sinv[t][tid];
    }
    __syncthreads();
    if (tid < 32) sinv[i][tid] += val;
    __syncthreads();
  }
  if (tid < 32) sinv[tid][tid] += 1.f;
  long abase = (long)blk * 1024;
  for (int r = 0; r < 4; ++r) {
    int i = i0 + (r << 3);
    const float* qrow = qn + base + (long)i * D_;
    float acc = 0.f;
    for (int d = 0; d < 256; ++d) acc += qrow[d] * skT[d][j];
    at_bf[abase + i * 32 + j] = f2bf((i >= j) ? acc : 0.f);
  }
  __syncthreads();
  int c = tid;
  float vt[32], kt[32];
#pragma unroll
  for (int t = 0; t < 32; ++t) {
    vt[t] = v[base + t * D_ + c] * sbeta[t];
    kt[t] = skT[c][t] * sbeta[t];
  }
#pragma unroll
  for (int i2 = 0; i2 < 32; ++i2) {
    float au = 0.f, aw = 0.f;
#pragma unroll
    for (int t = 0; t <= i2; ++t) {
      float f = sinv[i2][t];
      au += f * vt[t];
      aw += f * kt[t];
    }
    u[base + i2 * D_ + c] = au;
    w_bf[obase + i2 * 256 + c] = f2bf(aw);
  }
}

// ---------------- MFMA scan, barrier-free, FULL consume-then-prefetch pipeline ----------------
// 128 blocks x 1 wave; wave owns 16 cols, full K. S f32 in accumulators.
// Every operand class loaded one chunk ahead, issued right after its current consumer:
//   w@S -> LOAD_W(ci+1) ; u2 -> LOAD_U ; q@S -> LOAD_Q ; S+= -> LOAD_K ; out -> LOAD_A.
// Each load has >= 1 full chunk of covered slack; no vmcnt wait on the serial chain.
// `out` aliases `u` (disjoint rows/cols between reads and writes).
__global__ __launch_bounds__(64, 1)
void delta_scan(const unsigned short* __restrict__ qb, const unsigned short* __restrict__ wbf,
                const unsigned short* __restrict__ ktb, const unsigned short* __restrict__ atb,
                const float* u, float* out) {
  __shared__ unsigned short sB[16 * 264];   // S^T staging: [n=16][d=256] pad 264
  __shared__ unsigned short su2[16 * 40];   // u2^T: [n=16][t=32] pad 40
  int blk = blockIdx.x;
  int bh = blk & 7, cg = blk >> 3;          // same-bh blocks land on one XCD
  int h = bh & 3, b = bh >> 2;
  int lane = threadIdx.x;
  int l15 = lane & 15, l4 = lane >> 4;
  int colw = cg * 16;

  f32x4 zero4; zero4.x = 0.f; zero4.y = 0.f; zero4.z = 0.f; zero4.w = 0.f;
  f32x4 acc[16];
#pragma unroll
  for (int t = 0; t < 16; ++t) acc[t] = zero4;

  uint4 wf[2][8];
  float ru[2][4];
  uint4 qf[2][8];
  uint4 kf[16];
  uint4 af[2];

#define LOAD_W(CI) do {                                                          \
    long o8_ = ((long)bh * NCH + (CI)) * 8192;                                   \
    _Pragma("unroll")                                                            \
    for (int m_ = 0; m_ < 2; ++m_)                                               \
      _Pragma("unroll")                                                          \
      for (int kc_ = 0; kc_ < 8; ++kc_)                                          \
        wf[m_][kc_] = *reinterpret_cast<const uint4*>(                           \
            &wbf[o8_ + (16 * m_ + l15) * 256 + kc_ * 32 + l4 * 8]);              \
  } while (0)

#define LOAD_U(CI) do {                                                          \
    long ub_ = ((long)b * L_ + (long)(CI) * CHUNKSZ) * D_ + h * DH + colw;       \
    _Pragma("unroll")                                                            \
    for (int m_ = 0; m_ < 2; ++m_)                                               \
      _Pragma("unroll")                                                          \
      for (int r_ = 0; r_ < 4; ++r_)                                             \
        ru[m_][r_] = u[ub_ + (long)(16 * m_ + 4 * l4 + r_) * D_ + l15];          \
  } while (0)

#define LOAD_Q(CI) do {                                                          \
    long o8_ = ((long)bh * NCH + (CI)) * 8192;                                   \
    _Pragma("unroll")                                                            \
    for (int m_ = 0; m_ < 2; ++m_)                                               \
      _Pragma("unroll")                                                          \
      for (int kc_ = 0; kc_ < 8; ++kc_)                                          \
        qf[m_][kc_] = *reinterpret_cast<const uint4*>(                           \
            &qb[o8_ + (16 * m_ + l15) * 256 + kc_ * 32 + l4 * 8]);               \
  } while (0)

#define LOAD_K(CI) do {                                                          \
    long o8_ = ((long)bh * NCH + (CI)) * 8192;                                   \
    _Pragma("unroll")                                                            \
    for (int dt_ = 0; dt_ < 16; ++dt_)                                           \
      kf[dt_] = *reinterpret_cast<const uint4*>(                                 \
          &ktb[o8_ + (16 * dt_ + l15) * 32 + l4 * 8]);                           \
  } while (0)

#define LOAD_A(CI) do {                                                          \
    long oa_ = ((long)bh * NCH + (CI)) * 1024;                                   \
    _Pragma("unroll")                                                            \
    for (int m_ = 0; m_ < 2; ++m_)                                               \
      af[m_] = *reinterpret_cast<const uint4*>(                                  \
          &atb[oa_ + (16 * m_ + l15) * 32 + l4 * 8]);                            \
  } while (0)

  LOAD_W(0); LOAD_U(0); LOAD_Q(0); LOAD_K(0); LOAD_A(0);

  for (int ci = 0; ci < NCH; ++ci) {
    long ub = ((long)b * L_ + (long)ci * CHUNKSZ) * D_ + h * DH + colw;
    bool more = (ci + 1 < NCH);
    // ---- pack S -> sB (wave-local), read B-frags ----
#pragma unroll
    for (int dt = 0; dt < 16; ++dt) {
      uint2 pv;
      pv.x = pk2bf(acc[dt].x, acc[dt].y);
      pv.y = pk2bf(acc[dt].z, acc[dt].w);
      *reinterpret_cast<uint2*>(&sB[l15 * 264 + dt * 16 + l4 * 4]) = pv;
    }
    bf16x8 sf[8];
#pragma unroll
    for (int kc = 0; kc < 8; ++kc)
      sf[kc] = *reinterpret_cast<const bf16x8*>(&sB[l15 * 264 + kc * 32 + l4 * 8]);
    // ---- w@S (4 interleaved partial chains); then prefetch next w ----
    f32x4 wa[2][2];
    wa[0][0] = zero4; wa[0][1] = zero4; wa[1][0] = zero4; wa[1][1] = zero4;
#pragma unroll
    for (int kc = 0; kc < 8; ++kc) {
#pragma unroll
      for (int m = 0; m < 2; ++m)
        wa[m][kc & 1] = __builtin_amdgcn_mfma_f32_16x16x32_bf16(
            *reinterpret_cast<bf16x8*>(&wf[m][kc]), sf[kc], wa[m][kc & 1], 0, 0, 0);
    }
    if (more) LOAD_W(ci + 1);
    // ---- u2 = u - wS -> su2 -> B-frag; then prefetch next u ----
#pragma unroll
    for (int m = 0; m < 2; ++m) {
      f32x4 ws = wa[m][0] + wa[m][1];
      uint2 pv;
      pv.x = pk2bf(ru[m][0] - ws.x, ru[m][1] - ws.y);
      pv.y = pk2bf(ru[m][2] - ws.z, ru[m][3] - ws.w);
      *reinterpret_cast<uint2*>(&su2[l15 * 40 + m * 16 + l4 * 4]) = pv;
    }
    if (more) LOAD_U(ci + 1);
    bf16x8 u2f = *reinterpret_cast<const bf16x8*>(&su2[l15 * 40 + l4 * 8]);
    // ---- q@S; then prefetch next q ----
    f32x4 qa[2][2];
    qa[0][0] = zero4; qa[0][1] = zero4; qa[1][0] = zero4; qa[1][1] = zero4;
#pragma unroll
    for (int kc = 0; kc < 8; ++kc) {
#pragma unroll
      for (int m = 0; m < 2; ++m)
        qa[m][kc & 1] = __builtin_amdgcn_mfma_f32_16x16x32_bf16(
            *reinterpret_cast<bf16x8*>(&qf[m][kc]), sf[kc], qa[m][kc & 1], 0, 0, 0);
    }
    if (more) LOAD_Q(ci + 1);
    // ---- S += kT @ u2; then prefetch next kT ----
#pragma unroll
    for (int dt = 0; dt < 16; ++dt)
      acc[dt] = __builtin_amdgcn_mfma_f32_16x16x32_bf16(
          *reinterpret_cast<bf16x8*>(&kf[dt]), u2f, acc[dt], 0, 0, 0);
    if (more) LOAD_K(ci + 1);
    // ---- out = qS + attn@u2; then prefetch next attn ----
#pragma unroll
    for (int m = 0; m < 2; ++m) {
      f32x4 qacc = qa[m][0] + qa[m][1];
      f32x4 dv = __builtin_amdgcn_mfma_f32_16x16x32_bf16(
          *reinterpret_cast<bf16x8*>(&af[m]), u2f, qacc, 0, 0, 0);
#pragma unroll
      for (int r = 0; r < 4; ++r)
        out[ub + (long)(16 * m + 4 * l4 + r) * D_ + l15] = dv[r];
    }
    if (more) LOAD_A(ci + 1);
  }
#undef LOAD_W
#undef LOAD_U
#undef LOAD_Q
#undef LOAD_K
#undef LOAD_A
}

// ---------------- fused head stats x4 tensors: wave w -> tensor w ----------------
__global__ __launch_bounds__(256)
void head_stats4(const float* __restrict__ t0, const float* __restrict__ t1,
                 const float* __restrict__ t2, const float* __restrict__ t3,
                 float* __restrict__ outp) {
  long bl = blockIdx.x;
  int w = threadIdx.x >> 6, lane = threadIdx.x & 63;
  const float* x = (w == 0) ? t0 : (w == 1) ? t1 : (w == 2) ? t2 : t3;
  float m = 0.f, vv = 0.f, am = 0.f, l2 = 0.f;
#pragma unroll
  for (int h = 0; h < 4; ++h) {
    float4 v = *reinterpret_cast<const float4*>(&x[bl * 1024 + h * 256 + lane * 4]);
    float s = v.x + v.y + v.z + v.w;
    float q = v.x * v.x + v.y * v.y + v.z * v.z + v.w * v.w;
    float a = fabsf(v.x) + fabsf(v.y) + fabsf(v.z) + fabsf(v.w);
#pragma unroll
    for (int st = 32; st > 0; st >>= 1) {
      s += __shfl_xor(s, st); q += __shfl_xor(q, st); a += __shfl_xor(a, st);
    }
    float mean = s * (1.f / 256.f);
    m += mean;
    vv += q * (1.f / 256.f) - mean * mean;
    am += a * (1.f / 256.f);
    l2 += sqrtf(q);
  }
  if (lane == 0) {
    float* o = outp + bl * 16 + w * 4;
    o[0] = m * 0.25f; o[1] = vv * 0.25f; o[2] = am * 0.25f; o[3] = l2 * 0.25f;
  }
}

// ---------------- fused head stats x2 tensors (og) ----------------
__global__ __launch_bounds__(128)
void head_stats2(const float* __restrict__ t0, const float* __restrict__ t1,
                 float* __restrict__ outp) {
  long bl = blockIdx.x;
  int w = threadIdx.x >> 6, lane = threadIdx.x & 63;
  const float* x = (w == 0) ? t0 : t1;
  float m = 0.f, vv = 0.f, am = 0.f, l2 = 0.f;
#pragma unroll
  for (int h = 0; h < 4; ++h) {
    float4 v = *reinterpret_cast<const float4*>(&x[bl * 1024 + h * 256 + lane * 4]);
    float s = v.x + v.y + v.z + v.w;
    float q = v.x * v.x + v.y * v.y + v.z * v.z + v.w * v.w;
    float a = fabsf(v.x) + fabsf(v.y) + fabsf(v.z) + fabsf(v.w);
#pragma unroll
    for (int st = 32; st > 0; st >>= 1) {
      s += __shfl_xor(s, st); q += __shfl_xor(q, st); a += __shfl_xor(a, st);
    }
    float mean = s * (1.f / 256.f);
    m += mean;
    vv += q * (1.f / 256.f) - mean * mean;
    am += a * (1.f / 256.f);
    l2 += sqrtf(q);
  }
  if (lane == 0) {
    float* o = outp + bl * 8 + w * 4;
    o[0] = m * 0.25f; o[1] = vv * 0.25f; o[2] = am * 0.25f; o[3] = l2 * 0.25f;
  }
}

// ---------------- g = gelu(g + bias + stats @ Wtail) ----------------
__global__ __launch_bounds__(256)
void tail_bias_gelu(float* __restrict__ g, const float* __restrict__ stats,
                    const float* __restrict__ Wt, const float* __restrict__ bias,
                    int N, int K2) {
  long idx = (long)blockIdx.x * 256 + threadIdx.x;
  if (idx >= (long)BL * N) return;
  int n = idx % N;
  long m = idx / N;
  float s = g[idx] + bias[n];
  for (int k = 0; k < K2; ++k) s += stats[m * K2 + k] * Wt[(long)k * N + n];
  g[idx] = geluf(s);
}

// ---------------- softmax with temp, clip, renorm ----------------
__global__ __launch_bounds__(256)
void softmax_p(const float* __restrict__ logits, const float* __restrict__ temp_in,
               float* __restrict__ p) {
  int bl = blockIdx.x * 256 + threadIdx.x;
  if (bl >= BL) return;
  float temp = log1pf(expf(temp_in[0]));
  float l0 = logits[bl * 4 + 0] / temp, l1 = logits[bl * 4 + 1] / temp;
  float l2 = logits[bl * 4 + 2] / temp, l3 = logits[bl * 4 + 3] / temp;
  float mx = fmaxf(fmaxf(l0, l1), fmaxf(l2, l3));
  float e0 = expf(l0 - mx), e1 = expf(l1 - mx), e2 = expf(l2 - mx), e3 = expf(l3 - mx);
  float s = e0 + e1 + e2 + e3;
  e0 /= s; e1 /= s; e2 /= s; e3 /= s;
  e0 = fmaxf(e0, 0.02f); e1 = fmaxf(e1, 0.02f); e2 = fmaxf(e2, 0.02f); e3 = fmaxf(e3, 0.02f);
  s = e0 + e1 + e2 + e3;
  p[bl * 4 + 0] = e0 / s; p[bl * 4 + 1] = e1 / s; p[bl * 4 + 2] = e2 / s; p[bl * 4 + 3] = e3 / s;
}

// ---------------- mixture combine + conv residual ----------------
__global__ __launch_bounds__(256)
void combine(const float* __restrict__ ls, const float* __restrict__ ll,
             const float* __restrict__ dd, const float* __restrict__ vd,
             const float* __restrict__ p, const float* __restrict__ resg,
             const float* __restrict__ crl, float* __restrict__ o) {
  int idx = blockIdx.x * 256 + threadIdx.x;
  if (idx >= BLD) return;
  int c = idx % D_;
  long bl = idx / D_;
  int h = c >> 8;
  const float* pp = p + bl * 4;
  float sgate = sigmf(crl[h]) * resg[bl * H_ + h];
  o[idx] = pp[0] * ls[idx] + pp[1] * ll[idx] + pp[2] * dd[idx] + pp[3] * vd[idx] + sgate * ls[idx];
}

// ---------------- wave-parallel scale+rmsnorm: 4 rows/block ----------------
__global__ __launch_bounds__(256)
void scale_rmsnorm_wave(float* __restrict__ o, const float* __restrict__ og,
                        const float* __restrict__ nw) {
  long row = (long)blockIdx.x * 4 + (threadIdx.x >> 6);
  long bl = row >> 2;
  int lane = threadIdx.x & 63;
  float g = og[bl];
  float4 v = *reinterpret_cast<const float4*>(&o[row * 256 + lane * 4]);
  v.x *= g; v.y *= g; v.z *= g; v.w *= g;
  float q = v.x * v.x + v.y * v.y + v.z * v.z + v.w * v.w;
#pragma unroll
  for (int st = 32; st > 0; st >>= 1) q += __shfl_xor(q, st);
  float scale = rsqrtf(q * (1.f / 256.f) + 1e-5f);
  float4 w4 = *reinterpret_cast<const float4*>(&nw[lane * 4]);
  v.x *= scale * w4.x; v.y *= scale * w4.y; v.z *= scale * w4.z; v.w *= scale * w4.w;
  *reinterpret_cast<float4*>(&o[row * 256 + lane * 4]) = v;
}

extern "C" void kernel_launch(void* const* d_in, const int* in_sizes, int n_in,
                              void* d_out, int out_size, void* d_ws, size_t ws_size,
                              hipStream_t stream) {
  const float* hs       = (const float*)d_in[0];
  const float* Wq       = (const float*)d_in[1];
  const float* Wk       = (const float*)d_in[2];
  const float* Wv       = (const float*)d_in[3];
  const float* Wb       = (const float*)d_in[4];
  const float* wq_conv  = (const float*)d_in[5];
  const float* wk_conv  = (const float*)d_in[6];
  const float* wv_conv  = (const float*)d_in[7];
  const float* fir_long = (const float*)d_in[8];
  const float* fir_short= (const float*)d_in[9];
  const float* Wg1      = (const float*)d_in[10];
  const float* bg1      = (const float*)d_in[11];
  const float* Wg2      = (const float*)d_in[12];
  const float* bg2      = (const float*)d_in[13];
  const float* logit_temp     = (const float*)d_in[14];
  const float* conv_res_logit = (const float*)d_in[15];
  const float* Wres     = (const float*)d_in[16];
  const float* bres     = (const float*)d_in[17];
  const float* Wog1     = (const float*)d_in[18];
  const float* bog1     = (const float*)d_in[19];
  const float* Wog2     = (const float*)d_in[20];
  const float* bog2     = (const float*)d_in[21];
  const float* norm_w   = (const float*)d_in[22];
  const float* Wo       = (const float*)d_in[23];
  float* out = (float*)d_out;
  float* ws = (float*)d_ws;

  float* b0 = ws;             // qlin -> kn -> gate_hidden -> o_mix
  float* b1 = ws + 1L * BLD;  // klin -> v_in (v_direct)
  float* b2 = ws + 2L * BLD;  // vlin -> u -> delta_out -> og_hidden
  float* b3 = ws + 3L * BLD;  // qn -> local_long
  float* b4 = ws + 4L * BLD;  // w_bf (bf16, first half) -> local_short
  float* sm = ws + 5L * BLD;
  float* beta    = sm;
  float* resg    = beta + BL * H_;
  float* stats16 = resg + BL * H_;
  float* og8     = stats16 + BL * 16;
  float* logits  = og8 + BL * 8;
  float* pbuf    = logits + BL * 4;
  float* ogv     = pbuf + BL * 4;
  unsigned short* q_bfg  = (unsigned short*)(ogv + BL);   // BLD bf16
  unsigned short* kT_bfg = q_bfg + (long)BLD;             // BLD bf16
  unsigned short* at_bfg = kT_bfg + (long)BLD;            // 1M bf16
  unsigned short* hsb  = at_bfg + 1024L * 1024;           // BLD bf16
  unsigned short* wtq  = hsb + (long)BLD;
  unsigned short* wtk  = wtq + 1024L * 1024;
  unsigned short* wtv  = wtk + 1024L * 1024;
  unsigned short* wtg1 = wtv + 1024L * 1024;
  unsigned short* wto  = wtg1 + 1024L * 1024;
  unsigned short* wtog1= wto + 1024L * 1024;
  unsigned short* w_bfg = (unsigned short*)b4;            // bf16 w inside b4
  unsigned short* xb    = q_bfg;                          // reuse (q_bf dead after scan)

  size_t needed = (5L * BLD + BL * 41) * 4
                + (3L * BLD + 1024L * 1024 + 5L * 1024 * 1024 + 512L * 1024) * 2;
  if (ws_size < needed) return;

  dim3 blk(256);
  // 0. preconvert
  wconv_t<<<dim3(32, 32), blk, 0, stream>>>(Wq, wtq, 1024);
  wconv_t<<<dim3(32, 32), blk, 0, stream>>>(Wk, wtk, 1024);
  wconv_t<<<dim3(32, 32), blk, 0, stream>>>(Wv, wtv, 1024);
  wconv_t<<<dim3(32, 32), blk, 0, stream>>>(Wg1, wtg1, 1024);
  wconv_t<<<dim3(32, 32), blk, 0, stream>>>(Wo, wto, 1024);
  wconv_t<<<dim3(16, 32), blk, 0, stream>>>(Wog1, wtog1, 512);
  cvt_bf16<<<BLD / 1024, blk, 0, stream>>>(hs, hsb, BLD);
  // 1. projections
  gemm_bf16<<<dim3(8, 64), blk, 0, stream>>>(hsb, wtq, b0, 1024);
  gemm_bf16<<<dim3(8, 64), blk, 0, stream>>>(hsb, wtk, b1, 1024);
  gemm_bf16<<<dim3(8, 64), blk, 0, stream>>>(hsb, wtv, b2, 1024);
  // 2. conv + silu (tiled)
  dwconv_tiled<4><<<1024, blk, 0, stream>>>(b0, wq_conv, b3, 1);
  dwconv_tiled<4><<<1024, blk, 0, stream>>>(b1, wk_conv, b0, 1);
  dwconv_tiled<4><<<1024, blk, 0, stream>>>(b2, wv_conv, b1, 1);
  // 3. beta + res gate (fused wave GEMV)
  beta_res_gemv<<<BL, blk, 0, stream>>>(hs, Wb, Wres, bres, beta, resg);
  // 4. l2norm (wave-parallel)
  l2norm_wave<<<BL * H_ / 4, blk, 0, stream>>>(b3);
  l2norm_wave<<<BL * H_ / 4, blk, 0, stream>>>(b0);
  // 5-6. delta rule (u->b2; bf16 operands; scan writes delta_out in place over u)
  chunk_uw<<<B_ * H_ * NCH, blk, 0, stream>>>(b3, b0, b1, beta, b2, q_bfg, w_bfg, kT_bfg, at_bfg);
  delta_scan<<<128, dim3(64), 0, stream>>>(q_bfg, w_bfg, kT_bfg, at_bfg, b2, b2);
  // 7. local convs
  dwconv_tiled<64><<<1024, blk, 0, stream>>>(b1, fir_long, b3, 0);
  dwconv_tiled<5><<<1024, blk, 0, stream>>>(b1, fir_short, b4, 0);
  // 8. stats16 fused (ls=b4, ll=b3, dd=b2, vd=b1)
  head_stats4<<<BL, blk, 0, stream>>>(b4, b3, b2, b1, stats16);
  // 9. gate hidden
  gemm_bf16<<<dim3(8, 64), blk, 0, stream>>>(hsb, wtg1, b0, 1024);
  tail_bias_gelu<<<(BL * D_) / 256, blk, 0, stream>>>(b0, stats16, Wg1 + 1024L * 1024, bg1, D_, 16);
  // 10. logits, p
  gemv4<<<BL, blk, 0, stream>>>(b0, Wg2, bg2, logits);
  softmax_p<<<BL / 256, blk, 0, stream>>>(logits, logit_temp, pbuf);
  // 11. combine -> b0
  combine<<<BLD / 256, blk, 0, stream>>>(b4, b3, b2, b1, pbuf, resg, conv_res_logit, b0);
  // 12. og stats fused (o=b0, vd=b1)
  head_stats2<<<BL, dim3(128), 0, stream>>>(b0, b1, og8);
  // 13. output gate
  gemm_bf16<<<dim3(4, 64), blk, 0, stream>>>(hsb, wtog1, b2, 512);
  tail_bias_gelu<<<(BL * 512) / 256, blk, 0, stream>>>(b2, og8, Wog1 + 1024L * 512, bog1, 512, 8);
  gemv1_sig<<<BL, dim3(64), 0, stream>>>(b2, Wog2, bog2, ogv);
  // 14. scale + rmsnorm (wave-parallel)
  scale_rmsnorm_wave<<<BL * H_ / 4, blk, 0, stream>>>(b0, ogv, norm_w);
  // 15. final projection
  cvt_bf16<<<BLD / 1024, blk, 0, stream>>>(b0, xb, BLD);
  gemm_bf16<<<dim3(8, 64), blk, 0, stream>>>(xb, wto, out, 1024);
}

// Round 11
// 942.242 us; speedup vs baseline: 15.4497x; 1.0942x over previous
//
#include <hip/hip_runtime.h>
#include <math.h>

#define B_ 2
#define L_ 4096
#define D_ 1024
#define H_ 4
#define DH 256
#define CHUNKSZ 32
#define NCH (L_/CHUNKSZ)      // 128
#define BL (B_*L_)            // 8192
#define BLD (B_*L_*D_)        // 8388608

typedef __attribute__((ext_vector_type(8))) short bf16x8;
typedef __attribute__((ext_vector_type(4))) float f32x4;

__device__ __forceinline__ float sigmf(float x) { return 1.f / (1.f + expf(-x)); }
__device__ __forceinline__ float geluf(float x) { return 0.5f * x * (1.f + erff(x * 0.70710678118654752f)); }
__device__ __forceinline__ unsigned short f2bf(float f) {
  unsigned int u = __float_as_uint(f);
  unsigned int r = (u + 0x7FFFu + ((u >> 16) & 1u)) >> 16;
  return (unsigned short)r;
}
__device__ __forceinline__ unsigned int pk2bf(float a, float b) {
  return ((unsigned int)f2bf(b) << 16) | (unsigned int)f2bf(a);
}

// ---------------- f32 -> bf16 elementwise (n multiple of 4) ----------------
__global__ __launch_bounds__(256)
void cvt_bf16(const float* __restrict__ x, unsigned short* __restrict__ y, long n) {
  long i = ((long)blockIdx.x * 256 + threadIdx.x) * 4;
  if (i >= n) return;
  float4 v = *reinterpret_cast<const float4*>(&x[i]);
  ushort4 o;
  o.x = f2bf(v.x); o.y = f2bf(v.y); o.z = f2bf(v.z); o.w = f2bf(v.w);
  *reinterpret_cast<ushort4*>(&y[i]) = o;
}

// ---------------- W[k][n] f32 -> Wt[n][k] bf16 (32x32 tiles) ----------------
__global__ __launch_bounds__(256)
void wconv_t(const float* __restrict__ W, unsigned short* __restrict__ Wt, int N) {
  __shared__ float tile[32][33];
  int kb = blockIdx.y * 32, nb = blockIdx.x * 32;
  int tx = threadIdx.x & 31, ty = threadIdx.x >> 5;
  for (int i = 0; i < 32; i += 8)
    tile[ty + i][tx] = W[(long)(kb + ty + i) * N + nb + tx];
  __syncthreads();
  for (int i = 0; i < 32; i += 8)
    Wt[(long)(nb + ty + i) * 1024 + kb + tx] = f2bf(tile[tx][ty + i]);
}

// ---------------- bf16 MFMA GEMM: C[8192][N] = A[8192][1024] @ Bt[N][1024]^T ----------------
__global__ __launch_bounds__(256)
void gemm_bf16(const unsigned short* __restrict__ A, const unsigned short* __restrict__ Bt,
               float* __restrict__ C, int N) {
  __shared__ unsigned short Al[128 * 32];
  __shared__ unsigned short Bl[128 * 32];
  const int K = 1024;
  int bm = blockIdx.y * 128, bn = blockIdx.x * 128;
  int tid = threadIdx.x;
  int lane = tid & 63, wid = tid >> 6;
  int wr = wid >> 1, wc = wid & 1;
  int l15 = lane & 15, l4 = lane >> 4;
  f32x4 acc[4][4];
#pragma unroll
  for (int i = 0; i < 4; ++i)
#pragma unroll
    for (int j = 0; j < 4; ++j) { acc[i][j].x = 0.f; acc[i][j].y = 0.f; acc[i][j].z = 0.f; acc[i][j].w = 0.f; }
  for (int k0 = 0; k0 < K; k0 += 32) {
    __syncthreads();
#pragma unroll
    for (int i = 0; i < 2; ++i) {
      int idx = tid + i * 256;
      int r = idx >> 2, sl = idx & 3;
      int src = sl ^ ((r >> 1) & 3);
      __builtin_amdgcn_global_load_lds(
          (const __attribute__((address_space(1))) unsigned int*)&A[(long)(bm + r) * K + k0 + src * 8],
          (__attribute__((address_space(3))) unsigned int*)&Al[idx * 8], 16, 0, 0);
      __builtin_amdgcn_global_load_lds(
          (const __attribute__((address_space(1))) unsigned int*)&Bt[(long)(bn + r) * K + k0 + src * 8],
          (__attribute__((address_space(3))) unsigned int*)&Bl[idx * 8], 16, 0, 0);
    }
    __syncthreads();
    bf16x8 af[4], bfr[4];
#pragma unroll
    for (int fi = 0; fi < 4; ++fi) {
      int r = wr * 64 + fi * 16 + l15;
      af[fi] = *reinterpret_cast<const bf16x8*>(&Al[r * 32 + (l4 ^ ((r >> 1) & 3)) * 8]);
    }
#pragma unroll
    for (int fj = 0; fj < 4; ++fj) {
      int r = wc * 64 + fj * 16 + l15;
      bfr[fj] = *reinterpret_cast<const bf16x8*>(&Bl[r * 32 + (l4 ^ ((r >> 1) & 3)) * 8]);
    }
#pragma unroll
    for (int fi = 0; fi < 4; ++fi)
#pragma unroll
      for (int fj = 0; fj < 4; ++fj)
        acc[fi][fj] = __builtin_amdgcn_mfma_f32_16x16x32_bf16(af[fi], bfr[fj], acc[fi][fj], 0, 0, 0);
  }
#pragma unroll
  for (int fi = 0; fi < 4; ++fi) {
    int rb = bm + wr * 64 + fi * 16 + l4 * 4;
#pragma unroll
    for (int fj = 0; fj < 4; ++fj) {
      int cb = bn + wc * 64 + fj * 16 + l15;
#pragma unroll
      for (int j = 0; j < 4; ++j)
        C[(long)(rb + j) * N + cb] = acc[fi][fj][j];
    }
  }
}

// ---------------- tiled depthwise causal conv, sliding-window (8 consecutive outputs/group) ----------------
#define CTL 128
template<int K>
__global__ __launch_bounds__(256)
void dwconv_tiled(const float* __restrict__ x, const float* __restrict__ w,
                  float* __restrict__ y, int do_silu) {
  __shared__ float tile[(CTL + K - 1) * 64];
  int bid = blockIdx.x;
  int ct = bid & 15;
  int lt = (bid >> 4) & 31;
  int b  = bid >> 9;
  int c0 = ct * 64;
  int l0 = lt * CTL;
  int tid = threadIdx.x;
  const int rows = CTL + K - 1;
  for (int i = tid; i < rows * 16; i += 256) {
    int rr = i >> 4, c4 = i & 15;
    int l = l0 - (K - 1) + rr;
    float4 v = make_float4(0.f, 0.f, 0.f, 0.f);
    if (l >= 0) v = *reinterpret_cast<const float4*>(&x[((long)b * L_ + l) * D_ + c0 + c4 * 4]);
    *reinterpret_cast<float4*>(&tile[rr * 64 + c4 * 4]) = v;
  }
  __syncthreads();
  int c = tid & 63;
  int wv = tid >> 6;
  float wreg[K];
#pragma unroll
  for (int j = 0; j < K; ++j) wreg[j] = w[(long)(c0 + c) * K + j];
#pragma unroll
  for (int g = 0; g < 4; ++g) {
    int lo_base = g * 32 + wv * 8;
    float win[8];
#pragma unroll
    for (int r = 0; r < 8; ++r) win[r] = tile[(lo_base + r) * 64 + c];
    float acc[8] = {0.f, 0.f, 0.f, 0.f, 0.f, 0.f, 0.f, 0.f};
#pragma unroll
    for (int j = 0; j < K; ++j) {
#pragma unroll
      for (int r = 0; r < 8; ++r) acc[r] = fmaf(wreg[j], win[r], acc[r]);
      if (j < K - 1) {
#pragma unroll
        for (int r = 0; r < 7; ++r) win[r] = win[r + 1];
        win[7] = tile[(lo_base + j + 8) * 64 + c];
      }
    }
#pragma unroll
    for (int r = 0; r < 8; ++r) {
      float v = acc[r];
      if (do_silu) v = v * sigmf(v);
      y[((long)b * L_ + l0 + lo_base + r) * D_ + c0 + c] = v;
    }
  }
}

// ---------------- wave-parallel l2norm: 4 rows/block, shuffle reduce ----------------
__global__ __launch_bounds__(256)
void l2norm_wave(float* __restrict__ x) {
  long row = (long)blockIdx.x * 4 + (threadIdx.x >> 6);
  int lane = threadIdx.x & 63;
  float4 v = *reinterpret_cast<const float4*>(&x[row * 256 + lane * 4]);
  float q = v.x * v.x + v.y * v.y + v.z * v.z + v.w * v.w;
#pragma unroll
  for (int st = 32; st > 0; st >>= 1) q += __shfl_xor(q, st);
  float inv = rsqrtf(q + 1e-6f);
  v.x *= inv; v.y *= inv; v.z *= inv; v.w *= inv;
  *reinterpret_cast<float4*>(&x[row * 256 + lane * 4]) = v;
}

// ---------------- fused beta/resg GEMV ----------------
__global__ __launch_bounds__(256)
void beta_res_gemv(const float* __restrict__ hs, const float* __restrict__ Wb,
                   const float* __restrict__ Wres, const float* __restrict__ bres,
                   float* __restrict__ beta, float* __restrict__ resg) {
  long m = blockIdx.x;
  int n = threadIdx.x >> 6, lane = threadIdx.x & 63;
  float ab = 0.f, ar = 0.f;
  for (int k0 = lane * 4; k0 < 1024; k0 += 256) {
    float4 x = *reinterpret_cast<const float4*>(&hs[m * 1024 + k0]);
    ab += x.x * Wb[(k0 + 0) * 4 + n] + x.y * Wb[(k0 + 1) * 4 + n]
        + x.z * Wb[(k0 + 2) * 4 + n] + x.w * Wb[(k0 + 3) * 4 + n];
    ar += x.x * Wres[(k0 + 0) * 4 + n] + x.y * Wres[(k0 + 1) * 4 + n]
        + x.z * Wres[(k0 + 2) * 4 + n] + x.w * Wres[(k0 + 3) * 4 + n];
  }
#pragma unroll
  for (int st = 32; st > 0; st >>= 1) { ab += __shfl_xor(ab, st); ar += __shfl_xor(ar, st); }
  if (lane == 0) {
    beta[m * 4 + n] = sigmf(ab);
    resg[m * 4 + n] = sigmf(ar + bres[n]);
  }
}

// ---------------- per-chunk: inv, u (f32), and bf16 operands for the scan ----------------
__global__ __launch_bounds__(256)
void chunk_uw(const float* __restrict__ qn, const float* __restrict__ kn,
              const float* __restrict__ v, const float* __restrict__ beta,
              float* __restrict__ u,
              unsigned short* __restrict__ q_bf, unsigned short* __restrict__ w_bf,
              unsigned short* __restrict__ kT_bf, unsigned short* __restrict__ at_bf) {
  __shared__ float skT[256][33];
  __shared__ float sinv[32][33];
  __shared__ float sbeta[32];
  int blk = blockIdx.x;
  int ci = blk % NCH;
  int bh = blk / NCH;
  int h = bh % H_;
  int b = bh / H_;
  long base = ((long)b * L_ + (long)ci * CHUNKSZ) * D_ + h * DH;
  long brow = (long)b * L_ + (long)ci * CHUNKSZ;
  long obase = (long)blk * 8192;
  int tid = threadIdx.x;
  for (int i = tid; i < 32 * 256; i += 256) {
    int r = i >> 8, c = i & 255;
    skT[c][r] = kn[base + (long)r * D_ + c];
  }
  if (tid < 32) sbeta[tid] = beta[(brow + tid) * H_ + h];
  __syncthreads();
  for (int i = tid; i < 8192; i += 256)
    kT_bf[obase + i] = f2bf(skT[i >> 5][i & 31]);
  for (int i = tid; i < 8192; i += 256)
    q_bf[obase + i] = f2bf(qn[base + (long)(i >> 8) * D_ + (i & 255)]);
  int j = tid & 31, i0 = tid >> 5;
  for (int r = 0; r < 4; ++r) {
    int i = i0 + (r << 3);
    float acc = 0.f;
    for (int d = 0; d < 256; ++d) acc += skT[d][i] * skT[d][j];
    sinv[i][j] = (i > j) ? -acc * sbeta[i] : 0.f;
  }
  __syncthreads();
  for (int i = 1; i < 32; ++i) {
    float val = 0.f;
    if (tid < 32) {
      for (int t = 0; t < i; ++t) val += sinv[i][t] * sinv[t][tid];
    }
    __syncthreads();
    if (tid < 32) sinv[i][tid] += val;
    __syncthreads();
  }
  if (tid < 32) sinv[tid][tid] += 1.f;
  long abase = (long)blk * 1024;
  for (int r = 0; r < 4; ++r) {
    int i = i0 + (r << 3);
    const float* qrow = qn + base + (long)i * D_;
    float acc = 0.f;
    for (int d = 0; d < 256; ++d) acc += qrow[d] * skT[d][j];
    at_bf[abase + i * 32 + j] = f2bf((i >= j) ? acc : 0.f);
  }
  __syncthreads();
  int c = tid;
  float vt[32], kt[32];
#pragma unroll
  for (int t = 0; t < 32; ++t) {
    vt[t] = v[base + t * D_ + c] * sbeta[t];
    kt[t] = skT[c][t] * sbeta[t];
  }
#pragma unroll
  for (int i2 = 0; i2 < 32; ++i2) {
    float au = 0.f, aw = 0.f;
#pragma unroll
    for (int t = 0; t <= i2; ++t) {
      float f = sinv[i2][t];
      au += f * vt[t];
      aw += f * kt[t];
    }
    u[base + i2 * D_ + c] = au;
    w_bf[obase + i2 * 256 + c] = f2bf(aw);
  }
}

// ---------------- MFMA scan, barrier-free, peeled branch-free pipeline ----------------
// 128 blocks x 1 wave; wave owns 16 cols, full K. S f32 in accumulators.
// Main loop (127 iters) has unconditional prefetch of every operand class one chunk
// ahead, each issued right after its current consumer; last iteration peeled.
// kT frags split into 2x8 batches to reduce peak register pressure.
// `out` aliases `u` (u reads precede out stores in program order; disjoint cols across blocks).
__global__ __launch_bounds__(64, 1)
void delta_scan(const unsigned short* __restrict__ qb, const unsigned short* __restrict__ wbf,
                const unsigned short* __restrict__ ktb, const unsigned short* __restrict__ atb,
                const float* u, float* out) {
  __shared__ unsigned short sB[16 * 264];   // S^T staging: [n=16][d=256] pad 264
  __shared__ unsigned short su2[16 * 40];   // u2^T: [n=16][t=32] pad 40
  int blk = blockIdx.x;
  int bh = blk & 7, cg = blk >> 3;
  int h = bh & 3, b = bh >> 2;
  int lane = threadIdx.x;
  int l15 = lane & 15, l4 = lane >> 4;
  int colw = cg * 16;

  f32x4 zero4; zero4.x = 0.f; zero4.y = 0.f; zero4.z = 0.f; zero4.w = 0.f;
  f32x4 acc[16];
#pragma unroll
  for (int t = 0; t < 16; ++t) acc[t] = zero4;

  uint4 wf[2][8];
  float ru[2][4];
  uint4 qf[2][8];
  uint4 kfa[8], kfb[8];
  uint4 af[2];

#define LOAD_W(CI) do {                                                          \
    long o8_ = ((long)bh * NCH + (CI)) * 8192;                                   \
    _Pragma("unroll")                                                            \
    for (int m_ = 0; m_ < 2; ++m_)                                               \
      _Pragma("unroll")                                                          \
      for (int kc_ = 0; kc_ < 8; ++kc_)                                          \
        wf[m_][kc_] = *reinterpret_cast<const uint4*>(                           \
            &wbf[o8_ + (16 * m_ + l15) * 256 + kc_ * 32 + l4 * 8]);              \
  } while (0)

#define LOAD_U(CI) do {                                                          \
    long ub_ = ((long)b * L_ + (long)(CI) * CHUNKSZ) * D_ + h * DH + colw;       \
    _Pragma("unroll")                                                            \
    for (int m_ = 0; m_ < 2; ++m_)                                               \
      _Pragma("unroll")                                                          \
      for (int r_ = 0; r_ < 4; ++r_)                                             \
        ru[m_][r_] = u[ub_ + (long)(16 * m_ + 4 * l4 + r_) * D_ + l15];          \
  } while (0)

#define LOAD_Q(CI) do {                                                          \
    long o8_ = ((long)bh * NCH + (CI)) * 8192;                                   \
    _Pragma("unroll")                                                            \
    for (int m_ = 0; m_ < 2; ++m_)                                               \
      _Pragma("unroll")                                                          \
      for (int kc_ = 0; kc_ < 8; ++kc_)                                          \
        qf[m_][kc_] = *reinterpret_cast<const uint4*>(                           \
            &qb[o8_ + (16 * m_ + l15) * 256 + kc_ * 32 + l4 * 8]);               \
  } while (0)

#define LOAD_KA(CI) do {                                                         \
    long o8_ = ((long)bh * NCH + (CI)) * 8192;                                   \
    _Pragma("unroll")                                                            \
    for (int dt_ = 0; dt_ < 8; ++dt_)                                            \
      kfa[dt_] = *reinterpret_cast<const uint4*>(                                \
          &ktb[o8_ + (16 * dt_ + l15) * 32 + l4 * 8]);                           \
  } while (0)

#define LOAD_KB(CI) do {                                                         \
    long o8_ = ((long)bh * NCH + (CI)) * 8192;                                   \
    _Pragma("unroll")                                                            \
    for (int dt_ = 0; dt_ < 8; ++dt_)                                            \
      kfb[dt_] = *reinterpret_cast<const uint4*>(                                \
          &ktb[o8_ + (16 * (dt_ + 8) + l15) * 32 + l4 * 8]);                     \
  } while (0)

#define LOAD_A(CI) do {                                                          \
    long oa_ = ((long)bh * NCH + (CI)) * 1024;                                   \
    _Pragma("unroll")                                                            \
    for (int m_ = 0; m_ < 2; ++m_)                                               \
      af[m_] = *reinterpret_cast<const uint4*>(                                  \
          &atb[oa_ + (16 * m_ + l15) * 32 + l4 * 8]);                            \
  } while (0)

#define SCAN_BODY(CI, PF) do {                                                   \
    long ub = ((long)b * L_ + (long)(CI) * CHUNKSZ) * D_ + h * DH + colw;        \
    _Pragma("unroll")                                                            \
    for (int dt = 0; dt < 16; ++dt) {                                            \
      uint2 pv;                                                                  \
      pv.x = pk2bf(acc[dt].x, acc[dt].y);                                        \
      pv.y = pk2bf(acc[dt].z, acc[dt].w);                                        \
      *reinterpret_cast<uint2*>(&sB[l15 * 264 + dt * 16 + l4 * 4]) = pv;         \
    }                                                                            \
    bf16x8 sf[8];                                                                \
    _Pragma("unroll")                                                            \
    for (int kc = 0; kc < 8; ++kc)                                               \
      sf[kc] = *reinterpret_cast<const bf16x8*>(&sB[l15 * 264 + kc * 32 + l4 * 8]); \
    f32x4 wa[2][2];                                                              \
    wa[0][0] = zero4; wa[0][1] = zero4; wa[1][0] = zero4; wa[1][1] = zero4;      \
    _Pragma("unroll")                                                            \
    for (int kc = 0; kc < 8; ++kc) {                                             \
      _Pragma("unroll")                                                          \
      for (int m = 0; m < 2; ++m)                                                \
        wa[m][kc & 1] = __builtin_amdgcn_mfma_f32_16x16x32_bf16(                 \
            *reinterpret_cast<bf16x8*>(&wf[m][kc]), sf[kc], wa[m][kc & 1], 0, 0, 0); \
    }                                                                            \
    if (PF) LOAD_W((CI) + 1);                                                    \
    _Pragma("unroll")                                                            \
    for (int m = 0; m < 2; ++m) {                                                \
      f32x4 wsum = wa[m][0] + wa[m][1];                                          \
      uint2 pv;                                                                  \
      pv.x = pk2bf(ru[m][0] - wsum.x, ru[m][1] - wsum.y);                        \
      pv.y = pk2bf(ru[m][2] - wsum.z, ru[m][3] - wsum.w);                        \
      *reinterpret_cast<uint2*>(&su2[l15 * 40 + m * 16 + l4 * 4]) = pv;          \
    }                                                                            \
    if (PF) LOAD_U((CI) + 1);                                                    \
    bf16x8 u2f = *reinterpret_cast<const bf16x8*>(&su2[l15 * 40 + l4 * 8]);      \
    _Pragma("unroll")                                                            \
    for (int dt = 0; dt < 8; ++dt)                                               \
      acc[dt] = __builtin_amdgcn_mfma_f32_16x16x32_bf16(                         \
          *reinterpret_cast<bf16x8*>(&kfa[dt]), u2f, acc[dt], 0, 0, 0);          \
    if (PF) LOAD_KA((CI) + 1);                                                   \
    _Pragma("unroll")                                                            \
    for (int dt = 0; dt < 8; ++dt)                                               \
      acc[dt + 8] = __builtin_amdgcn_mfma_f32_16x16x32_bf16(                     \
          *reinterpret_cast<bf16x8*>(&kfb[dt]), u2f, acc[dt + 8], 0, 0, 0);      \
    if (PF) LOAD_KB((CI) + 1);                                                   \
    f32x4 qa[2][2];                                                              \
    qa[0][0] = zero4; qa[0][1] = zero4; qa[1][0] = zero4; qa[1][1] = zero4;      \
    _Pragma("unroll")                                                            \
    for (int kc = 0; kc < 8; ++kc) {                                             \
      _Pragma("unroll")                                                          \
      for (int m = 0; m < 2; ++m)                                                \
        qa[m][kc & 1] = __builtin_amdgcn_mfma_f32_16x16x32_bf16(                 \
            *reinterpret_cast<bf16x8*>(&qf[m][kc]), sf[kc], qa[m][kc & 1], 0, 0, 0); \
    }                                                                            \
    if (PF) LOAD_Q((CI) + 1);                                                    \
    _Pragma("unroll")                                                            \
    for (int m = 0; m < 2; ++m) {                                                \
      f32x4 qacc = qa[m][0] + qa[m][1];                                          \
      f32x4 dv = __builtin_amdgcn_mfma_f32_16x16x32_bf16(                        \
          *reinterpret_cast<bf16x8*>(&af[m]), u2f, qacc, 0, 0, 0);               \
      _Pragma("unroll")                                                          \
      for (int r = 0; r < 4; ++r)                                                \
        out[ub + (long)(16 * m + 4 * l4 + r) * D_ + l15] = dv[r];                \
    }                                                                            \
    if (PF) LOAD_A((CI) + 1);                                                    \
  } while (0)

  LOAD_W(0); LOAD_U(0); LOAD_Q(0); LOAD_KA(0); LOAD_KB(0); LOAD_A(0);

  for (int ci = 0; ci < NCH - 1; ++ci) {
    SCAN_BODY(ci, 1);
  }
  SCAN_BODY(NCH - 1, 0);

#undef LOAD_W
#undef LOAD_U
#undef LOAD_Q
#undef LOAD_KA
#undef LOAD_KB
#undef LOAD_A
#undef SCAN_BODY
}

// ---------------- fused head stats x4 tensors: wave w -> tensor w ----------------
__global__ __launch_bounds__(256)
void head_stats4(const float* __restrict__ t0, const float* __restrict__ t1,
                 const float* __restrict__ t2, const float* __restrict__ t3,
                 float* __restrict__ outp) {
  long bl = blockIdx.x;
  int w = threadIdx.x >> 6, lane = threadIdx.x & 63;
  const float* x = (w == 0) ? t0 : (w == 1) ? t1 : (w == 2) ? t2 : t3;
  float m = 0.f, vv = 0.f, am = 0.f, l2 = 0.f;
#pragma unroll
  for (int h = 0; h < 4; ++h) {
    float4 v = *reinterpret_cast<const float4*>(&x[bl * 1024 + h * 256 + lane * 4]);
    float s = v.x + v.y + v.z + v.w;
    float q = v.x * v.x + v.y * v.y + v.z * v.z + v.w * v.w;
    float a = fabsf(v.x) + fabsf(v.y) + fabsf(v.z) + fabsf(v.w);
#pragma unroll
    for (int st = 32; st > 0; st >>= 1) {
      s += __shfl_xor(s, st); q += __shfl_xor(q, st); a += __shfl_xor(a, st);
    }
    float mean = s * (1.f / 256.f);
    m += mean;
    vv += q * (1.f / 256.f) - mean * mean;
    am += a * (1.f / 256.f);
    l2 += sqrtf(q);
  }
  if (lane == 0) {
    float* o = outp + bl * 16 + w * 4;
    o[0] = m * 0.25f; o[1] = vv * 0.25f; o[2] = am * 0.25f; o[3] = l2 * 0.25f;
  }
}

// ---------------- gate: gelu(g + bg1 + stats@Wtail) @ Wg2 + bg2 -> softmax p (fused) ----------------
__global__ __launch_bounds__(256)
void gate_fused(const float* __restrict__ g, const float* __restrict__ stats,
                const float* __restrict__ Wg1t, const float* __restrict__ bg1,
                const float* __restrict__ Wg2, const float* __restrict__ bg2,
                const float* __restrict__ temp_in, float* __restrict__ p) {
  __shared__ float red[4][4];
  long m = blockIdx.x;
  int tid = threadIdx.x;
  int c0 = tid * 4;
  float4 gv = *reinterpret_cast<const float4*>(&g[m * 1024 + c0]);
  float st[16];
#pragma unroll
  for (int k = 0; k < 16; ++k) st[k] = stats[m * 16 + k];
  float la[4] = {0.f, 0.f, 0.f, 0.f};
  float gvv[4] = {gv.x, gv.y, gv.z, gv.w};
#pragma unroll
  for (int j = 0; j < 4; ++j) {
    int c = c0 + j;
    float s = gvv[j] + bg1[c];
#pragma unroll
    for (int k = 0; k < 16; ++k) s += st[k] * Wg1t[(long)k * 1024 + c];
    float ge = geluf(s);
#pragma unroll
    for (int n = 0; n < 4; ++n) la[n] += ge * Wg2[c * 4 + n];
  }
#pragma unroll
  for (int stp = 32; stp > 0; stp >>= 1)
#pragma unroll
    for (int n = 0; n < 4; ++n) la[n] += __shfl_xor(la[n], stp);
  int w = tid >> 6;
  if ((tid & 63) == 0) {
#pragma unroll
    for (int n = 0; n < 4; ++n) red[w][n] = la[n];
  }
  __syncthreads();
  if (tid == 0) {
    float temp = log1pf(expf(temp_in[0]));
    float l[4];
#pragma unroll
    for (int n = 0; n < 4; ++n)
      l[n] = (red[0][n] + red[1][n] + red[2][n] + red[3][n] + bg2[n]) / temp;
    float mx = fmaxf(fmaxf(l[0], l[1]), fmaxf(l[2], l[3]));
    float e[4], s = 0.f;
#pragma unroll
    for (int n = 0; n < 4; ++n) { e[n] = expf(l[n] - mx); s += e[n]; }
    float s2 = 0.f;
#pragma unroll
    for (int n = 0; n < 4; ++n) { e[n] = fmaxf(e[n] / s, 0.02f); s2 += e[n]; }
#pragma unroll
    for (int n = 0; n < 4; ++n) p[m * 4 + n] = e[n] / s2;
  }
}

// ---------------- combine + og stats (o, v_direct) fused; block per (b,l) row ----------------
__global__ __launch_bounds__(256)
void combine_ogstats(const float* __restrict__ ls, const float* __restrict__ ll,
                     const float* __restrict__ dd, const float* __restrict__ vd,
                     const float* __restrict__ p, const float* __restrict__ resg,
                     const float* __restrict__ crl, float* __restrict__ o,
                     float* __restrict__ og8) {
  __shared__ float part[4][8];
  long bl = blockIdx.x;
  int h = threadIdx.x >> 6, lane = threadIdx.x & 63;
  long base = bl * 1024 + h * 256 + lane * 4;
  float4 lsv = *reinterpret_cast<const float4*>(&ls[base]);
  float4 llv = *reinterpret_cast<const float4*>(&ll[base]);
  float4 ddv = *reinterpret_cast<const float4*>(&dd[base]);
  float4 vdv = *reinterpret_cast<const float4*>(&vd[base]);
  float p0 = p[bl * 4 + 0], p1 = p[bl * 4 + 1], p2 = p[bl * 4 + 2], p3 = p[bl * 4 + 3];
  float sg = sigmf(crl[h]) * resg[bl * 4 + h];
  float c0 = p0 + sg;
  float4 ov;
  ov.x = c0 * lsv.x + p1 * llv.x + p2 * ddv.x + p3 * vdv.x;
  ov.y = c0 * lsv.y + p1 * llv.y + p2 * ddv.y + p3 * vdv.y;
  ov.z = c0 * lsv.z + p1 * llv.z + p2 * ddv.z + p3 * vdv.z;
  ov.w = c0 * lsv.w + p1 * llv.w + p2 * ddv.w + p3 * vdv.w;
  *reinterpret_cast<float4*>(&o[base]) = ov;
  float s = ov.x + ov.y + ov.z + ov.w;
  float q = ov.x * ov.x + ov.y * ov.y + ov.z * ov.z + ov.w * ov.w;
  float a = fabsf(ov.x) + fabsf(ov.y) + fabsf(ov.z) + fabsf(ov.w);
  float sv = vdv.x + vdv.y + vdv.z + vdv.w;
  float qv = vdv.x * vdv.x + vdv.y * vdv.y + vdv.z * vdv.z + vdv.w * vdv.w;
  float av = fabsf(vdv.x) + fabsf(vdv.y) + fabsf(vdv.z) + fabsf(vdv.w);
#pragma unroll
  for (int st = 32; st > 0; st >>= 1) {
    s += __shfl_xor(s, st); q += __shfl_xor(q, st); a += __shfl_xor(a, st);
    sv += __shfl_xor(sv, st); qv += __shfl_xor(qv, st); av += __shfl_xor(av, st);
  }
  if (lane == 0) {
    float mo = s * (1.f / 256.f), mv = sv * (1.f / 256.f);
    part[h][0] = mo; part[h][1] = q * (1.f / 256.f) - mo * mo;
    part[h][2] = a * (1.f / 256.f); part[h][3] = sqrtf(q);
    part[h][4] = mv; part[h][5] = qv * (1.f / 256.f) - mv * mv;
    part[h][6] = av * (1.f / 256.f); part[h][7] = sqrtf(qv);
  }
  __syncthreads();
  if (threadIdx.x < 8) {
    int t = threadIdx.x;
    og8[bl * 8 + t] = 0.25f * (part[0][t] + part[1][t] + part[2][t] + part[3][t]);
  }
}

// ---------------- og: gelu(g + bog1 + og8@Wtail) @ Wog2 + bog2 -> sigmoid (fused) ----------------
__global__ __launch_bounds__(256)
void og_gate_fused(const float* __restrict__ g, const float* __restrict__ og8,
                   const float* __restrict__ Wog1t, const float* __restrict__ bog1,
                   const float* __restrict__ Wog2, const float* __restrict__ bog2,
                   float* __restrict__ ogv) {
  __shared__ float red[4];
  long m = blockIdx.x;
  int tid = threadIdx.x;
  int c0 = tid * 2;
  float2 gv = *reinterpret_cast<const float2*>(&g[m * 512 + c0]);
  float st[8];
#pragma unroll
  for (int k = 0; k < 8; ++k) st[k] = og8[m * 8 + k];
  float a = 0.f;
  float gvv[2] = {gv.x, gv.y};
#pragma unroll
  for (int j = 0; j < 2; ++j) {
    int c = c0 + j;
    float s = gvv[j] + bog1[c];
#pragma unroll
    for (int k = 0; k < 8; ++k) s += st[k] * Wog1t[(long)k * 512 + c];
    a += geluf(s) * Wog2[c];
  }
#pragma unroll
  for (int stp = 32; stp > 0; stp >>= 1) a += __shfl_xor(a, stp);
  int w = tid >> 6;
  if ((tid & 63) == 0) red[w] = a;
  __syncthreads();
  if (tid == 0) ogv[m] = sigmf(red[0] + red[1] + red[2] + red[3] + bog2[0]);
}

// ---------------- wave-parallel scale+rmsnorm, writes bf16 directly ----------------
__global__ __launch_bounds__(256)
void scale_rmsnorm_bf16(const float* __restrict__ o, const float* __restrict__ og,
                        const float* __restrict__ nw, unsigned short* __restrict__ xb) {
  long row = (long)blockIdx.x * 4 + (threadIdx.x >> 6);
  long bl = row >> 2;
  int lane = threadIdx.x & 63;
  float g = og[bl];
  float4 v = *reinterpret_cast<const float4*>(&o[row * 256 + lane * 4]);
  v.x *= g; v.y *= g; v.z *= g; v.w *= g;
  float q = v.x * v.x + v.y * v.y + v.z * v.z + v.w * v.w;
#pragma unroll
  for (int st = 32; st > 0; st >>= 1) q += __shfl_xor(q, st);
  float scale = rsqrtf(q * (1.f / 256.f) + 1e-5f);
  float4 w4 = *reinterpret_cast<const float4*>(&nw[lane * 4]);
  ushort4 r;
  r.x = f2bf(v.x * scale * w4.x);
  r.y = f2bf(v.y * scale * w4.y);
  r.z = f2bf(v.z * scale * w4.z);
  r.w = f2bf(v.w * scale * w4.w);
  *reinterpret_cast<ushort4*>(&xb[row * 256 + lane * 4]) = r;
}

extern "C" void kernel_launch(void* const* d_in, const int* in_sizes, int n_in,
                              void* d_out, int out_size, void* d_ws, size_t ws_size,
                              hipStream_t stream) {
  const float* hs       = (const float*)d_in[0];
  const float* Wq       = (const float*)d_in[1];
  const float* Wk       = (const float*)d_in[2];
  const float* Wv       = (const float*)d_in[3];
  const float* Wb       = (const float*)d_in[4];
  const float* wq_conv  = (const float*)d_in[5];
  const float* wk_conv  = (const float*)d_in[6];
  const float* wv_conv  = (const float*)d_in[7];
  const float* fir_long = (const float*)d_in[8];
  const float* fir_short= (const float*)d_in[9];
  const float* Wg1      = (const float*)d_in[10];
  const float* bg1      = (const float*)d_in[11];
  const float* Wg2      = (const float*)d_in[12];
  const float* bg2      = (const float*)d_in[13];
  const float* logit_temp     = (const float*)d_in[14];
  const float* conv_res_logit = (const float*)d_in[15];
  const float* Wres     = (const float*)d_in[16];
  const float* bres     = (const float*)d_in[17];
  const float* Wog1     = (const float*)d_in[18];
  const float* bog1     = (const float*)d_in[19];
  const float* Wog2     = (const float*)d_in[20];
  const float* bog2     = (const float*)d_in[21];
  const float* norm_w   = (const float*)d_in[22];
  const float* Wo       = (const float*)d_in[23];
  float* out = (float*)d_out;
  float* ws = (float*)d_ws;

  float* b0 = ws;             // qlin -> kn -> gate_hidden -> o_mix
  float* b1 = ws + 1L * BLD;  // klin -> v_in (v_direct)
  float* b2 = ws + 2L * BLD;  // vlin -> u -> delta_out -> og_hidden
  float* b3 = ws + 3L * BLD;  // qn -> local_long
  float* b4 = ws + 4L * BLD;  // w_bf (bf16, first half) -> local_short
  float* sm = ws + 5L * BLD;
  float* beta    = sm;
  float* resg    = beta + BL * H_;
  float* stats16 = resg + BL * H_;
  float* og8     = stats16 + BL * 16;
  float* logits  = og8 + BL * 8;
  float* pbuf    = logits + BL * 4;
  float* ogv     = pbuf + BL * 4;
  unsigned short* q_bfg  = (unsigned short*)(ogv + BL);   // BLD bf16
  unsigned short* kT_bfg = q_bfg + (long)BLD;             // BLD bf16
  unsigned short* at_bfg = kT_bfg + (long)BLD;            // 1M bf16
  unsigned short* hsb  = at_bfg + 1024L * 1024;           // BLD bf16
  unsigned short* wtq  = hsb + (long)BLD;
  unsigned short* wtk  = wtq + 1024L * 1024;
  unsigned short* wtv  = wtk + 1024L * 1024;
  unsigned short* wtg1 = wtv + 1024L * 1024;
  unsigned short* wto  = wtg1 + 1024L * 1024;
  unsigned short* wtog1= wto + 1024L * 1024;
  unsigned short* w_bfg = (unsigned short*)b4;            // bf16 w inside b4
  unsigned short* xb    = q_bfg;                          // reuse (q_bf dead after scan)

  size_t needed = (5L * BLD + BL * 41) * 4
                + (3L * BLD + 1024L * 1024 + 5L * 1024 * 1024 + 512L * 1024) * 2;
  if (ws_size < needed) return;

  dim3 blk(256);
  // 0. preconvert
  wconv_t<<<dim3(32, 32), blk, 0, stream>>>(Wq, wtq, 1024);
  wconv_t<<<dim3(32, 32), blk, 0, stream>>>(Wk, wtk, 1024);
  wconv_t<<<dim3(32, 32), blk, 0, stream>>>(Wv, wtv, 1024);
  wconv_t<<<dim3(32, 32), blk, 0, stream>>>(Wg1, wtg1, 1024);
  wconv_t<<<dim3(32, 32), blk, 0, stream>>>(Wo, wto, 1024);
  wconv_t<<<dim3(16, 32), blk, 0, stream>>>(Wog1, wtog1, 512);
  cvt_bf16<<<BLD / 1024, blk, 0, stream>>>(hs, hsb, BLD);
  // 1. projections
  gemm_bf16<<<dim3(8, 64), blk, 0, stream>>>(hsb, wtq, b0, 1024);
  gemm_bf16<<<dim3(8, 64), blk, 0, stream>>>(hsb, wtk, b1, 1024);
  gemm_bf16<<<dim3(8, 64), blk, 0, stream>>>(hsb, wtv, b2, 1024);
  // 2. conv + silu (sliding-window tiled)
  dwconv_tiled<4><<<1024, blk, 0, stream>>>(b0, wq_conv, b3, 1);
  dwconv_tiled<4><<<1024, blk, 0, stream>>>(b1, wk_conv, b0, 1);
  dwconv_tiled<4><<<1024, blk, 0, stream>>>(b2, wv_conv, b1, 1);
  // 3. beta + res gate (fused wave GEMV)
  beta_res_gemv<<<BL, blk, 0, stream>>>(hs, Wb, Wres, bres, beta, resg);
  // 4. l2norm (wave-parallel)
  l2norm_wave<<<BL * H_ / 4, blk, 0, stream>>>(b3);
  l2norm_wave<<<BL * H_ / 4, blk, 0, stream>>>(b0);
  // 5-6. delta rule (u->b2; bf16 operands; scan writes delta_out in place over u)
  chunk_uw<<<B_ * H_ * NCH, blk, 0, stream>>>(b3, b0, b1, beta, b2, q_bfg, w_bfg, kT_bfg, at_bfg);
  delta_scan<<<128, dim3(64), 0, stream>>>(q_bfg, w_bfg, kT_bfg, at_bfg, b2, b2);
  // 7. local convs
  dwconv_tiled<64><<<1024, blk, 0, stream>>>(b1, fir_long, b3, 0);
  dwconv_tiled<5><<<1024, blk, 0, stream>>>(b1, fir_short, b4, 0);
  // 8. stats16 fused (ls=b4, ll=b3, dd=b2, vd=b1)
  head_stats4<<<BL, blk, 0, stream>>>(b4, b3, b2, b1, stats16);
  // 9. gate hidden + gate tail + logits + softmax (fused)
  gemm_bf16<<<dim3(8, 64), blk, 0, stream>>>(hsb, wtg1, b0, 1024);
  gate_fused<<<BL, blk, 0, stream>>>(b0, stats16, Wg1 + 1024L * 1024, bg1, Wg2, bg2, logit_temp, pbuf);
  // 10. combine + og stats (fused) -> b0, og8
  combine_ogstats<<<BL, blk, 0, stream>>>(b4, b3, b2, b1, pbuf, resg, conv_res_logit, b0, og8);
  // 11. output gate: gemm + fused tail/gemv/sigmoid
  gemm_bf16<<<dim3(4, 64), blk, 0, stream>>>(hsb, wtog1, b2, 512);
  og_gate_fused<<<BL, blk, 0, stream>>>(b2, og8, Wog1 + 1024L * 512, bog1, Wog2, bog2, ogv);
  // 12. scale + rmsnorm -> bf16 directly
  scale_rmsnorm_bf16<<<BL * H_ / 4, blk, 0, stream>>>(b0, ogv, norm_w, xb);
  // 13. final projection
  gemm_bf16<<<dim3(8, 64), blk, 0, stream>>>(xb, wto, out, 1024);
}